// Round 1
// baseline (2103.540 us; speedup 1.0000x reference)
//
#include <hip/hip_runtime.h>
#include <math.h>

#define NN 20000
#define NE 320000
#define NB 512
#define FIN 43
#define HD 128
#define HC 512
#define ATT_SCALE 0.08838834764831843f

// ---------------- tiled fp32 GEMM body: Y = X@W + bias (optional relu) ----------------
__device__ __forceinline__ void gemm_body(
    const float* __restrict__ X, const float* __restrict__ W,
    const float* __restrict__ bias, float* __restrict__ Y,
    int Nr, int K, int M, int rowBase, int colBase, int do_relu)
{
  __shared__ float As[16][68];
  __shared__ __align__(16) float Bs[16][64];
  const int tid = threadIdx.x;
  const int tx = tid & 15, ty = tid >> 4;
  float acc[4][4] = {};
  for (int k0 = 0; k0 < K; k0 += 16) {
#pragma unroll
    for (int i = 0; i < 4; ++i) {
      int idx = tid + i * 256;
      int r = idx >> 4, kk = idx & 15;
      int gr = rowBase + r, gk = k0 + kk;
      As[kk][r] = (gr < Nr && gk < K) ? X[(size_t)gr * (size_t)K + gk] : 0.f;
    }
#pragma unroll
    for (int i = 0; i < 4; ++i) {
      int idx = tid + i * 256;
      int kk = idx >> 6, n = idx & 63;
      int gk = k0 + kk, gn = colBase + n;
      Bs[kk][n] = (gk < K && gn < M) ? W[(size_t)gk * (size_t)M + gn] : 0.f;
    }
    __syncthreads();
#pragma unroll
    for (int kk = 0; kk < 16; ++kk) {
      float4 b = *(const float4*)&Bs[kk][tx * 4];
#pragma unroll
      for (int i = 0; i < 4; ++i) {
        float a = As[kk][ty * 4 + i];
        acc[i][0] += a * b.x;
        acc[i][1] += a * b.y;
        acc[i][2] += a * b.z;
        acc[i][3] += a * b.w;
      }
    }
    __syncthreads();
  }
#pragma unroll
  for (int i = 0; i < 4; ++i) {
    int row = rowBase + ty * 4 + i;
    if (row >= Nr) continue;
#pragma unroll
    for (int j = 0; j < 4; ++j) {
      int col = colBase + tx * 4 + j;
      if (col >= M) continue;
      float v = acc[i][j] + bias[col];
      if (do_relu) v = fmaxf(v, 0.f);
      Y[(size_t)row * (size_t)M + col] = v;
    }
  }
}

__global__ __launch_bounds__(256) void gemm_kernel(
    const float* __restrict__ X, const float* __restrict__ W,
    const float* __restrict__ bias, float* __restrict__ Y,
    int Nr, int K, int M, int do_relu)
{
  gemm_body(X, W, bias, Y, Nr, K, M, blockIdx.x * 64, blockIdx.y * 64, do_relu);
}

// q/k/v/skip in one launch: blockIdx.y in [0,32): 8 col-blocks per output
__global__ __launch_bounds__(256) void gemm4_kernel(
    const float* __restrict__ X,
    const float* __restrict__ W0, const float* __restrict__ c0, float* __restrict__ Y0,
    const float* __restrict__ W1, const float* __restrict__ c1, float* __restrict__ Y1,
    const float* __restrict__ W2, const float* __restrict__ c2, float* __restrict__ Y2,
    const float* __restrict__ W3, const float* __restrict__ c3, float* __restrict__ Y3,
    int Nr, int K)
{
  int which = blockIdx.y >> 3;
  const float* W = which == 0 ? W0 : which == 1 ? W1 : which == 2 ? W2 : W3;
  const float* bias = which == 0 ? c0 : which == 1 ? c1 : which == 2 ? c2 : c3;
  float* Y = which == 0 ? Y0 : which == 1 ? Y1 : which == 2 ? Y2 : Y3;
  gemm_body(X, W, bias, Y, Nr, K, HC, blockIdx.x * 64, (blockIdx.y & 7) * 64, 0);
}

// ---------------- CSR build over dst ----------------
__global__ __launch_bounds__(256) void count_kernel(const int* __restrict__ dst, int* __restrict__ cnt)
{
  int e = blockIdx.x * 256 + threadIdx.x;
  if (e < NE) atomicAdd(&cnt[dst[e]], 1);
}

__global__ __launch_bounds__(1024) void scan_kernel(const int* __restrict__ cnt, int* __restrict__ row_start)
{
  __shared__ int sums[1024];
  int t = threadIdx.x;
  const int per = (NN + 1023) / 1024;
  int beg = t * per;
  int end = beg + per; if (end > NN) end = NN; if (beg > NN) beg = NN;
  int s = 0;
  for (int i = beg; i < end; ++i) s += cnt[i];
  sums[t] = s;
  __syncthreads();
  for (int off = 1; off < 1024; off <<= 1) {
    int v = (t >= off) ? sums[t - off] : 0;
    __syncthreads();
    sums[t] += v;
    __syncthreads();
  }
  int prefix = (t == 0) ? 0 : sums[t - 1];
  for (int i = beg; i < end; ++i) { row_start[i] = prefix; prefix += cnt[i]; }
  if (t == 1023) row_start[NN] = prefix;
}

__global__ __launch_bounds__(256) void scatter_kernel(
    const int* __restrict__ dst, const int* __restrict__ row_start,
    int* __restrict__ cursor, int* __restrict__ edge_list)
{
  int e = blockIdx.x * 256 + threadIdx.x;
  if (e < NE) {
    int d = dst[e];
    int p = atomicAdd(&cursor[d], 1);
    edge_list[row_start[d] + p] = e;
  }
}

// ---------------- edge attention scores ----------------
__global__ __launch_bounds__(256) void edge_alpha_kernel(
    const float* __restrict__ q, const float* __restrict__ k,
    const int* __restrict__ src, const int* __restrict__ dst,
    float* __restrict__ alpha)
{
  int gw = (int)((blockIdx.x * 256u + threadIdx.x) >> 6);
  int lane = threadIdx.x & 63;
  if (gw >= NE) return;
  int s = src[gw], d = dst[gw];
  const float* qp = q + (size_t)d * HC;
  const float* kp = k + (size_t)s * HC;
#pragma unroll
  for (int h = 0; h < 4; ++h) {
    float p = qp[h * 128 + lane] * kp[h * 128 + lane]
            + qp[h * 128 + 64 + lane] * kp[h * 128 + 64 + lane];
#pragma unroll
    for (int off = 32; off >= 1; off >>= 1) p += __shfl_xor(p, off);
    if (lane == 0) alpha[(size_t)gw * 4 + h] = p * ATT_SCALE;
  }
}

// ---------------- segment softmax per (node, head), in place ----------------
__global__ __launch_bounds__(256) void softmax_kernel(
    float* __restrict__ alpha, const int* __restrict__ row_start, const int* __restrict__ edge_list)
{
  int idx = blockIdx.x * 256 + threadIdx.x;
  if (idx >= NN * 4) return;
  int node = idx >> 2, h = idx & 3;
  int beg = row_start[node], end = row_start[node + 1];
  if (beg == end) return;
  float m = -INFINITY;
  for (int j = beg; j < end; ++j) m = fmaxf(m, alpha[(size_t)edge_list[j] * 4 + h]);
  float den = 0.f;
  for (int j = beg; j < end; ++j) den += expf(alpha[(size_t)edge_list[j] * 4 + h] - m);
  float inv = 1.f / fmaxf(den, 1e-16f);
  for (int j = beg; j < end; ++j) {
    size_t a = (size_t)edge_list[j] * 4 + h;
    alpha[a] = expf(alpha[a] - m) * inv;
  }
}

// ---------------- aggregate: out[node] += sum_e w[e,h] * v[src_e] ----------------
__global__ __launch_bounds__(256) void aggregate_kernel(
    const float* __restrict__ v, const float* __restrict__ w,
    const int* __restrict__ src, const int* __restrict__ row_start,
    const int* __restrict__ edge_list, float* __restrict__ out)
{
  int node = blockIdx.x;
  int tid = threadIdx.x;
  int beg = row_start[node], end = row_start[node + 1];
  int c0 = tid, c1 = tid + 256;
  int h0 = c0 >> 7, h1 = c1 >> 7;
  float acc0 = 0.f, acc1 = 0.f;
  for (int j = beg; j < end; ++j) {
    int e = edge_list[j];
    int s = src[e];
    const float* vp = v + (size_t)s * HC;
    float w0 = w[(size_t)e * 4 + h0];
    float w1 = w[(size_t)e * 4 + h1];
    acc0 += w0 * vp[c0];
    acc1 += w1 * vp[c1];
  }
  size_t o = (size_t)node * HC;
  out[o + c0] += acc0;
  out[o + c1] += acc1;
}

// ---------------- pooling ----------------
__global__ __launch_bounds__(256) void pool_init_kernel(float* __restrict__ gm, float* __restrict__ gsum, int* __restrict__ gcnt)
{
  int i = blockIdx.x * 256 + threadIdx.x;
  if (i < NB * HD) { ((int*)gm)[i] = 0xFF800000; gsum[i] = 0.f; }
  if (i < NB) gcnt[i] = 0;
}

__global__ __launch_bounds__(256) void pool_kernel(
    const float* __restrict__ h, const int* __restrict__ batch,
    float* __restrict__ gm, float* __restrict__ gsum, int* __restrict__ gcnt)
{
  int idx = blockIdx.x * 256 + threadIdx.x;
  if (idx >= NN * HD) return;
  int node = idx >> 7, c = idx & 127;
  int b = batch[node];
  float val = h[idx];
  // h is post-ReLU (>=0), so signed-int max == float max here
  atomicMax((int*)&gm[(size_t)b * HD + c], __float_as_int(val));
  atomicAdd(&gsum[(size_t)b * HD + c], val);
  if (c == 0) atomicAdd(&gcnt[b], 1);
}

__global__ __launch_bounds__(256) void pool_finalize_kernel(
    const float* __restrict__ gm, const float* __restrict__ gsum,
    const int* __restrict__ gcnt, float* __restrict__ g)
{
  int idx = blockIdx.x * 256 + threadIdx.x;
  if (idx >= NB * HD) return;
  int b = idx >> 7, c = idx & 127;
  float m = gm[idx];
  if (m < -1e30f) m = 0.f;  // empty graph -> 0 (matches isfinite clamp)
  float cf = (float)gcnt[b];
  g[(size_t)b * 256 + c] = m;
  g[(size_t)b * 256 + 128 + c] = gsum[idx] / fmaxf(cf, 1.f);
}

extern "C" void kernel_launch(void* const* d_in, const int* in_sizes, int n_in,
                              void* d_out, int out_size, void* d_ws, size_t ws_size,
                              hipStream_t stream)
{
  const float* x = (const float*)d_in[0];
  const int* edge_index = (const int*)d_in[1];
  const int* batch = (const int*)d_in[2];
  const int* src = edge_index;
  const int* dstv = edge_index + NE;

  const float *Wq[3], *bq[3], *Wk[3], *bk[3], *Wv[3], *bv[3], *Wsk[3], *bsk[3], *Wm[3], *bm[3];
  int base = 3;
  for (int l = 0; l < 3; ++l) {
    Wq[l]  = (const float*)d_in[base + 0]; bq[l]  = (const float*)d_in[base + 1];
    Wk[l]  = (const float*)d_in[base + 2]; bk[l]  = (const float*)d_in[base + 3];
    Wv[l]  = (const float*)d_in[base + 4]; bv[l]  = (const float*)d_in[base + 5];
    Wsk[l] = (const float*)d_in[base + 6]; bsk[l] = (const float*)d_in[base + 7];
    Wm[l]  = (const float*)d_in[base + 8]; bm[l]  = (const float*)d_in[base + 9];
    base += 10;
  }
  const float* Wg1 = (const float*)d_in[33]; const float* bg1 = (const float*)d_in[34];
  const float* Wg2 = (const float*)d_in[35]; const float* bg2 = (const float*)d_in[36];
  const float* Wf1 = (const float*)d_in[37]; const float* bf1 = (const float*)d_in[38];
  const float* Wf2 = (const float*)d_in[39]; const float* bf2 = (const float*)d_in[40];

  // ---- workspace layout (floats) ----
  float* ws = (float*)d_ws;
  float* q    = ws;                    // 20000*512
  float* kbuf = q    + (size_t)NN * HC;
  float* vbuf = kbuf + (size_t)NN * HC;
  float* t0   = vbuf + (size_t)NN * HC;   // skip + aggregate
  float* h    = t0   + (size_t)NN * HC;   // 20000*128
  float* alph = h    + (size_t)NN * HD;   // E*4 (alpha, then w)
  float* gm   = alph + (size_t)NE * 4;    // 512*128
  float* gsum = gm   + (size_t)NB * HD;
  float* g    = gsum + (size_t)NB * HD;   // 512*256
  float* g1   = g    + (size_t)NB * 256;  // 512*1024
  float* g2   = g1   + (size_t)NB * 1024; // 512*512
  float* g3   = g2   + (size_t)NB * 512;  // 512*256
  int* icnt      = (int*)(g3 + (size_t)NB * 256); // NN
  int* cursor    = icnt + NN;                     // NN
  int* row_start = cursor + NN;                   // NN+1
  int* edge_list = row_start + NN + 1;            // NE
  int* gcnt      = edge_list + NE;                // NB

  const int GR = (NN + 63) / 64;  // 313 row-blocks

  // ---- CSR build (once; edges are layer-invariant) ----
  hipMemsetAsync(icnt, 0, sizeof(int) * 2 * NN, stream);  // icnt + cursor
  count_kernel<<<(NE + 255) / 256, 256, 0, stream>>>(dstv, icnt);
  scan_kernel<<<1, 1024, 0, stream>>>(icnt, row_start);
  scatter_kernel<<<(NE + 255) / 256, 256, 0, stream>>>(dstv, row_start, cursor, edge_list);

  // ---- 3 TransformerConv layers ----
  const float* cur = x;
  int K = FIN;
  for (int l = 0; l < 3; ++l) {
    gemm4_kernel<<<dim3(GR, 32), 256, 0, stream>>>(
        cur,
        Wq[l], bq[l], q,
        Wk[l], bk[l], kbuf,
        Wv[l], bv[l], vbuf,
        Wsk[l], bsk[l], t0,
        NN, K);
    edge_alpha_kernel<<<(NE + 3) / 4, 256, 0, stream>>>(q, kbuf, src, dstv, alph);
    softmax_kernel<<<(NN * 4 + 255) / 256, 256, 0, stream>>>(alph, row_start, edge_list);
    aggregate_kernel<<<NN, 256, 0, stream>>>(vbuf, alph, src, row_start, edge_list, t0);
    gemm_kernel<<<dim3(GR, 2), 256, 0, stream>>>(t0, Wm[l], bm[l], h, NN, HC, HD, 1);
    cur = h;
    K = HD;
  }

  // ---- pooling ----
  pool_init_kernel<<<(NB * HD + 255) / 256, 256, 0, stream>>>(gm, gsum, gcnt);
  pool_kernel<<<(NN * HD + 255) / 256, 256, 0, stream>>>(h, batch, gm, gsum, gcnt);
  pool_finalize_kernel<<<(NB * HD + 255) / 256, 256, 0, stream>>>(gm, gsum, gcnt, g);

  // ---- MLP head ----
  gemm_kernel<<<dim3((NB + 63) / 64, 16), 256, 0, stream>>>(g,  Wg1, bg1, g1, NB, 256,  1024, 1);
  gemm_kernel<<<dim3((NB + 63) / 64, 8),  256, 0, stream>>>(g1, Wg2, bg2, g2, NB, 1024, 512,  1);
  gemm_kernel<<<dim3((NB + 63) / 64, 4),  256, 0, stream>>>(g2, Wf1, bf1, g3, NB, 512,  256,  1);
  gemm_kernel<<<dim3((NB + 63) / 64, 1),  256, 0, stream>>>(g3, Wf2, bf2, (float*)d_out, NB, 256, 1, 0);
}

// Round 2
// 1737.821 us; speedup vs baseline: 1.2104x; 1.2104x over previous
//
#include <hip/hip_runtime.h>
#include <hip/hip_bf16.h>
#include <math.h>

#define NN 20000
#define MPAD 20096          // 157*128 row padding for MFMA staging
#define NE 320000
#define NB 512
#define FIN 43
#define HD 128
#define HC 512
#define NQKVS 2048
#define ATT_SCALE 0.08838834764831843f

typedef __attribute__((ext_vector_type(8))) short bf16x8v;
typedef __attribute__((ext_vector_type(4))) float f32x4v;

__device__ __forceinline__ void gload16(void* lds, const void* g) {
  __builtin_amdgcn_global_load_lds(
      (const __attribute__((address_space(1))) void*)g,
      (__attribute__((address_space(3))) void*)lds, 16, 0, 0);
}

// ============ split-bf16 MFMA GEMM: Y = (Ahi+Alo)@(Bhi+Blo)^approx + bias ============
// A: [M][ldA] bf16 hi/lo (row-major, rows padded to >= gridDim.x*128)
// B: [N][K] bf16 hi/lo  (TRANSPOSED weights: row n holds column n of original W)
// Y: fp32 [M][ldY]; optional bf16 hi/lo split outputs (same ldY)
template<int DO_RELU, int WRITE_SPLIT>
__global__ __launch_bounds__(256, 2) void gemm_mfma_kernel(
    const __hip_bfloat16* __restrict__ Ahi_, const __hip_bfloat16* __restrict__ Alo_, int ldA,
    const __hip_bfloat16* __restrict__ Bhi_, const __hip_bfloat16* __restrict__ Blo_,
    const float* __restrict__ bias,
    float* __restrict__ Y, int ldY,
    __hip_bfloat16* __restrict__ Yhi, __hip_bfloat16* __restrict__ Ylo,
    int M, int K)
{
  __shared__ short Ah[128 * 64], Al[128 * 64], Bh[128 * 64], Bl[128 * 64];
  const short* Ahi = (const short*)Ahi_;
  const short* Alo = (const short*)Alo_;
  const short* Bhi = (const short*)Bhi_;
  const short* Blo = (const short*)Blo_;
  const int tid = threadIdx.x;
  const int w = tid >> 6, lane = tid & 63;
  const int rowBase = blockIdx.x * 128, colBase = blockIdx.y * 128;
  const int srow = lane >> 3;                  // staging row within 8-row group
  const int sw = ((lane & 7) ^ srow) << 3;     // pre-swizzled k-chunk (elements)
  const int lr = lane & 15, lg = lane >> 4;
  const int wr = w >> 1, wc = w & 1;

  f32x4v acc[4][4];
#pragma unroll
  for (int m = 0; m < 4; ++m)
#pragma unroll
    for (int n = 0; n < 4; ++n) acc[m][n] = (f32x4v){0.f, 0.f, 0.f, 0.f};

  for (int k0 = 0; k0 < K; k0 += 64) {
    if (k0) __syncthreads();
#pragma unroll
    for (int t = 0; t < 4; ++t) {
      int r0 = w * 32 + t * 8;
      size_t arow = (size_t)(rowBase + r0 + srow) * ldA + k0 + sw;
      size_t brow = (size_t)(colBase + r0 + srow) * K + k0 + sw;
      gload16(&Ah[r0 * 64], Ahi + arow);
      gload16(&Al[r0 * 64], Alo + arow);
      gload16(&Bh[r0 * 64], Bhi + brow);
      gload16(&Bl[r0 * 64], Blo + brow);
    }
    __syncthreads();
#pragma unroll
    for (int kk = 0; kk < 2; ++kk) {
      bf16x8v ah[4], al[4], bh[4], bl[4];
      int cbase = ((kk * 4 + lg) ^ (lr & 7)) * 8;
#pragma unroll
      for (int m = 0; m < 4; ++m) {
        int idx = (wr * 64 + m * 16 + lr) * 64 + cbase;
        ah[m] = *(const bf16x8v*)&Ah[idx];
        al[m] = *(const bf16x8v*)&Al[idx];
      }
#pragma unroll
      for (int n = 0; n < 4; ++n) {
        int idx = (wc * 64 + n * 16 + lr) * 64 + cbase;
        bh[n] = *(const bf16x8v*)&Bh[idx];
        bl[n] = *(const bf16x8v*)&Bl[idx];
      }
#pragma unroll
      for (int m = 0; m < 4; ++m)
#pragma unroll
        for (int n = 0; n < 4; ++n) {
          acc[m][n] = __builtin_amdgcn_mfma_f32_16x16x32_bf16(ah[m], bh[n], acc[m][n], 0, 0, 0);
          acc[m][n] = __builtin_amdgcn_mfma_f32_16x16x32_bf16(ah[m], bl[n], acc[m][n], 0, 0, 0);
          acc[m][n] = __builtin_amdgcn_mfma_f32_16x16x32_bf16(al[m], bh[n], acc[m][n], 0, 0, 0);
        }
    }
  }
  // epilogue: C/D layout col=lane&15, row=(lane>>4)*4+reg (m89-verified)
#pragma unroll
  for (int m = 0; m < 4; ++m) {
#pragma unroll
    for (int n = 0; n < 4; ++n) {
      int col = colBase + wc * 64 + n * 16 + lr;
      float bb = bias[col];
#pragma unroll
      for (int r = 0; r < 4; ++r) {
        int row = rowBase + wr * 64 + m * 16 + lg * 4 + r;
        if (row < M) {
          float v = acc[m][n][r] + bb;
          if (DO_RELU) v = fmaxf(v, 0.f);
          Y[(size_t)row * ldY + col] = v;
          if (WRITE_SPLIT) {
            __hip_bfloat16 hv = __float2bfloat16(v);
            Yhi[(size_t)row * ldY + col] = hv;
            Ylo[(size_t)row * ldY + col] = __float2bfloat16(v - __bfloat162float(hv));
          }
        }
      }
    }
  }
}

// ============ weight pack: W[K][Nsrc] -> Wt hi/lo [(colOff+n)][Kpad] (transposed, split) ============
__global__ __launch_bounds__(256) void pack_w_kernel(
    const float* __restrict__ W, int K, int Kpad, int Nsrc, int colOff,
    __hip_bfloat16* __restrict__ hi, __hip_bfloat16* __restrict__ lo)
{
  int idx = blockIdx.x * 256 + threadIdx.x;
  if (idx >= Nsrc * Kpad) return;
  int n = idx / Kpad, k = idx - n * Kpad;
  float v = (k < K) ? W[(size_t)k * Nsrc + n] : 0.f;
  __hip_bfloat16 h = __float2bfloat16(v);
  size_t o = (size_t)(colOff + n) * Kpad + k;
  hi[o] = h;
  lo[o] = __float2bfloat16(v - __bfloat162float(h));
}

__global__ __launch_bounds__(256) void pack_bias4_kernel(
    const float* __restrict__ b0, const float* __restrict__ b1,
    const float* __restrict__ b2, const float* __restrict__ b3, float* __restrict__ out)
{
  int i = blockIdx.x * 256 + threadIdx.x;
  if (i >= 2048) return;
  const float* b = (i < 512) ? b0 : (i < 1024) ? b1 : (i < 1536) ? b2 : b3;
  out[i] = b[i & 511];
}

__global__ __launch_bounds__(256) void split_x_kernel(
    const float* __restrict__ x, __hip_bfloat16* __restrict__ hi, __hip_bfloat16* __restrict__ lo)
{
  int idx = blockIdx.x * 256 + threadIdx.x;
  if (idx >= NN * 64) return;
  int r = idx >> 6, c = idx & 63;
  float v = (c < FIN) ? x[(size_t)r * FIN + c] : 0.f;
  __hip_bfloat16 h = __float2bfloat16(v);
  hi[idx] = h;
  lo[idx] = __float2bfloat16(v - __bfloat162float(h));
}

// ============ fp32 tiled GEMM (small head matmuls) ============
__device__ __forceinline__ void gemm_body(
    const float* __restrict__ X, const float* __restrict__ W,
    const float* __restrict__ bias, float* __restrict__ Y,
    int Nr, int K, int M, int rowBase, int colBase, int do_relu)
{
  __shared__ float As[16][68];
  __shared__ __align__(16) float Bs[16][64];
  const int tid = threadIdx.x;
  const int tx = tid & 15, ty = tid >> 4;
  float acc[4][4] = {};
  for (int k0 = 0; k0 < K; k0 += 16) {
#pragma unroll
    for (int i = 0; i < 4; ++i) {
      int idx = tid + i * 256;
      int r = idx >> 4, kk = idx & 15;
      int gr = rowBase + r, gk = k0 + kk;
      As[kk][r] = (gr < Nr && gk < K) ? X[(size_t)gr * (size_t)K + gk] : 0.f;
    }
#pragma unroll
    for (int i = 0; i < 4; ++i) {
      int idx = tid + i * 256;
      int kk = idx >> 6, n = idx & 63;
      int gk = k0 + kk, gn = colBase + n;
      Bs[kk][n] = (gk < K && gn < M) ? W[(size_t)gk * (size_t)M + gn] : 0.f;
    }
    __syncthreads();
#pragma unroll
    for (int kk = 0; kk < 16; ++kk) {
      float4 b = *(const float4*)&Bs[kk][tx * 4];
#pragma unroll
      for (int i = 0; i < 4; ++i) {
        float a = As[kk][ty * 4 + i];
        acc[i][0] += a * b.x;
        acc[i][1] += a * b.y;
        acc[i][2] += a * b.z;
        acc[i][3] += a * b.w;
      }
    }
    __syncthreads();
  }
#pragma unroll
  for (int i = 0; i < 4; ++i) {
    int row = rowBase + ty * 4 + i;
    if (row >= Nr) continue;
#pragma unroll
    for (int j = 0; j < 4; ++j) {
      int col = colBase + tx * 4 + j;
      if (col >= M) continue;
      float v = acc[i][j] + bias[col];
      if (do_relu) v = fmaxf(v, 0.f);
      Y[(size_t)row * (size_t)M + col] = v;
    }
  }
}

__global__ __launch_bounds__(256) void gemm_kernel(
    const float* __restrict__ X, const float* __restrict__ W,
    const float* __restrict__ bias, float* __restrict__ Y,
    int Nr, int K, int M, int do_relu)
{
  gemm_body(X, W, bias, Y, Nr, K, M, blockIdx.x * 64, blockIdx.y * 64, do_relu);
}

// ============ CSR build over dst ============
__global__ __launch_bounds__(256) void count_kernel(const int* __restrict__ dst, int* __restrict__ cnt)
{
  int e = blockIdx.x * 256 + threadIdx.x;
  if (e < NE) atomicAdd(&cnt[dst[e]], 1);
}

__global__ __launch_bounds__(1024) void scan_kernel(const int* __restrict__ cnt, int* __restrict__ row_start)
{
  __shared__ int sums[1024];
  int t = threadIdx.x;
  const int per = (NN + 1023) / 1024;
  int beg = t * per;
  int end = beg + per; if (end > NN) end = NN; if (beg > NN) beg = NN;
  int s = 0;
  for (int i = beg; i < end; ++i) s += cnt[i];
  sums[t] = s;
  __syncthreads();
  for (int off = 1; off < 1024; off <<= 1) {
    int v = (t >= off) ? sums[t - off] : 0;
    __syncthreads();
    sums[t] += v;
    __syncthreads();
  }
  int prefix = (t == 0) ? 0 : sums[t - 1];
  for (int i = beg; i < end; ++i) { row_start[i] = prefix; prefix += cnt[i]; }
  if (t == 1023) row_start[NN] = prefix;
}

__global__ __launch_bounds__(256) void scatter_kernel(
    const int* __restrict__ dst, const int* __restrict__ row_start,
    int* __restrict__ cursor, int* __restrict__ edge_list)
{
  int e = blockIdx.x * 256 + threadIdx.x;
  if (e < NE) {
    int d = dst[e];
    int p = atomicAdd(&cursor[d], 1);
    edge_list[row_start[d] + p] = e;
  }
}

// ============ edge attention scores (q/k live in packed qkvs, stride 2048) ============
__global__ __launch_bounds__(256) void edge_alpha_kernel(
    const float* __restrict__ qkvs,
    const int* __restrict__ src, const int* __restrict__ dst,
    float* __restrict__ alpha)
{
  int gw = (int)((blockIdx.x * 256u + threadIdx.x) >> 6);
  int lane = threadIdx.x & 63;
  if (gw >= NE) return;
  int s = src[gw], d = dst[gw];
  const float* qp = qkvs + (size_t)d * NQKVS;
  const float* kp = qkvs + (size_t)s * NQKVS + 512;
#pragma unroll
  for (int h = 0; h < 4; ++h) {
    float p = qp[h * 128 + lane] * kp[h * 128 + lane]
            + qp[h * 128 + 64 + lane] * kp[h * 128 + 64 + lane];
#pragma unroll
    for (int off = 32; off >= 1; off >>= 1) p += __shfl_xor(p, off);
    if (lane == 0) alpha[(size_t)gw * 4 + h] = p * ATT_SCALE;
  }
}

// ============ segment softmax per (node, head), in place ============
__global__ __launch_bounds__(256) void softmax_kernel(
    float* __restrict__ alpha, const int* __restrict__ row_start, const int* __restrict__ edge_list)
{
  int idx = blockIdx.x * 256 + threadIdx.x;
  if (idx >= NN * 4) return;
  int node = idx >> 2, h = idx & 3;
  int beg = row_start[node], end = row_start[node + 1];
  if (beg == end) return;
  float m = -INFINITY;
  for (int j = beg; j < end; ++j) m = fmaxf(m, alpha[(size_t)edge_list[j] * 4 + h]);
  float den = 0.f;
  for (int j = beg; j < end; ++j) den += expf(alpha[(size_t)edge_list[j] * 4 + h] - m);
  float inv = 1.f / fmaxf(den, 1e-16f);
  for (int j = beg; j < end; ++j) {
    size_t a = (size_t)edge_list[j] * 4 + h;
    alpha[a] = expf(alpha[a] - m) * inv;
  }
}

// ============ aggregate: t0 = skip + sum_e w[e,h]*v[src_e]; write bf16 hi/lo split ============
__global__ __launch_bounds__(256) void aggregate_kernel(
    const float* __restrict__ qkvs, const float* __restrict__ w,
    const int* __restrict__ src, const int* __restrict__ row_start,
    const int* __restrict__ edge_list,
    __hip_bfloat16* __restrict__ t0hi, __hip_bfloat16* __restrict__ t0lo)
{
  int node = blockIdx.x;
  int tid = threadIdx.x;
  int beg = row_start[node], end = row_start[node + 1];
  int c0 = tid, c1 = tid + 256;
  int h0 = c0 >> 7, h1 = c1 >> 7;
  float acc0 = 0.f, acc1 = 0.f;
  for (int j = beg; j < end; ++j) {
    int e = edge_list[j];
    int s = src[e];
    const float* vp = qkvs + (size_t)s * NQKVS + 1024;
    float w0 = w[(size_t)e * 4 + h0];
    float w1 = w[(size_t)e * 4 + h1];
    acc0 += w0 * vp[c0];
    acc1 += w1 * vp[c1];
  }
  const float* sp = qkvs + (size_t)node * NQKVS + 1536;
  float v0 = acc0 + sp[c0];
  float v1 = acc1 + sp[c1];
  size_t o = (size_t)node * HC;
  __hip_bfloat16 h0v = __float2bfloat16(v0);
  __hip_bfloat16 h1v = __float2bfloat16(v1);
  t0hi[o + c0] = h0v; t0lo[o + c0] = __float2bfloat16(v0 - __bfloat162float(h0v));
  t0hi[o + c1] = h1v; t0lo[o + c1] = __float2bfloat16(v1 - __bfloat162float(h1v));
}

// ============ pooling ============
__global__ __launch_bounds__(256) void pool_init_kernel(float* __restrict__ gm, float* __restrict__ gsum, int* __restrict__ gcnt)
{
  int i = blockIdx.x * 256 + threadIdx.x;
  if (i < NB * HD) { ((int*)gm)[i] = 0xFF800000; gsum[i] = 0.f; }
  if (i < NB) gcnt[i] = 0;
}

__global__ __launch_bounds__(256) void pool_kernel(
    const float* __restrict__ h, const int* __restrict__ batch,
    float* __restrict__ gm, float* __restrict__ gsum, int* __restrict__ gcnt)
{
  int idx = blockIdx.x * 256 + threadIdx.x;
  if (idx >= NN * HD) return;
  int node = idx >> 7, c = idx & 127;
  int b = batch[node];
  float val = h[idx];
  atomicMax((int*)&gm[(size_t)b * HD + c], __float_as_int(val));  // post-ReLU >= 0
  atomicAdd(&gsum[(size_t)b * HD + c], val);
  if (c == 0) atomicAdd(&gcnt[b], 1);
}

__global__ __launch_bounds__(256) void pool_finalize_kernel(
    const float* __restrict__ gm, const float* __restrict__ gsum,
    const int* __restrict__ gcnt, float* __restrict__ g)
{
  int idx = blockIdx.x * 256 + threadIdx.x;
  if (idx >= NB * HD) return;
  int b = idx >> 7, c = idx & 127;
  float m = gm[idx];
  if (m < -1e30f) m = 0.f;
  float cf = (float)gcnt[b];
  g[(size_t)b * 256 + c] = m;
  g[(size_t)b * 256 + 128 + c] = gsum[idx] / fmaxf(cf, 1.f);
}

extern "C" void kernel_launch(void* const* d_in, const int* in_sizes, int n_in,
                              void* d_out, int out_size, void* d_ws, size_t ws_size,
                              hipStream_t stream)
{
  const float* x = (const float*)d_in[0];
  const int* edge_index = (const int*)d_in[1];
  const int* batch = (const int*)d_in[2];
  const int* src = edge_index;
  const int* dstv = edge_index + NE;

  const float *Wq[3], *bq[3], *Wk[3], *bk[3], *Wv[3], *bv[3], *Wsk[3], *bsk[3], *Wm[3], *bm[3];
  int base = 3;
  for (int l = 0; l < 3; ++l) {
    Wq[l]  = (const float*)d_in[base + 0]; bq[l]  = (const float*)d_in[base + 1];
    Wk[l]  = (const float*)d_in[base + 2]; bk[l]  = (const float*)d_in[base + 3];
    Wv[l]  = (const float*)d_in[base + 4]; bv[l]  = (const float*)d_in[base + 5];
    Wsk[l] = (const float*)d_in[base + 6]; bsk[l] = (const float*)d_in[base + 7];
    Wm[l]  = (const float*)d_in[base + 8]; bm[l]  = (const float*)d_in[base + 9];
    base += 10;
  }
  const float* Wg1 = (const float*)d_in[33]; const float* bg1 = (const float*)d_in[34];
  const float* Wg2 = (const float*)d_in[35]; const float* bg2 = (const float*)d_in[36];
  const float* Wf1 = (const float*)d_in[37]; const float* bf1 = (const float*)d_in[38];
  const float* Wf2 = (const float*)d_in[39]; const float* bf2 = (const float*)d_in[40];

  // ---- workspace layout (bytes, 256B aligned chunks) ----
  char* p = (char*)d_ws;
  auto alloc = [&](size_t bytes) { char* r = p; p += (bytes + 255) & ~(size_t)255; return r; };
  float* qkvs = (float*)alloc((size_t)NN * NQKVS * 4);
  float* h    = (float*)alloc((size_t)NN * HD * 4);
  float* alph = (float*)alloc((size_t)NE * 4 * 4);
  __hip_bfloat16* t0hi = (__hip_bfloat16*)alloc((size_t)MPAD * HC * 2);
  __hip_bfloat16* t0lo = (__hip_bfloat16*)alloc((size_t)MPAD * HC * 2);
  __hip_bfloat16* hhi  = (__hip_bfloat16*)alloc((size_t)MPAD * HD * 2);
  __hip_bfloat16* hlo  = (__hip_bfloat16*)alloc((size_t)MPAD * HD * 2);
  __hip_bfloat16* xhi  = (__hip_bfloat16*)alloc((size_t)MPAD * 64 * 2);
  __hip_bfloat16* xlo  = (__hip_bfloat16*)alloc((size_t)MPAD * 64 * 2);
  __hip_bfloat16* Wphi = (__hip_bfloat16*)alloc((size_t)2048 * 128 * 2);
  __hip_bfloat16* Wplo = (__hip_bfloat16*)alloc((size_t)2048 * 128 * 2);
  __hip_bfloat16* Wmphi = (__hip_bfloat16*)alloc((size_t)128 * 512 * 2);
  __hip_bfloat16* Wmplo = (__hip_bfloat16*)alloc((size_t)128 * 512 * 2);
  float* bpack = (float*)alloc(2048 * 4);
  float* gm   = (float*)alloc((size_t)NB * HD * 4);
  float* gsum = (float*)alloc((size_t)NB * HD * 4);
  float* g    = (float*)alloc((size_t)NB * 256 * 4);
  float* g1   = (float*)alloc((size_t)NB * 1024 * 4);
  float* g2   = (float*)alloc((size_t)NB * 512 * 4);
  float* g3   = (float*)alloc((size_t)NB * 256 * 4);
  int* icnt      = (int*)alloc(NN * 4);
  int* cursor    = (int*)alloc(NN * 4);
  int* row_start = (int*)alloc((NN + 1) * 4);
  int* edge_list = (int*)alloc((size_t)NE * 4);
  int* gcnt      = (int*)alloc(NB * 4);

  const int GR128 = (NN + 127) / 128;  // 157

  // ---- CSR build ----
  hipMemsetAsync(icnt, 0, sizeof(int) * NN, stream);
  hipMemsetAsync(cursor, 0, sizeof(int) * NN, stream);
  count_kernel<<<(NE + 255) / 256, 256, 0, stream>>>(dstv, icnt);
  scan_kernel<<<1, 1024, 0, stream>>>(icnt, row_start);
  scatter_kernel<<<(NE + 255) / 256, 256, 0, stream>>>(dstv, row_start, cursor, edge_list);

  // ---- input split ----
  split_x_kernel<<<(NN * 64 + 255) / 256, 256, 0, stream>>>(x, xhi, xlo);

  // ---- 3 TransformerConv layers ----
  for (int l = 0; l < 3; ++l) {
    int K = (l == 0) ? FIN : HD;
    int Kpad = (l == 0) ? 64 : 128;
    const __hip_bfloat16* Ahi = (l == 0) ? xhi : hhi;
    const __hip_bfloat16* Alo = (l == 0) ? xlo : hlo;

    // pack weights (transposed, split)
    int pw = (512 * Kpad + 255) / 256;
    pack_w_kernel<<<pw, 256, 0, stream>>>(Wq[l],  K, Kpad, 512, 0,    Wphi, Wplo);
    pack_w_kernel<<<pw, 256, 0, stream>>>(Wk[l],  K, Kpad, 512, 512,  Wphi, Wplo);
    pack_w_kernel<<<pw, 256, 0, stream>>>(Wv[l],  K, Kpad, 512, 1024, Wphi, Wplo);
    pack_w_kernel<<<pw, 256, 0, stream>>>(Wsk[l], K, Kpad, 512, 1536, Wphi, Wplo);
    pack_bias4_kernel<<<8, 256, 0, stream>>>(bq[l], bk[l], bv[l], bsk[l], bpack);
    pack_w_kernel<<<(128 * 512 + 255) / 256, 256, 0, stream>>>(Wm[l], 512, 512, 128, 0, Wmphi, Wmplo);

    // fused q|k|v|skip GEMM -> qkvs [NN][2048]
    gemm_mfma_kernel<0, 0><<<dim3(GR128, 16), 256, 0, stream>>>(
        Ahi, Alo, Kpad, Wphi, Wplo, bpack, qkvs, NQKVS, nullptr, nullptr, NN, Kpad);

    edge_alpha_kernel<<<(NE + 3) / 4, 256, 0, stream>>>(qkvs, src, dstv, alph);
    softmax_kernel<<<(NN * 4 + 255) / 256, 256, 0, stream>>>(alph, row_start, edge_list);
    aggregate_kernel<<<NN, 256, 0, stream>>>(qkvs, alph, src, row_start, edge_list, t0hi, t0lo);

    // projection GEMM 512->128 + ReLU, write h fp32 + hi/lo split
    gemm_mfma_kernel<1, 1><<<dim3(GR128, 1), 256, 0, stream>>>(
        t0hi, t0lo, HC, Wmphi, Wmplo, bm[l], h, HD, hhi, hlo, NN, HC);
  }

  // ---- pooling ----
  pool_init_kernel<<<(NB * HD + 255) / 256, 256, 0, stream>>>(gm, gsum, gcnt);
  pool_kernel<<<(NN * HD + 255) / 256, 256, 0, stream>>>(h, batch, gm, gsum, gcnt);
  pool_finalize_kernel<<<(NB * HD + 255) / 256, 256, 0, stream>>>(gm, gsum, gcnt, g);

  // ---- MLP head (fp32) ----
  gemm_kernel<<<dim3((NB + 63) / 64, 16), 256, 0, stream>>>(g,  Wg1, bg1, g1, NB, 256,  1024, 1);
  gemm_kernel<<<dim3((NB + 63) / 64, 8),  256, 0, stream>>>(g1, Wg2, bg2, g2, NB, 1024, 512,  1);
  gemm_kernel<<<dim3((NB + 63) / 64, 4),  256, 0, stream>>>(g2, Wf1, bf1, g3, NB, 512,  256,  1);
  gemm_kernel<<<dim3((NB + 63) / 64, 1),  256, 0, stream>>>(g3, Wf2, bf2, (float*)d_out, NB, 256, 1, 0);
}

// Round 3
// 1173.765 us; speedup vs baseline: 1.7921x; 1.4806x over previous
//
#include <hip/hip_runtime.h>
#include <hip/hip_bf16.h>
#include <math.h>

#define NN 20000
#define MPAD 20096          // 157*128 row padding for MFMA staging
#define NE 320000
#define NB 512
#define FIN 43
#define HD 128
#define HC 512
#define NQKVS 2048
#define ATT_SCALE 0.08838834764831843f
#define CHUNK 512

typedef __attribute__((ext_vector_type(8))) short bf16x8v;
typedef __attribute__((ext_vector_type(4))) float f32x4v;

__device__ __forceinline__ void gload16(void* lds, const void* g) {
  __builtin_amdgcn_global_load_lds(
      (const __attribute__((address_space(1))) void*)g,
      (__attribute__((address_space(3))) void*)lds, 16, 0, 0);
}

// ============ split-bf16 MFMA GEMM: Y = (Ahi+Alo)@(Bhi+Blo)^approx + bias ============
// A: [M][ldA] bf16 hi/lo (row-major, rows padded to >= gridDim.x*128)
// B: [N][K] bf16 hi/lo  (TRANSPOSED weights: row n holds column n of original W)
// Y: fp32 [M][ldY]; optional bf16 hi/lo split outputs (same ldY)
template<int DO_RELU, int WRITE_SPLIT>
__global__ __launch_bounds__(256, 2) void gemm_mfma_kernel(
    const __hip_bfloat16* __restrict__ Ahi_, const __hip_bfloat16* __restrict__ Alo_, int ldA,
    const __hip_bfloat16* __restrict__ Bhi_, const __hip_bfloat16* __restrict__ Blo_,
    const float* __restrict__ bias,
    float* __restrict__ Y, int ldY,
    __hip_bfloat16* __restrict__ Yhi, __hip_bfloat16* __restrict__ Ylo,
    int M, int K)
{
  __shared__ short Ah[128 * 64], Al[128 * 64], Bh[128 * 64], Bl[128 * 64];
  const short* Ahi = (const short*)Ahi_;
  const short* Alo = (const short*)Alo_;
  const short* Bhi = (const short*)Bhi_;
  const short* Blo = (const short*)Blo_;
  const int tid = threadIdx.x;
  const int w = tid >> 6, lane = tid & 63;
  const int rowBase = blockIdx.x * 128, colBase = blockIdx.y * 128;
  const int srow = lane >> 3;                  // staging row within 8-row group
  const int sw = ((lane & 7) ^ srow) << 3;     // pre-swizzled k-chunk (elements)
  const int lr = lane & 15, lg = lane >> 4;
  const int wr = w >> 1, wc = w & 1;

  f32x4v acc[4][4];
#pragma unroll
  for (int m = 0; m < 4; ++m)
#pragma unroll
    for (int n = 0; n < 4; ++n) acc[m][n] = (f32x4v){0.f, 0.f, 0.f, 0.f};

  for (int k0 = 0; k0 < K; k0 += 64) {
    if (k0) __syncthreads();
#pragma unroll
    for (int t = 0; t < 4; ++t) {
      int r0 = w * 32 + t * 8;
      size_t arow = (size_t)(rowBase + r0 + srow) * ldA + k0 + sw;
      size_t brow = (size_t)(colBase + r0 + srow) * K + k0 + sw;
      gload16(&Ah[r0 * 64], Ahi + arow);
      gload16(&Al[r0 * 64], Alo + arow);
      gload16(&Bh[r0 * 64], Bhi + brow);
      gload16(&Bl[r0 * 64], Blo + brow);
    }
    __syncthreads();
#pragma unroll
    for (int kk = 0; kk < 2; ++kk) {
      bf16x8v ah[4], al[4], bh[4], bl[4];
      int cbase = ((kk * 4 + lg) ^ (lr & 7)) * 8;
#pragma unroll
      for (int m = 0; m < 4; ++m) {
        int idx = (wr * 64 + m * 16 + lr) * 64 + cbase;
        ah[m] = *(const bf16x8v*)&Ah[idx];
        al[m] = *(const bf16x8v*)&Al[idx];
      }
#pragma unroll
      for (int n = 0; n < 4; ++n) {
        int idx = (wc * 64 + n * 16 + lr) * 64 + cbase;
        bh[n] = *(const bf16x8v*)&Bh[idx];
        bl[n] = *(const bf16x8v*)&Bl[idx];
      }
#pragma unroll
      for (int m = 0; m < 4; ++m)
#pragma unroll
        for (int n = 0; n < 4; ++n) {
          acc[m][n] = __builtin_amdgcn_mfma_f32_16x16x32_bf16(ah[m], bh[n], acc[m][n], 0, 0, 0);
          acc[m][n] = __builtin_amdgcn_mfma_f32_16x16x32_bf16(ah[m], bl[n], acc[m][n], 0, 0, 0);
          acc[m][n] = __builtin_amdgcn_mfma_f32_16x16x32_bf16(al[m], bh[n], acc[m][n], 0, 0, 0);
        }
    }
  }
  // epilogue: C/D layout col=lane&15, row=(lane>>4)*4+reg (m89-verified)
#pragma unroll
  for (int m = 0; m < 4; ++m) {
#pragma unroll
    for (int n = 0; n < 4; ++n) {
      int col = colBase + wc * 64 + n * 16 + lr;
      float bb = bias[col];
#pragma unroll
      for (int r = 0; r < 4; ++r) {
        int row = rowBase + wr * 64 + m * 16 + lg * 4 + r;
        if (row < M) {
          float v = acc[m][n][r] + bb;
          if (DO_RELU) v = fmaxf(v, 0.f);
          Y[(size_t)row * ldY + col] = v;
          if (WRITE_SPLIT) {
            __hip_bfloat16 hv = __float2bfloat16(v);
            Yhi[(size_t)row * ldY + col] = hv;
            Ylo[(size_t)row * ldY + col] = __float2bfloat16(v - __bfloat162float(hv));
          }
        }
      }
    }
  }
}

// ============ pack everything in one launch ============
struct PackArgs {
  const float* W[12];     // [l*4 + {q,k,v,s}]  shape [K][512]
  const float* b[12];
  const float* Wm[3];     // [512][128]
  __hip_bfloat16 *Wp_hi[3], *Wp_lo[3];   // [2048][Kpad]  Kpad: 64,128,128
  __hip_bfloat16 *Wm_hi[3], *Wm_lo[3];   // [128][512]
  float* bpack;                           // [3][2048]
};

// segment boundaries (dest elements):
//  [0, 131072):        layer0 qkvs, Kpad=64, K=43
//  [131072, 655360):   layers1,2 qkvs, Kpad=K=128 (262144 each)
//  [655360, 851968):   proj l=0..2, [128][512] (65536 each)
//  [851968, 858112):   biases [3][2048]
__global__ __launch_bounds__(256) void pack_all_kernel(PackArgs a)
{
  int idx = blockIdx.x * 256 + threadIdx.x;
  if (idx < 131072) {
    int n = idx >> 6, k = idx & 63;
    int mat = n >> 9, nn = n & 511;
    float v = (k < FIN) ? a.W[mat][(size_t)k * 512 + nn] : 0.f;
    __hip_bfloat16 h = __float2bfloat16(v);
    a.Wp_hi[0][idx] = h;
    a.Wp_lo[0][idx] = __float2bfloat16(v - __bfloat162float(h));
  } else if (idx < 655360) {
    int rel = idx - 131072;
    int l = 1 + (rel >> 18);
    int r2 = rel & 262143;
    int n = r2 >> 7, k = r2 & 127;
    int mat = n >> 9, nn = n & 511;
    float v = a.W[l * 4 + mat][(size_t)k * 512 + nn];
    __hip_bfloat16 h = __float2bfloat16(v);
    a.Wp_hi[l][r2] = h;
    a.Wp_lo[l][r2] = __float2bfloat16(v - __bfloat162float(h));
  } else if (idx < 851968) {
    int rel = idx - 655360;
    int l = rel >> 16;
    int r2 = rel & 65535;
    int n = r2 >> 9, k = r2 & 511;
    float v = a.Wm[l][(size_t)k * 128 + n];
    __hip_bfloat16 h = __float2bfloat16(v);
    a.Wm_hi[l][r2] = h;
    a.Wm_lo[l][r2] = __float2bfloat16(v - __bfloat162float(h));
  } else if (idx < 858112) {
    int rel = idx - 851968;
    int l = rel >> 11, c = rel & 2047;
    a.bpack[rel] = a.b[l * 4 + (c >> 9)][c & 511];
  }
}

__global__ __launch_bounds__(256) void split_x_kernel(
    const float* __restrict__ x, __hip_bfloat16* __restrict__ hi, __hip_bfloat16* __restrict__ lo)
{
  int idx = blockIdx.x * 256 + threadIdx.x;
  if (idx >= NN * 64) return;
  int r = idx >> 6, c = idx & 63;
  float v = (c < FIN) ? x[(size_t)r * FIN + c] : 0.f;
  __hip_bfloat16 h = __float2bfloat16(v);
  hi[idx] = h;
  lo[idx] = __float2bfloat16(v - __bfloat162float(h));
}

// ============ CSR build over dst ============
__global__ __launch_bounds__(256) void count_kernel(const int* __restrict__ dst, int* __restrict__ cnt)
{
  int e = blockIdx.x * 256 + threadIdx.x;
  if (e < NE) atomicAdd(&cnt[dst[e]], 1);
}

__global__ __launch_bounds__(1024) void scan_kernel(const int* __restrict__ cnt, int* __restrict__ row_start)
{
  __shared__ int sums[1024];
  int t = threadIdx.x;
  const int per = (NN + 1023) / 1024;
  int beg = t * per;
  int end = beg + per; if (end > NN) end = NN; if (beg > NN) beg = NN;
  int s = 0;
  for (int i = beg; i < end; ++i) s += cnt[i];
  sums[t] = s;
  __syncthreads();
  for (int off = 1; off < 1024; off <<= 1) {
    int v = (t >= off) ? sums[t - off] : 0;
    __syncthreads();
    sums[t] += v;
    __syncthreads();
  }
  int prefix = (t == 0) ? 0 : sums[t - 1];
  for (int i = beg; i < end; ++i) { row_start[i] = prefix; prefix += cnt[i]; }
  if (t == 1023) row_start[NN] = prefix;
}

__global__ __launch_bounds__(256) void scatter_kernel(
    const int* __restrict__ dst, const int* __restrict__ row_start,
    int* __restrict__ cursor, int* __restrict__ edge_list)
{
  int e = blockIdx.x * 256 + threadIdx.x;
  if (e < NE) {
    int d = dst[e];
    int p = atomicAdd(&cursor[d], 1);
    edge_list[row_start[d] + p] = e;
  }
}

// ============ fused attention: alpha + online softmax + aggregate + skip + split ============
// One block per dst node; wave w owns head w (128 output cols, 2 per lane).
__global__ __launch_bounds__(256) void attn_kernel(
    const float* __restrict__ qkvs,
    const int* __restrict__ src, const int* __restrict__ row_start,
    const int* __restrict__ edge_list,
    __hip_bfloat16* __restrict__ t0hi, __hip_bfloat16* __restrict__ t0lo)
{
  __shared__ int ssrc[CHUNK];
  __shared__ float pex[CHUNK * 4];   // [j][head]
  const int node = blockIdx.x;
  const int w = threadIdx.x >> 6, lane = threadIdx.x & 63;
  const int beg = row_start[node], end = row_start[node + 1];

  const float* qp = qkvs + (size_t)node * NQKVS + w * 128;
  const float q0 = qp[lane], q1 = qp[64 + lane];

  float m = -INFINITY, den = 0.f, acc0 = 0.f, acc1 = 0.f;

  for (int c0 = beg; c0 < end; c0 += CHUNK) {
    int len = end - c0; if (len > CHUNK) len = CHUNK;
    __syncthreads();
    for (int i = threadIdx.x; i < len; i += 256)
      ssrc[i] = src[edge_list[c0 + i]];
    __syncthreads();
    // alpha per edge for this wave's head
    for (int j = 0; j < len; ++j) {
      const float* kp = qkvs + (size_t)ssrc[j] * NQKVS + 512 + w * 128;
      float p = q0 * kp[lane] + q1 * kp[64 + lane];
#pragma unroll
      for (int off = 32; off >= 1; off >>= 1) p += __shfl_xor(p, off);
      if (lane == 0) pex[j * 4 + w] = p * ATT_SCALE;
    }
    // online softmax update (wave-private head column of pex)
    float mloc = -INFINITY;
    for (int j = lane; j < len; j += 64) mloc = fmaxf(mloc, pex[j * 4 + w]);
#pragma unroll
    for (int off = 32; off >= 1; off >>= 1) mloc = fmaxf(mloc, __shfl_xor(mloc, off));
    float mnew = fmaxf(m, mloc);
    float scale = expf(m - mnew);    // first chunk: exp(-inf)=0
    acc0 *= scale; acc1 *= scale; den *= scale;
    float sloc = 0.f;
    for (int j = lane; j < len; j += 64) {
      float p = expf(pex[j * 4 + w] - mnew);
      pex[j * 4 + w] = p;
      sloc += p;
    }
#pragma unroll
    for (int off = 32; off >= 1; off >>= 1) sloc += __shfl_xor(sloc, off);
    den += sloc; m = mnew;
    // aggregate v
    for (int j = 0; j < len; ++j) {
      float p = pex[j * 4 + w];          // wave-uniform LDS read -> broadcast
      const float* vp = qkvs + (size_t)ssrc[j] * NQKVS + 1024 + w * 128;
      acc0 += p * vp[lane];
      acc1 += p * vp[64 + lane];
    }
  }

  float inv = 1.f / fmaxf(den, 1e-16f);
  const float* sp = qkvs + (size_t)node * NQKVS + 1536 + w * 128;
  float v0 = acc0 * inv + sp[lane];
  float v1 = acc1 * inv + sp[64 + lane];
  size_t o = (size_t)node * HC + w * 128;
  __hip_bfloat16 h0 = __float2bfloat16(v0);
  __hip_bfloat16 h1 = __float2bfloat16(v1);
  t0hi[o + lane] = h0;
  t0lo[o + lane] = __float2bfloat16(v0 - __bfloat162float(h0));
  t0hi[o + 64 + lane] = h1;
  t0lo[o + 64 + lane] = __float2bfloat16(v1 - __bfloat162float(h1));
}

// ============ pooling ============
__global__ __launch_bounds__(256) void pool_init_kernel(float* __restrict__ gm, float* __restrict__ gsum, int* __restrict__ gcnt)
{
  int i = blockIdx.x * 256 + threadIdx.x;
  if (i < NB * HD) { ((int*)gm)[i] = 0xFF800000; gsum[i] = 0.f; }
  if (i < NB) gcnt[i] = 0;
}

__global__ __launch_bounds__(256) void pool_kernel(
    const float* __restrict__ h, const int* __restrict__ batch,
    float* __restrict__ gm, float* __restrict__ gsum, int* __restrict__ gcnt)
{
  int idx = blockIdx.x * 256 + threadIdx.x;
  if (idx >= NN * HD) return;
  int node = idx >> 7, c = idx & 127;
  int b = batch[node];
  float val = h[idx];
  atomicMax((int*)&gm[(size_t)b * HD + c], __float_as_int(val));  // post-ReLU >= 0
  atomicAdd(&gsum[(size_t)b * HD + c], val);
  if (c == 0) atomicAdd(&gcnt[b], 1);
}

__global__ __launch_bounds__(256) void pool_finalize_kernel(
    const float* __restrict__ gm, const float* __restrict__ gsum,
    const int* __restrict__ gcnt, float* __restrict__ g)
{
  int idx = blockIdx.x * 256 + threadIdx.x;
  if (idx >= NB * HD) return;
  int b = idx >> 7, c = idx & 127;
  float mv = gm[idx];
  if (mv < -1e30f) mv = 0.f;
  float cf = (float)gcnt[b];
  g[(size_t)b * 256 + c] = mv;
  g[(size_t)b * 256 + 128 + c] = gsum[idx] / fmaxf(cf, 1.f);
}

// ============ fused MLP head: [512,256]->1024->512->256->1 ============
struct HeadW { const float *Wg1, *bg1, *Wg2, *bg2, *Wf1, *bf1, *Wf2, *bf2; };

__global__ __launch_bounds__(256) void head_kernel(
    const float* __restrict__ g, HeadW a, float* __restrict__ out)
{
  __shared__ float s0[4][256];
  __shared__ float s1[4][1024];
  __shared__ float s2[4][512];
  __shared__ float s3[4][256];
  const int r0 = blockIdx.x * 4;
  const int t = threadIdx.x;
  for (int i = t; i < 4 * 256; i += 256) s0[i >> 8][i & 255] = g[(size_t)r0 * 256 + i];
  __syncthreads();
  // L1: 256 -> 1024, relu (4 cols/thread x 4 rows)
  {
    float acc[4][4];
#pragma unroll
    for (int j = 0; j < 4; ++j) {
      float b = a.bg1[t + j * 256];
#pragma unroll
      for (int r = 0; r < 4; ++r) acc[r][j] = b;
    }
    for (int k = 0; k < 256; ++k) {
      float w0 = a.Wg1[(size_t)k * 1024 + t];
      float w1 = a.Wg1[(size_t)k * 1024 + t + 256];
      float w2 = a.Wg1[(size_t)k * 1024 + t + 512];
      float w3 = a.Wg1[(size_t)k * 1024 + t + 768];
#pragma unroll
      for (int r = 0; r < 4; ++r) {
        float s = s0[r][k];
        acc[r][0] += s * w0; acc[r][1] += s * w1; acc[r][2] += s * w2; acc[r][3] += s * w3;
      }
    }
#pragma unroll
    for (int r = 0; r < 4; ++r)
#pragma unroll
      for (int j = 0; j < 4; ++j) s1[r][t + j * 256] = fmaxf(acc[r][j], 0.f);
  }
  __syncthreads();
  // L2: 1024 -> 512, relu (2 cols/thread x 4 rows)
  {
    float acc[4][2];
#pragma unroll
    for (int j = 0; j < 2; ++j) {
      float b = a.bg2[t + j * 256];
#pragma unroll
      for (int r = 0; r < 4; ++r) acc[r][j] = b;
    }
    for (int k = 0; k < 1024; ++k) {
      float w0 = a.Wg2[(size_t)k * 512 + t];
      float w1 = a.Wg2[(size_t)k * 512 + t + 256];
#pragma unroll
      for (int r = 0; r < 4; ++r) {
        float s = s1[r][k];
        acc[r][0] += s * w0; acc[r][1] += s * w1;
      }
    }
#pragma unroll
    for (int r = 0; r < 4; ++r)
#pragma unroll
      for (int j = 0; j < 2; ++j) s2[r][t + j * 256] = fmaxf(acc[r][j], 0.f);
  }
  __syncthreads();
  // L3: 512 -> 256, relu (1 col/thread x 4 rows)
  {
    float b = a.bf1[t];
    float acc[4] = {b, b, b, b};
    for (int k = 0; k < 512; ++k) {
      float wv = a.Wf1[(size_t)k * 256 + t];
#pragma unroll
      for (int r = 0; r < 4; ++r) acc[r] += s2[r][k] * wv;
    }
#pragma unroll
    for (int r = 0; r < 4; ++r) s3[r][t] = fmaxf(acc[r], 0.f);
  }
  __syncthreads();
  // L4: 256 -> 1 (wave w handles row w)
  {
    int w = t >> 6, lane = t & 63;
    float p = s3[w][lane] * a.Wf2[lane]
            + s3[w][64 + lane] * a.Wf2[64 + lane]
            + s3[w][128 + lane] * a.Wf2[128 + lane]
            + s3[w][192 + lane] * a.Wf2[192 + lane];
#pragma unroll
    for (int off = 32; off >= 1; off >>= 1) p += __shfl_xor(p, off);
    if (lane == 0) out[r0 + w] = p + a.bf2[0];
  }
}

extern "C" void kernel_launch(void* const* d_in, const int* in_sizes, int n_in,
                              void* d_out, int out_size, void* d_ws, size_t ws_size,
                              hipStream_t stream)
{
  const float* x = (const float*)d_in[0];
  const int* edge_index = (const int*)d_in[1];
  const int* batch = (const int*)d_in[2];
  const int* src = edge_index;
  const int* dstv = edge_index + NE;

  const float *Wq[3], *bq[3], *Wk[3], *bk[3], *Wv[3], *bv[3], *Wsk[3], *bsk[3], *Wm[3], *bm[3];
  int base = 3;
  for (int l = 0; l < 3; ++l) {
    Wq[l]  = (const float*)d_in[base + 0]; bq[l]  = (const float*)d_in[base + 1];
    Wk[l]  = (const float*)d_in[base + 2]; bk[l]  = (const float*)d_in[base + 3];
    Wv[l]  = (const float*)d_in[base + 4]; bv[l]  = (const float*)d_in[base + 5];
    Wsk[l] = (const float*)d_in[base + 6]; bsk[l] = (const float*)d_in[base + 7];
    Wm[l]  = (const float*)d_in[base + 8]; bm[l]  = (const float*)d_in[base + 9];
    base += 10;
  }
  const float* Wg1 = (const float*)d_in[33]; const float* bg1 = (const float*)d_in[34];
  const float* Wg2 = (const float*)d_in[35]; const float* bg2 = (const float*)d_in[36];
  const float* Wf1 = (const float*)d_in[37]; const float* bf1 = (const float*)d_in[38];
  const float* Wf2 = (const float*)d_in[39]; const float* bf2 = (const float*)d_in[40];

  // ---- workspace layout ----
  char* p = (char*)d_ws;
  auto alloc = [&](size_t bytes) { char* r = p; p += (bytes + 255) & ~(size_t)255; return r; };
  float* qkvs = (float*)alloc((size_t)NN * NQKVS * 4);
  float* h    = (float*)alloc((size_t)NN * HD * 4);
  __hip_bfloat16* t0hi = (__hip_bfloat16*)alloc((size_t)MPAD * HC * 2);
  __hip_bfloat16* t0lo = (__hip_bfloat16*)alloc((size_t)MPAD * HC * 2);
  __hip_bfloat16* hhi  = (__hip_bfloat16*)alloc((size_t)MPAD * HD * 2);
  __hip_bfloat16* hlo  = (__hip_bfloat16*)alloc((size_t)MPAD * HD * 2);
  __hip_bfloat16* xhi  = (__hip_bfloat16*)alloc((size_t)MPAD * 64 * 2);
  __hip_bfloat16* xlo  = (__hip_bfloat16*)alloc((size_t)MPAD * 64 * 2);
  __hip_bfloat16* Wp_hi[3], *Wp_lo[3], *Wm_hi[3], *Wm_lo[3];
  Wp_hi[0] = (__hip_bfloat16*)alloc((size_t)2048 * 64 * 2);
  Wp_lo[0] = (__hip_bfloat16*)alloc((size_t)2048 * 64 * 2);
  for (int l = 1; l < 3; ++l) {
    Wp_hi[l] = (__hip_bfloat16*)alloc((size_t)2048 * 128 * 2);
    Wp_lo[l] = (__hip_bfloat16*)alloc((size_t)2048 * 128 * 2);
  }
  for (int l = 0; l < 3; ++l) {
    Wm_hi[l] = (__hip_bfloat16*)alloc((size_t)128 * 512 * 2);
    Wm_lo[l] = (__hip_bfloat16*)alloc((size_t)128 * 512 * 2);
  }
  float* bpack = (float*)alloc(3 * 2048 * 4);
  float* gm   = (float*)alloc((size_t)NB * HD * 4);
  float* gsum = (float*)alloc((size_t)NB * HD * 4);
  float* g    = (float*)alloc((size_t)NB * 256 * 4);
  int* icnt      = (int*)alloc(NN * 4);
  int* cursor    = (int*)alloc(NN * 4);
  int* row_start = (int*)alloc((NN + 1) * 4);
  int* edge_list = (int*)alloc((size_t)NE * 4);
  int* gcnt      = (int*)alloc(NB * 4);

  const int GR128 = (NN + 127) / 128;  // 157

  // ---- pack all weights/biases (one launch) ----
  PackArgs pa;
  for (int l = 0; l < 3; ++l) {
    pa.W[l * 4 + 0] = Wq[l];  pa.W[l * 4 + 1] = Wk[l];
    pa.W[l * 4 + 2] = Wv[l];  pa.W[l * 4 + 3] = Wsk[l];
    pa.b[l * 4 + 0] = bq[l];  pa.b[l * 4 + 1] = bk[l];
    pa.b[l * 4 + 2] = bv[l];  pa.b[l * 4 + 3] = bsk[l];
    pa.Wm[l] = Wm[l];
    pa.Wp_hi[l] = Wp_hi[l]; pa.Wp_lo[l] = Wp_lo[l];
    pa.Wm_hi[l] = Wm_hi[l]; pa.Wm_lo[l] = Wm_lo[l];
  }
  pa.bpack = bpack;
  pack_all_kernel<<<(858112 + 255) / 256, 256, 0, stream>>>(pa);

  // ---- CSR build ----
  hipMemsetAsync(icnt, 0, sizeof(int) * NN, stream);
  hipMemsetAsync(cursor, 0, sizeof(int) * NN, stream);
  count_kernel<<<(NE + 255) / 256, 256, 0, stream>>>(dstv, icnt);
  scan_kernel<<<1, 1024, 0, stream>>>(icnt, row_start);
  scatter_kernel<<<(NE + 255) / 256, 256, 0, stream>>>(dstv, row_start, cursor, edge_list);

  // ---- input split ----
  split_x_kernel<<<(NN * 64 + 255) / 256, 256, 0, stream>>>(x, xhi, xlo);

  // ---- 3 TransformerConv layers ----
  for (int l = 0; l < 3; ++l) {
    int Kpad = (l == 0) ? 64 : 128;
    const __hip_bfloat16* Ahi = (l == 0) ? xhi : hhi;
    const __hip_bfloat16* Alo = (l == 0) ? xlo : hlo;

    gemm_mfma_kernel<0, 0><<<dim3(GR128, 16), 256, 0, stream>>>(
        Ahi, Alo, Kpad, Wp_hi[l], Wp_lo[l], bpack + l * 2048, qkvs, NQKVS,
        nullptr, nullptr, NN, Kpad);

    attn_kernel<<<NN, 256, 0, stream>>>(qkvs, src, row_start, edge_list, t0hi, t0lo);

    gemm_mfma_kernel<1, 1><<<dim3(GR128, 1), 256, 0, stream>>>(
        t0hi, t0lo, HC, Wm_hi[l], Wm_lo[l], bm[l], h, HD, hhi, hlo, NN, HC);
  }

  // ---- pooling ----
  pool_init_kernel<<<(NB * HD + 255) / 256, 256, 0, stream>>>(gm, gsum, gcnt);
  pool_kernel<<<(NN * HD + 255) / 256, 256, 0, stream>>>(h, batch, gm, gsum, gcnt);
  pool_finalize_kernel<<<(NB * HD + 255) / 256, 256, 0, stream>>>(gm, gsum, gcnt, g);

  // ---- fused MLP head ----
  HeadW hw = {Wg1, bg1, Wg2, bg2, Wf1, bf1, Wf2, bf2};
  head_kernel<<<NB / 4, 256, 0, stream>>>(g, hw, (float*)d_out);
}

// Round 4
// 856.243 us; speedup vs baseline: 2.4567x; 1.3708x over previous
//
#include <hip/hip_runtime.h>
#include <hip/hip_bf16.h>
#include <hip/hip_fp16.h>
#include <math.h>

#define NN 20000
#define MPAD 20096          // 157*128 row padding for MFMA staging
#define NE 320000
#define NB 512
#define FIN 43
#define HD 128
#define HC 512
#define ATT_SCALE 0.08838834764831843f
#define CHUNK 512
#define PEXLD (CHUNK + 8)

typedef __attribute__((ext_vector_type(8))) short bf16x8v;
typedef __attribute__((ext_vector_type(4))) short s16x4;
typedef __attribute__((ext_vector_type(4))) float f32x4v;

__device__ __forceinline__ void gload16(void* lds, const void* g) {
  __builtin_amdgcn_global_load_lds(
      (const __attribute__((address_space(1))) void*)g,
      (__attribute__((address_space(3))) void*)lds, 16, 0, 0);
}

// ============ split-bf16 MFMA GEMM: Y = (Ahi+Alo)@(Bhi+Blo)^approx + bias ============
// MODE 1: proj  -> relu, fp32 Y [M][ldY], bf16 hi/lo split Yhi/Ylo
// MODE 2: qkvs  -> cols [0,512): fp32 Q -> Y[row*1024+col]
//                  cols [512,1536): fp16 K|V -> kvh[row*1024+col-512]
//                  cols [1536,2048): fp32 S -> Y[row*1024+col-1024]
template<int MODE>
__global__ __launch_bounds__(256, 2) void gemm_mfma_kernel(
    const __hip_bfloat16* __restrict__ Ahi_, const __hip_bfloat16* __restrict__ Alo_, int ldA,
    const __hip_bfloat16* __restrict__ Bhi_, const __hip_bfloat16* __restrict__ Blo_,
    const float* __restrict__ bias,
    float* __restrict__ Y, int ldY,
    __hip_bfloat16* __restrict__ Yhi, __hip_bfloat16* __restrict__ Ylo,
    __half* __restrict__ kvh,
    int M, int K)
{
  __shared__ short Ah[128 * 64], Al[128 * 64], Bh[128 * 64], Bl[128 * 64];
  const short* Ahi = (const short*)Ahi_;
  const short* Alo = (const short*)Alo_;
  const short* Bhi = (const short*)Bhi_;
  const short* Blo = (const short*)Blo_;
  const int tid = threadIdx.x;
  const int w = tid >> 6, lane = tid & 63;
  const int rowBase = blockIdx.x * 128, colBase = blockIdx.y * 128;
  const int srow = lane >> 3;                  // staging row within 8-row group
  const int sw = ((lane & 7) ^ srow) << 3;     // pre-swizzled k-chunk (elements)
  const int lr = lane & 15, lg = lane >> 4;
  const int wr = w >> 1, wc = w & 1;

  f32x4v acc[4][4];
#pragma unroll
  for (int m = 0; m < 4; ++m)
#pragma unroll
    for (int n = 0; n < 4; ++n) acc[m][n] = (f32x4v){0.f, 0.f, 0.f, 0.f};

  for (int k0 = 0; k0 < K; k0 += 64) {
    if (k0) __syncthreads();
#pragma unroll
    for (int t = 0; t < 4; ++t) {
      int r0 = w * 32 + t * 8;
      size_t arow = (size_t)(rowBase + r0 + srow) * ldA + k0 + sw;
      size_t brow = (size_t)(colBase + r0 + srow) * K + k0 + sw;
      gload16(&Ah[r0 * 64], Ahi + arow);
      gload16(&Al[r0 * 64], Alo + arow);
      gload16(&Bh[r0 * 64], Bhi + brow);
      gload16(&Bl[r0 * 64], Blo + brow);
    }
    __syncthreads();
#pragma unroll
    for (int kk = 0; kk < 2; ++kk) {
      bf16x8v ah[4], al[4], bh[4], bl[4];
      int cbase = ((kk * 4 + lg) ^ (lr & 7)) * 8;
#pragma unroll
      for (int m = 0; m < 4; ++m) {
        int idx = (wr * 64 + m * 16 + lr) * 64 + cbase;
        ah[m] = *(const bf16x8v*)&Ah[idx];
        al[m] = *(const bf16x8v*)&Al[idx];
      }
#pragma unroll
      for (int n = 0; n < 4; ++n) {
        int idx = (wc * 64 + n * 16 + lr) * 64 + cbase;
        bh[n] = *(const bf16x8v*)&Bh[idx];
        bl[n] = *(const bf16x8v*)&Bl[idx];
      }
#pragma unroll
      for (int m = 0; m < 4; ++m)
#pragma unroll
        for (int n = 0; n < 4; ++n) {
          acc[m][n] = __builtin_amdgcn_mfma_f32_16x16x32_bf16(ah[m], bh[n], acc[m][n], 0, 0, 0);
          acc[m][n] = __builtin_amdgcn_mfma_f32_16x16x32_bf16(ah[m], bl[n], acc[m][n], 0, 0, 0);
          acc[m][n] = __builtin_amdgcn_mfma_f32_16x16x32_bf16(al[m], bh[n], acc[m][n], 0, 0, 0);
        }
    }
  }
  // epilogue: C/D layout col=lane&15, row=(lane>>4)*4+reg (m89-verified)
#pragma unroll
  for (int m = 0; m < 4; ++m) {
#pragma unroll
    for (int n = 0; n < 4; ++n) {
      int col = colBase + wc * 64 + n * 16 + lr;
      float bb = bias[col];
#pragma unroll
      for (int r = 0; r < 4; ++r) {
        int row = rowBase + wr * 64 + m * 16 + lg * 4 + r;
        if (row < M) {
          float v = acc[m][n][r] + bb;
          if (MODE == 1) {
            v = fmaxf(v, 0.f);
            Y[(size_t)row * ldY + col] = v;
            __hip_bfloat16 hv = __float2bfloat16(v);
            Yhi[(size_t)row * ldY + col] = hv;
            Ylo[(size_t)row * ldY + col] = __float2bfloat16(v - __bfloat162float(hv));
          } else {
            if (col < 512)       Y[(size_t)row * 1024 + col] = v;
            else if (col < 1536) kvh[(size_t)row * 1024 + col - 512] = __float2half(v);
            else                 Y[(size_t)row * 1024 + col - 1024] = v;
          }
        }
      }
    }
  }
}

// ============ pack everything in one launch ============
struct PackArgs {
  const float* W[12];     // [l*4 + {q,k,v,s}]  shape [K][512]
  const float* b[12];
  const float* Wm[3];     // [512][128]
  __hip_bfloat16 *Wp_hi[3], *Wp_lo[3];   // [2048][Kpad]  Kpad: 64,128,128
  __hip_bfloat16 *Wm_hi[3], *Wm_lo[3];   // [128][512]
  float* bpack;                           // [3][2048]
};

__global__ __launch_bounds__(256) void pack_all_kernel(PackArgs a)
{
  int idx = blockIdx.x * 256 + threadIdx.x;
  if (idx < 131072) {
    int n = idx >> 6, k = idx & 63;
    int mat = n >> 9, nn = n & 511;
    float v = (k < FIN) ? a.W[mat][(size_t)k * 512 + nn] : 0.f;
    __hip_bfloat16 h = __float2bfloat16(v);
    a.Wp_hi[0][idx] = h;
    a.Wp_lo[0][idx] = __float2bfloat16(v - __bfloat162float(h));
  } else if (idx < 655360) {
    int rel = idx - 131072;
    int l = 1 + (rel >> 18);
    int r2 = rel & 262143;
    int n = r2 >> 7, k = r2 & 127;
    int mat = n >> 9, nn = n & 511;
    float v = a.W[l * 4 + mat][(size_t)k * 512 + nn];
    __hip_bfloat16 h = __float2bfloat16(v);
    a.Wp_hi[l][r2] = h;
    a.Wp_lo[l][r2] = __float2bfloat16(v - __bfloat162float(h));
  } else if (idx < 851968) {
    int rel = idx - 655360;
    int l = rel >> 16;
    int r2 = rel & 65535;
    int n = r2 >> 9, k = r2 & 511;
    float v = a.Wm[l][(size_t)k * 128 + n];
    __hip_bfloat16 h = __float2bfloat16(v);
    a.Wm_hi[l][r2] = h;
    a.Wm_lo[l][r2] = __float2bfloat16(v - __bfloat162float(h));
  } else if (idx < 858112) {
    int rel = idx - 851968;
    int l = rel >> 11, c = rel & 2047;
    a.bpack[rel] = a.b[l * 4 + (c >> 9)][c & 511];
  }
}

__global__ __launch_bounds__(256) void split_x_kernel(
    const float* __restrict__ x, __hip_bfloat16* __restrict__ hi, __hip_bfloat16* __restrict__ lo)
{
  int idx = blockIdx.x * 256 + threadIdx.x;
  if (idx >= NN * 64) return;
  int r = idx >> 6, c = idx & 63;
  float v = (c < FIN) ? x[(size_t)r * FIN + c] : 0.f;
  __hip_bfloat16 h = __float2bfloat16(v);
  hi[idx] = h;
  lo[idx] = __float2bfloat16(v - __bfloat162float(h));
}

// ============ CSR build over dst ============
__global__ __launch_bounds__(256) void count_kernel(const int* __restrict__ dst, int* __restrict__ cnt)
{
  int e = blockIdx.x * 256 + threadIdx.x;
  if (e < NE) atomicAdd(&cnt[dst[e]], 1);
}

__global__ __launch_bounds__(1024) void scan_kernel(const int* __restrict__ cnt, int* __restrict__ row_start)
{
  __shared__ int sums[1024];
  int t = threadIdx.x;
  const int per = (NN + 1023) / 1024;
  int beg = t * per;
  int end = beg + per; if (end > NN) end = NN; if (beg > NN) beg = NN;
  int s = 0;
  for (int i = beg; i < end; ++i) s += cnt[i];
  sums[t] = s;
  __syncthreads();
  for (int off = 1; off < 1024; off <<= 1) {
    int v = (t >= off) ? sums[t - off] : 0;
    __syncthreads();
    sums[t] += v;
    __syncthreads();
  }
  int prefix = (t == 0) ? 0 : sums[t - 1];
  for (int i = beg; i < end; ++i) { row_start[i] = prefix; prefix += cnt[i]; }
  if (t == 1023) row_start[NN] = prefix;
}

// edge_list stores the SRC NODE ID (not edge id) -> attn staging is coalesced
__global__ __launch_bounds__(256) void scatter_kernel(
    const int* __restrict__ src, const int* __restrict__ dst,
    const int* __restrict__ row_start,
    int* __restrict__ cursor, int* __restrict__ edge_list)
{
  int e = blockIdx.x * 256 + threadIdx.x;
  if (e < NE) {
    int d = dst[e];
    int p = atomicAdd(&cursor[d], 1);
    edge_list[row_start[d] + p] = src[e];
  }
}

// ============ fused attention: alpha + online softmax + aggregate + skip + split ============
// One block per dst node; wave w owns head w. Two 32-lane groups process 2 edges/iter.
__global__ __launch_bounds__(256) void attn_kernel(
    const float* __restrict__ qs, const __half* __restrict__ kvh,
    const int* __restrict__ row_start, const int* __restrict__ edge_list,
    __hip_bfloat16* __restrict__ t0hi, __hip_bfloat16* __restrict__ t0lo)
{
  __shared__ int ssrc[CHUNK];
  __shared__ float pex[4 * PEXLD];
  const int node = blockIdx.x;
  const int w = threadIdx.x >> 6, lane = threadIdx.x & 63;
  const int g = lane >> 5, sl = lane & 31;
  const int beg = row_start[node], end = row_start[node + 1];

  const float* qp = qs + (size_t)node * 1024 + w * 128 + 4 * sl;
  const float q0 = qp[0], q1 = qp[1], q2 = qp[2], q3 = qp[3];
  float* pw = pex + w * PEXLD;

  float m = -INFINITY, den = 0.f;
  float a0 = 0.f, a1 = 0.f, a2 = 0.f, a3 = 0.f;

  for (int c0 = beg; c0 < end; c0 += CHUNK) {
    int len = end - c0; if (len > CHUNK) len = CHUNK;
    __syncthreads();
    for (int i = threadIdx.x; i < len; i += 256)
      ssrc[i] = edge_list[c0 + i];
    __syncthreads();

    // alpha: two edges per iteration (one per 32-lane group)
    for (int j = 0; j < len; j += 2) {
      int jj = j + g;
      float p = 0.f;
      if (jj < len) {
        const __half* kp = kvh + (size_t)ssrc[jj] * 1024 + w * 128 + 4 * sl;
        float2 raw = *(const float2*)kp;
        float2 f01 = __half22float2(*(__half2*)&raw.x);
        float2 f23 = __half22float2(*(__half2*)&raw.y);
        p = q0 * f01.x + q1 * f01.y + q2 * f23.x + q3 * f23.y;
      }
#pragma unroll
      for (int off = 16; off >= 1; off >>= 1) p += __shfl_xor(p, off);
      if (sl == 0 && jj < len) pw[jj] = p * ATT_SCALE;
    }
    // online softmax update (wave-private pex column; no block barrier needed)
    float mloc = -INFINITY;
    for (int j = lane; j < len; j += 64) mloc = fmaxf(mloc, pw[j]);
#pragma unroll
    for (int off = 32; off >= 1; off >>= 1) mloc = fmaxf(mloc, __shfl_xor(mloc, off));
    float mnew = fmaxf(m, mloc);
    float scale = expf(m - mnew);    // first chunk: exp(-inf)=0
    a0 *= scale; a1 *= scale; a2 *= scale; a3 *= scale; den *= scale;
    float sloc = 0.f;
    for (int j = lane; j < len; j += 64) {
      float p = expf(pw[j] - mnew);
      pw[j] = p;
      sloc += p;
    }
#pragma unroll
    for (int off = 32; off >= 1; off >>= 1) sloc += __shfl_xor(sloc, off);
    den += sloc; m = mnew;

    // aggregate v: two edges per iteration
    for (int j = 0; j < len; j += 2) {
      int jj = j + g;
      if (jj < len) {
        float p = pw[jj];
        const __half* vp = kvh + (size_t)ssrc[jj] * 1024 + 512 + w * 128 + 4 * sl;
        float2 raw = *(const float2*)vp;
        float2 f01 = __half22float2(*(__half2*)&raw.x);
        float2 f23 = __half22float2(*(__half2*)&raw.y);
        a0 += p * f01.x; a1 += p * f01.y; a2 += p * f23.x; a3 += p * f23.y;
      }
    }
  }

  // combine the two 32-lane groups
  a0 += __shfl_xor(a0, 32);
  a1 += __shfl_xor(a1, 32);
  a2 += __shfl_xor(a2, 32);
  a3 += __shfl_xor(a3, 32);

  if (g == 0) {
    float inv = 1.f / fmaxf(den, 1e-16f);
    const float* sp = qs + (size_t)node * 1024 + 512 + w * 128 + 4 * sl;
    float v[4];
    v[0] = a0 * inv + sp[0];
    v[1] = a1 * inv + sp[1];
    v[2] = a2 * inv + sp[2];
    v[3] = a3 * inv + sp[3];
    s16x4 hi4, lo4;
#pragma unroll
    for (int i = 0; i < 4; ++i) {
      __hip_bfloat16 hv = __float2bfloat16(v[i]);
      __hip_bfloat16 lv = __float2bfloat16(v[i] - __bfloat162float(hv));
      hi4[i] = *(short*)&hv;
      lo4[i] = *(short*)&lv;
    }
    size_t o = (size_t)node * HC + w * 128 + 4 * sl;
    *(s16x4*)(t0hi + o) = hi4;
    *(s16x4*)(t0lo + o) = lo4;
  }
}

// ============ pooling ============
__global__ __launch_bounds__(256) void pool_init_kernel(float* __restrict__ gm, float* __restrict__ gsum, int* __restrict__ gcnt)
{
  int i = blockIdx.x * 256 + threadIdx.x;
  if (i < NB * HD) { ((int*)gm)[i] = 0xFF800000; gsum[i] = 0.f; }
  if (i < NB) gcnt[i] = 0;
}

__global__ __launch_bounds__(256) void pool_kernel(
    const float* __restrict__ h, const int* __restrict__ batch,
    float* __restrict__ gm, float* __restrict__ gsum, int* __restrict__ gcnt)
{
  int idx = blockIdx.x * 256 + threadIdx.x;
  if (idx >= NN * HD) return;
  int node = idx >> 7, c = idx & 127;
  int b = batch[node];
  float val = h[idx];
  atomicMax((int*)&gm[(size_t)b * HD + c], __float_as_int(val));  // post-ReLU >= 0
  atomicAdd(&gsum[(size_t)b * HD + c], val);
  if (c == 0) atomicAdd(&gcnt[b], 1);
}

__global__ __launch_bounds__(256) void pool_finalize_kernel(
    const float* __restrict__ gm, const float* __restrict__ gsum,
    const int* __restrict__ gcnt, float* __restrict__ g)
{
  int idx = blockIdx.x * 256 + threadIdx.x;
  if (idx >= NB * HD) return;
  int b = idx >> 7, c = idx & 127;
  float mv = gm[idx];
  if (mv < -1e30f) mv = 0.f;
  float cf = (float)gcnt[b];
  g[(size_t)b * 256 + c] = mv;
  g[(size_t)b * 256 + 128 + c] = gsum[idx] / fmaxf(cf, 1.f);
}

// ============ fused MLP head: [512,256]->1024->512->256->1 ============
struct HeadW { const float *Wg1, *bg1, *Wg2, *bg2, *Wf1, *bf1, *Wf2, *bf2; };

__global__ __launch_bounds__(256) void head_kernel(
    const float* __restrict__ g, HeadW a, float* __restrict__ out)
{
  __shared__ float s0[4][256];
  __shared__ float s1[4][1024];
  __shared__ float s2[4][512];
  __shared__ float s3[4][256];
  const int r0 = blockIdx.x * 4;
  const int t = threadIdx.x;
  for (int i = t; i < 4 * 256; i += 256) s0[i >> 8][i & 255] = g[(size_t)r0 * 256 + i];
  __syncthreads();
  {
    float acc[4][4];
#pragma unroll
    for (int j = 0; j < 4; ++j) {
      float b = a.bg1[t + j * 256];
#pragma unroll
      for (int r = 0; r < 4; ++r) acc[r][j] = b;
    }
    for (int k = 0; k < 256; ++k) {
      float w0 = a.Wg1[(size_t)k * 1024 + t];
      float w1 = a.Wg1[(size_t)k * 1024 + t + 256];
      float w2 = a.Wg1[(size_t)k * 1024 + t + 512];
      float w3 = a.Wg1[(size_t)k * 1024 + t + 768];
#pragma unroll
      for (int r = 0; r < 4; ++r) {
        float s = s0[r][k];
        acc[r][0] += s * w0; acc[r][1] += s * w1; acc[r][2] += s * w2; acc[r][3] += s * w3;
      }
    }
#pragma unroll
    for (int r = 0; r < 4; ++r)
#pragma unroll
      for (int j = 0; j < 4; ++j) s1[r][t + j * 256] = fmaxf(acc[r][j], 0.f);
  }
  __syncthreads();
  {
    float acc[4][2];
#pragma unroll
    for (int j = 0; j < 2; ++j) {
      float b = a.bg2[t + j * 256];
#pragma unroll
      for (int r = 0; r < 4; ++r) acc[r][j] = b;
    }
    for (int k = 0; k < 1024; ++k) {
      float w0 = a.Wg2[(size_t)k * 512 + t];
      float w1 = a.Wg2[(size_t)k * 512 + t + 256];
#pragma unroll
      for (int r = 0; r < 4; ++r) {
        float s = s1[r][k];
        acc[r][0] += s * w0; acc[r][1] += s * w1;
      }
    }
#pragma unroll
    for (int r = 0; r < 4; ++r)
#pragma unroll
      for (int j = 0; j < 2; ++j) s2[r][t + j * 256] = fmaxf(acc[r][j], 0.f);
  }
  __syncthreads();
  {
    float b = a.bf1[t];
    float acc[4] = {b, b, b, b};
    for (int k = 0; k < 512; ++k) {
      float wv = a.Wf1[(size_t)k * 256 + t];
#pragma unroll
      for (int r = 0; r < 4; ++r) acc[r] += s2[r][k] * wv;
    }
#pragma unroll
    for (int r = 0; r < 4; ++r) s3[r][t] = fmaxf(acc[r], 0.f);
  }
  __syncthreads();
  {
    int w = t >> 6, lane = t & 63;
    float p = s3[w][lane] * a.Wf2[lane]
            + s3[w][64 + lane] * a.Wf2[64 + lane]
            + s3[w][128 + lane] * a.Wf2[128 + lane]
            + s3[w][192 + lane] * a.Wf2[192 + lane];
#pragma unroll
    for (int off = 32; off >= 1; off >>= 1) p += __shfl_xor(p, off);
    if (lane == 0) out[r0 + w] = p + a.bf2[0];
  }
}

extern "C" void kernel_launch(void* const* d_in, const int* in_sizes, int n_in,
                              void* d_out, int out_size, void* d_ws, size_t ws_size,
                              hipStream_t stream)
{
  const float* x = (const float*)d_in[0];
  const int* edge_index = (const int*)d_in[1];
  const int* batch = (const int*)d_in[2];
  const int* src = edge_index;
  const int* dstv = edge_index + NE;

  const float *Wq[3], *bq[3], *Wk[3], *bk[3], *Wv[3], *bv[3], *Wsk[3], *bsk[3], *Wm[3], *bm[3];
  int base = 3;
  for (int l = 0; l < 3; ++l) {
    Wq[l]  = (const float*)d_in[base + 0]; bq[l]  = (const float*)d_in[base + 1];
    Wk[l]  = (const float*)d_in[base + 2]; bk[l]  = (const float*)d_in[base + 3];
    Wv[l]  = (const float*)d_in[base + 4]; bv[l]  = (const float*)d_in[base + 5];
    Wsk[l] = (const float*)d_in[base + 6]; bsk[l] = (const float*)d_in[base + 7];
    Wm[l]  = (const float*)d_in[base + 8]; bm[l]  = (const float*)d_in[base + 9];
    base += 10;
  }
  const float* Wg1 = (const float*)d_in[33]; const float* bg1 = (const float*)d_in[34];
  const float* Wg2 = (const float*)d_in[35]; const float* bg2 = (const float*)d_in[36];
  const float* Wf1 = (const float*)d_in[37]; const float* bf1 = (const float*)d_in[38];
  const float* Wf2 = (const float*)d_in[39]; const float* bf2 = (const float*)d_in[40];

  // ---- workspace layout ----
  char* p = (char*)d_ws;
  auto alloc = [&](size_t bytes) { char* r = p; p += (bytes + 255) & ~(size_t)255; return r; };
  float* qs   = (float*)alloc((size_t)MPAD * 1024 * 4);    // Q | S  fp32
  __half* kvh = (__half*)alloc((size_t)MPAD * 1024 * 2);   // K | V  fp16
  float* h    = (float*)alloc((size_t)NN * HD * 4);
  __hip_bfloat16* t0hi = (__hip_bfloat16*)alloc((size_t)MPAD * HC * 2);
  __hip_bfloat16* t0lo = (__hip_bfloat16*)alloc((size_t)MPAD * HC * 2);
  __hip_bfloat16* hhi  = (__hip_bfloat16*)alloc((size_t)MPAD * HD * 2);
  __hip_bfloat16* hlo  = (__hip_bfloat16*)alloc((size_t)MPAD * HD * 2);
  __hip_bfloat16* xhi  = (__hip_bfloat16*)alloc((size_t)MPAD * 64 * 2);
  __hip_bfloat16* xlo  = (__hip_bfloat16*)alloc((size_t)MPAD * 64 * 2);
  __hip_bfloat16* Wp_hi[3], *Wp_lo[3], *Wm_hi[3], *Wm_lo[3];
  Wp_hi[0] = (__hip_bfloat16*)alloc((size_t)2048 * 64 * 2);
  Wp_lo[0] = (__hip_bfloat16*)alloc((size_t)2048 * 64 * 2);
  for (int l = 1; l < 3; ++l) {
    Wp_hi[l] = (__hip_bfloat16*)alloc((size_t)2048 * 128 * 2);
    Wp_lo[l] = (__hip_bfloat16*)alloc((size_t)2048 * 128 * 2);
  }
  for (int l = 0; l < 3; ++l) {
    Wm_hi[l] = (__hip_bfloat16*)alloc((size_t)128 * 512 * 2);
    Wm_lo[l] = (__hip_bfloat16*)alloc((size_t)128 * 512 * 2);
  }
  float* bpack = (float*)alloc(3 * 2048 * 4);
  float* gm   = (float*)alloc((size_t)NB * HD * 4);
  float* gsum = (float*)alloc((size_t)NB * HD * 4);
  float* g    = (float*)alloc((size_t)NB * 256 * 4);
  int* icnt      = (int*)alloc(NN * 4);
  int* cursor    = (int*)alloc(NN * 4);
  int* row_start = (int*)alloc((NN + 1) * 4);
  int* edge_list = (int*)alloc((size_t)NE * 4);
  int* gcnt      = (int*)alloc(NB * 4);

  const int GR128 = (NN + 127) / 128;  // 157

  // ---- pack all weights/biases (one launch) ----
  PackArgs pa;
  for (int l = 0; l < 3; ++l) {
    pa.W[l * 4 + 0] = Wq[l];  pa.W[l * 4 + 1] = Wk[l];
    pa.W[l * 4 + 2] = Wv[l];  pa.W[l * 4 + 3] = Wsk[l];
    pa.b[l * 4 + 0] = bq[l];  pa.b[l * 4 + 1] = bk[l];
    pa.b[l * 4 + 2] = bv[l];  pa.b[l * 4 + 3] = bsk[l];
    pa.Wm[l] = Wm[l];
    pa.Wp_hi[l] = Wp_hi[l]; pa.Wp_lo[l] = Wp_lo[l];
    pa.Wm_hi[l] = Wm_hi[l]; pa.Wm_lo[l] = Wm_lo[l];
  }
  pa.bpack = bpack;
  pack_all_kernel<<<(858112 + 255) / 256, 256, 0, stream>>>(pa);

  // ---- CSR build ----
  hipMemsetAsync(icnt, 0, sizeof(int) * NN, stream);
  hipMemsetAsync(cursor, 0, sizeof(int) * NN, stream);
  count_kernel<<<(NE + 255) / 256, 256, 0, stream>>>(dstv, icnt);
  scan_kernel<<<1, 1024, 0, stream>>>(icnt, row_start);
  scatter_kernel<<<(NE + 255) / 256, 256, 0, stream>>>(src, dstv, row_start, cursor, edge_list);

  // ---- input split ----
  split_x_kernel<<<(NN * 64 + 255) / 256, 256, 0, stream>>>(x, xhi, xlo);

  // ---- 3 TransformerConv layers ----
  for (int l = 0; l < 3; ++l) {
    int Kpad = (l == 0) ? 64 : 128;
    const __hip_bfloat16* Ahi = (l == 0) ? xhi : hhi;
    const __hip_bfloat16* Alo = (l == 0) ? xlo : hlo;

    gemm_mfma_kernel<2><<<dim3(GR128, 16), 256, 0, stream>>>(
        Ahi, Alo, Kpad, Wp_hi[l], Wp_lo[l], bpack + l * 2048, qs, 1024,
        nullptr, nullptr, kvh, NN, Kpad);

    attn_kernel<<<NN, 256, 0, stream>>>(qs, kvh, row_start, edge_list, t0hi, t0lo);

    gemm_mfma_kernel<1><<<dim3(GR128, 1), 256, 0, stream>>>(
        t0hi, t0lo, HC, Wm_hi[l], Wm_lo[l], bm[l], h, HD, hhi, hlo, nullptr, NN, HC);
  }

  // ---- pooling ----
  pool_init_kernel<<<(NB * HD + 255) / 256, 256, 0, stream>>>(gm, gsum, gcnt);
  pool_kernel<<<(NN * HD + 255) / 256, 256, 0, stream>>>(h, batch, gm, gsum, gcnt);
  pool_finalize_kernel<<<(NB * HD + 255) / 256, 256, 0, stream>>>(gm, gsum, gcnt, g);

  // ---- fused MLP head ----
  HeadW hw = {Wg1, bg1, Wg2, bg2, Wf1, bf1, Wf2, bf2};
  head_kernel<<<NB / 4, 256, 0, stream>>>(g, hw, (float*)d_out);
}

// Round 5
// 779.593 us; speedup vs baseline: 2.6983x; 1.0983x over previous
//
#include <hip/hip_runtime.h>
#include <hip/hip_bf16.h>
#include <hip/hip_fp16.h>
#include <math.h>

#define NN 20000
#define MPAD 20096          // 157*128 row padding for MFMA staging
#define NE 320000
#define NB 512
#define FIN 43
#define HD 128
#define HC 512
#define ATT_SCALE 0.08838834764831843f
#define CHUNK 512
#define PEXLD (CHUNK + 8)

typedef __attribute__((ext_vector_type(8))) short bf16x8v;
typedef __attribute__((ext_vector_type(8))) short short8v;
typedef __attribute__((ext_vector_type(4))) float f32x4v;
typedef _Float16 half2_t __attribute__((ext_vector_type(2)));

__device__ __forceinline__ void gload16(void* lds, const void* g) {
  __builtin_amdgcn_global_load_lds(
      (const __attribute__((address_space(1))) void*)g,
      (__attribute__((address_space(3))) void*)lds, 16, 0, 0);
}

__device__ __forceinline__ float dot2acc(half2_t a, half2_t b, float c) {
#if __has_builtin(__builtin_amdgcn_fdot2)
  return __builtin_amdgcn_fdot2(a, b, c, false);
#else
  return c + (float)a[0] * (float)b[0] + (float)a[1] * (float)b[1];
#endif
}

// ============ split-bf16 MFMA GEMM: Y = (Ahi+Alo)@(Bhi+Blo)^approx + bias ============
// MODE 1: relu, fp32 Y [M][ldY], bf16 hi/lo split Yhi/Ylo (proj + head layers)
// MODE 2: qkvs  -> cols [0,512): fp32 Q -> Y[row*1024+col]
//                  cols [512,1536): fp16 K|V -> kvh[row*1024+col-512]
//                  cols [1536,2048): fp32 S -> Y[row*1024+col-1024]
template<int MODE>
__global__ __launch_bounds__(256, 2) void gemm_mfma_kernel(
    const __hip_bfloat16* __restrict__ Ahi_, const __hip_bfloat16* __restrict__ Alo_, int ldA,
    const __hip_bfloat16* __restrict__ Bhi_, const __hip_bfloat16* __restrict__ Blo_,
    const float* __restrict__ bias,
    float* __restrict__ Y, int ldY,
    __hip_bfloat16* __restrict__ Yhi, __hip_bfloat16* __restrict__ Ylo,
    __half* __restrict__ kvh,
    int M, int K)
{
  __shared__ short Ah[128 * 64], Al[128 * 64], Bh[128 * 64], Bl[128 * 64];
  const short* Ahi = (const short*)Ahi_;
  const short* Alo = (const short*)Alo_;
  const short* Bhi = (const short*)Bhi_;
  const short* Blo = (const short*)Blo_;
  const int tid = threadIdx.x;
  const int w = tid >> 6, lane = tid & 63;
  const int rowBase = blockIdx.x * 128, colBase = blockIdx.y * 128;
  const int srow = lane >> 3;                  // staging row within 8-row group
  const int sw = ((lane & 7) ^ srow) << 3;     // pre-swizzled k-chunk (elements)
  const int lr = lane & 15, lg = lane >> 4;
  const int wr = w >> 1, wc = w & 1;

  f32x4v acc[4][4];
#pragma unroll
  for (int m = 0; m < 4; ++m)
#pragma unroll
    for (int n = 0; n < 4; ++n) acc[m][n] = (f32x4v){0.f, 0.f, 0.f, 0.f};

  for (int k0 = 0; k0 < K; k0 += 64) {
    if (k0) __syncthreads();
#pragma unroll
    for (int t = 0; t < 4; ++t) {
      int r0 = w * 32 + t * 8;
      size_t arow = (size_t)(rowBase + r0 + srow) * ldA + k0 + sw;
      size_t brow = (size_t)(colBase + r0 + srow) * K + k0 + sw;
      gload16(&Ah[r0 * 64], Ahi + arow);
      gload16(&Al[r0 * 64], Alo + arow);
      gload16(&Bh[r0 * 64], Bhi + brow);
      gload16(&Bl[r0 * 64], Blo + brow);
    }
    __syncthreads();
#pragma unroll
    for (int kk = 0; kk < 2; ++kk) {
      bf16x8v ah[4], al[4], bh[4], bl[4];
      int cbase = ((kk * 4 + lg) ^ (lr & 7)) * 8;
#pragma unroll
      for (int m = 0; m < 4; ++m) {
        int idx = (wr * 64 + m * 16 + lr) * 64 + cbase;
        ah[m] = *(const bf16x8v*)&Ah[idx];
        al[m] = *(const bf16x8v*)&Al[idx];
      }
#pragma unroll
      for (int n = 0; n < 4; ++n) {
        int idx = (wc * 64 + n * 16 + lr) * 64 + cbase;
        bh[n] = *(const bf16x8v*)&Bh[idx];
        bl[n] = *(const bf16x8v*)&Bl[idx];
      }
#pragma unroll
      for (int m = 0; m < 4; ++m)
#pragma unroll
        for (int n = 0; n < 4; ++n) {
          acc[m][n] = __builtin_amdgcn_mfma_f32_16x16x32_bf16(ah[m], bh[n], acc[m][n], 0, 0, 0);
          acc[m][n] = __builtin_amdgcn_mfma_f32_16x16x32_bf16(ah[m], bl[n], acc[m][n], 0, 0, 0);
          acc[m][n] = __builtin_amdgcn_mfma_f32_16x16x32_bf16(al[m], bh[n], acc[m][n], 0, 0, 0);
        }
    }
  }
  // epilogue: C/D layout col=lane&15, row=(lane>>4)*4+reg (m89-verified)
#pragma unroll
  for (int m = 0; m < 4; ++m) {
#pragma unroll
    for (int n = 0; n < 4; ++n) {
      int col = colBase + wc * 64 + n * 16 + lr;
      float bb = bias[col];
#pragma unroll
      for (int r = 0; r < 4; ++r) {
        int row = rowBase + wr * 64 + m * 16 + lg * 4 + r;
        if (row < M) {
          float v = acc[m][n][r] + bb;
          if (MODE == 1) {
            v = fmaxf(v, 0.f);
            Y[(size_t)row * ldY + col] = v;
            __hip_bfloat16 hv = __float2bfloat16(v);
            Yhi[(size_t)row * ldY + col] = hv;
            Ylo[(size_t)row * ldY + col] = __float2bfloat16(v - __bfloat162float(hv));
          } else {
            if (col < 512)       Y[(size_t)row * 1024 + col] = v;
            else if (col < 1536) kvh[(size_t)row * 1024 + col - 512] = __float2half(v);
            else                 Y[(size_t)row * 1024 + col - 1024] = v;
          }
        }
      }
    }
  }
}

// ============ pack everything in one launch ============
struct PackArgs {
  const float* W[12];     // [l*4 + {q,k,v,s}]  shape [K][512]
  const float* b[12];
  const float* Wm[3];     // [512][128]
  const float *Wg1, *Wg2, *Wf1;           // head weights
  __hip_bfloat16 *Wp_hi[3], *Wp_lo[3];   // [2048][Kpad]  Kpad: 64,128,128
  __hip_bfloat16 *Wm_hi[3], *Wm_lo[3];   // [128][512]
  __hip_bfloat16 *Wg1_hi, *Wg1_lo;       // [1024][256]
  __hip_bfloat16 *Wg2_hi, *Wg2_lo;       // [512][1024]
  __hip_bfloat16 *Wf1_hi, *Wf1_lo;       // [256][512]
  float* bpack;                           // [3][2048]
};

// segment boundaries (dest elements):
//  [0, 131072):          layer0 qkvs, Kpad=64, K=43
//  [131072, 655360):     layers1,2 qkvs, Kpad=K=128 (262144 each)
//  [655360, 851968):     proj l=0..2, [128][512] (65536 each)
//  [851968, 858112):     biases [3][2048]
//  [858112, 1120256):    Wg1^T [1024][256]
//  [1120256, 1644544):   Wg2^T [512][1024]
//  [1644544, 1775616):   Wf1^T [256][512]
__global__ __launch_bounds__(256) void pack_all_kernel(PackArgs a)
{
  int idx = blockIdx.x * 256 + threadIdx.x;
  if (idx < 131072) {
    int n = idx >> 6, k = idx & 63;
    int mat = n >> 9, nn = n & 511;
    float v = (k < FIN) ? a.W[mat][(size_t)k * 512 + nn] : 0.f;
    __hip_bfloat16 h = __float2bfloat16(v);
    a.Wp_hi[0][idx] = h;
    a.Wp_lo[0][idx] = __float2bfloat16(v - __bfloat162float(h));
  } else if (idx < 655360) {
    int rel = idx - 131072;
    int l = 1 + (rel >> 18);
    int r2 = rel & 262143;
    int n = r2 >> 7, k = r2 & 127;
    int mat = n >> 9, nn = n & 511;
    float v = a.W[l * 4 + mat][(size_t)k * 512 + nn];
    __hip_bfloat16 h = __float2bfloat16(v);
    a.Wp_hi[l][r2] = h;
    a.Wp_lo[l][r2] = __float2bfloat16(v - __bfloat162float(h));
  } else if (idx < 851968) {
    int rel = idx - 655360;
    int l = rel >> 16;
    int r2 = rel & 65535;
    int n = r2 >> 9, k = r2 & 511;
    float v = a.Wm[l][(size_t)k * 128 + n];
    __hip_bfloat16 h = __float2bfloat16(v);
    a.Wm_hi[l][r2] = h;
    a.Wm_lo[l][r2] = __float2bfloat16(v - __bfloat162float(h));
  } else if (idx < 858112) {
    int rel = idx - 851968;
    int l = rel >> 11, c = rel & 2047;
    a.bpack[rel] = a.b[l * 4 + (c >> 9)][c & 511];
  } else if (idx < 1120256) {
    int rel = idx - 858112;
    int n = rel >> 8, k = rel & 255;
    float v = a.Wg1[(size_t)k * 1024 + n];
    __hip_bfloat16 h = __float2bfloat16(v);
    a.Wg1_hi[rel] = h;
    a.Wg1_lo[rel] = __float2bfloat16(v - __bfloat162float(h));
  } else if (idx < 1644544) {
    int rel = idx - 1120256;
    int n = rel >> 10, k = rel & 1023;
    float v = a.Wg2[(size_t)k * 512 + n];
    __hip_bfloat16 h = __float2bfloat16(v);
    a.Wg2_hi[rel] = h;
    a.Wg2_lo[rel] = __float2bfloat16(v - __bfloat162float(h));
  } else if (idx < 1775616) {
    int rel = idx - 1644544;
    int n = rel >> 9, k = rel & 511;
    float v = a.Wf1[(size_t)k * 256 + n];
    __hip_bfloat16 h = __float2bfloat16(v);
    a.Wf1_hi[rel] = h;
    a.Wf1_lo[rel] = __float2bfloat16(v - __bfloat162float(h));
  }
}

__global__ __launch_bounds__(256) void split_x_kernel(
    const float* __restrict__ x, __hip_bfloat16* __restrict__ hi, __hip_bfloat16* __restrict__ lo)
{
  int idx = blockIdx.x * 256 + threadIdx.x;
  if (idx >= NN * 64) return;
  int r = idx >> 6, c = idx & 63;
  float v = (c < FIN) ? x[(size_t)r * FIN + c] : 0.f;
  __hip_bfloat16 h = __float2bfloat16(v);
  hi[idx] = h;
  lo[idx] = __float2bfloat16(v - __bfloat162float(h));
}

// ============ CSR build over dst ============
__global__ __launch_bounds__(256) void count_kernel(const int* __restrict__ dst, int* __restrict__ cnt)
{
  int e = blockIdx.x * 256 + threadIdx.x;
  if (e < NE) atomicAdd(&cnt[dst[e]], 1);
}

__global__ __launch_bounds__(1024) void scan_kernel(const int* __restrict__ cnt, int* __restrict__ row_start)
{
  __shared__ int sums[1024];
  int t = threadIdx.x;
  const int per = (NN + 1023) / 1024;
  int beg = t * per;
  int end = beg + per; if (end > NN) end = NN; if (beg > NN) beg = NN;
  int s = 0;
  for (int i = beg; i < end; ++i) s += cnt[i];
  sums[t] = s;
  __syncthreads();
  for (int off = 1; off < 1024; off <<= 1) {
    int v = (t >= off) ? sums[t - off] : 0;
    __syncthreads();
    sums[t] += v;
    __syncthreads();
  }
  int prefix = (t == 0) ? 0 : sums[t - 1];
  for (int i = beg; i < end; ++i) { row_start[i] = prefix; prefix += cnt[i]; }
  if (t == 1023) row_start[NN] = prefix;
}

// edge_list stores the SRC NODE ID (not edge id) -> attn staging is coalesced
__global__ __launch_bounds__(256) void scatter_kernel(
    const int* __restrict__ src, const int* __restrict__ dst,
    const int* __restrict__ row_start,
    int* __restrict__ cursor, int* __restrict__ edge_list)
{
  int e = blockIdx.x * 256 + threadIdx.x;
  if (e < NE) {
    int d = dst[e];
    int p = atomicAdd(&cursor[d], 1);
    edge_list[row_start[d] + p] = src[e];
  }
}

// ============ fused attention: alpha + online softmax + aggregate + skip + split ============
// One block per dst node; wave w owns head w. Four 16-lane subgroups -> 4 edges/iter.
__global__ __launch_bounds__(256) void attn_kernel(
    const float* __restrict__ qs, const __half* __restrict__ kvh,
    const int* __restrict__ row_start, const int* __restrict__ edge_list,
    __hip_bfloat16* __restrict__ t0hi, __hip_bfloat16* __restrict__ t0lo)
{
  __shared__ int ssrc[CHUNK];
  __shared__ float pex[4 * PEXLD];
  const int node = blockIdx.x;
  const int w = threadIdx.x >> 6, lane = threadIdx.x & 63;
  const int g4 = lane >> 4, sl = lane & 15;
  const int beg = row_start[node], end = row_start[node + 1];

  const float* qp = qs + (size_t)node * 1024 + w * 128 + 8 * sl;
  half2_t qh[4];
  {
    float4 qa = *(const float4*)qp;
    float4 qb = *(const float4*)(qp + 4);
    qh[0] = (half2_t){(_Float16)qa.x, (_Float16)qa.y};
    qh[1] = (half2_t){(_Float16)qa.z, (_Float16)qa.w};
    qh[2] = (half2_t){(_Float16)qb.x, (_Float16)qb.y};
    qh[3] = (half2_t){(_Float16)qb.z, (_Float16)qb.w};
  }
  float* pw = pex + w * PEXLD;

  float m = -INFINITY, den = 0.f;
  float a[8] = {0.f, 0.f, 0.f, 0.f, 0.f, 0.f, 0.f, 0.f};

  for (int c0 = beg; c0 < end; c0 += CHUNK) {
    int len = end - c0; if (len > CHUNK) len = CHUNK;
    __syncthreads();
    for (int i = threadIdx.x; i < len; i += 256)
      ssrc[i] = edge_list[c0 + i];
    __syncthreads();

    // alpha: four edges per iteration (one per 16-lane subgroup)
    for (int j = 0; j < len; j += 4) {
      int jj = j + g4;
      float p = 0.f;
      if (jj < len) {
        const __half* kp = kvh + (size_t)ssrc[jj] * 1024 + w * 128 + 8 * sl;
        float4 raw = *(const float4*)kp;
        const half2_t* kh = (const half2_t*)&raw;
        p = dot2acc(qh[0], kh[0], p);
        p = dot2acc(qh[1], kh[1], p);
        p = dot2acc(qh[2], kh[2], p);
        p = dot2acc(qh[3], kh[3], p);
      }
#pragma unroll
      for (int off = 8; off >= 1; off >>= 1) p += __shfl_xor(p, off);
      if (sl == 0 && jj < len) pw[jj] = p * ATT_SCALE;
    }
    // online softmax update (wave-private pex column)
    float mloc = -INFINITY;
    for (int j = lane; j < len; j += 64) mloc = fmaxf(mloc, pw[j]);
#pragma unroll
    for (int off = 32; off >= 1; off >>= 1) mloc = fmaxf(mloc, __shfl_xor(mloc, off));
    float mnew = fmaxf(m, mloc);
    float scale = expf(m - mnew);    // first chunk: exp(-inf)=0
#pragma unroll
    for (int i = 0; i < 8; ++i) a[i] *= scale;
    den *= scale;
    float sloc = 0.f;
    for (int j = lane; j < len; j += 64) {
      float p = expf(pw[j] - mnew);
      pw[j] = p;
      sloc += p;
    }
#pragma unroll
    for (int off = 32; off >= 1; off >>= 1) sloc += __shfl_xor(sloc, off);
    den += sloc; m = mnew;

    // aggregate v: four edges per iteration
    for (int j = 0; j < len; j += 4) {
      int jj = j + g4;
      if (jj < len) {
        float pj = pw[jj];
        const __half* vp = kvh + (size_t)ssrc[jj] * 1024 + 512 + w * 128 + 8 * sl;
        float4 raw = *(const float4*)vp;
        const __half2* vh = (const __half2*)&raw;
        float2 f0 = __half22float2(vh[0]);
        float2 f1 = __half22float2(vh[1]);
        float2 f2 = __half22float2(vh[2]);
        float2 f3 = __half22float2(vh[3]);
        a[0] += pj * f0.x; a[1] += pj * f0.y;
        a[2] += pj * f1.x; a[3] += pj * f1.y;
        a[4] += pj * f2.x; a[5] += pj * f2.y;
        a[6] += pj * f3.x; a[7] += pj * f3.y;
      }
    }
  }

  // combine the four 16-lane subgroups
#pragma unroll
  for (int i = 0; i < 8; ++i) {
    a[i] += __shfl_xor(a[i], 16);
    a[i] += __shfl_xor(a[i], 32);
  }

  if (g4 == 0) {
    float inv = 1.f / fmaxf(den, 1e-16f);
    const float* sp = qs + (size_t)node * 1024 + 512 + w * 128 + 8 * sl;
    short8v hi8, lo8;
#pragma unroll
    for (int i = 0; i < 8; ++i) {
      float v = a[i] * inv + sp[i];
      __hip_bfloat16 hv = __float2bfloat16(v);
      __hip_bfloat16 lv = __float2bfloat16(v - __bfloat162float(hv));
      hi8[i] = *(short*)&hv;
      lo8[i] = *(short*)&lv;
    }
    size_t o = (size_t)node * HC + w * 128 + 8 * sl;
    *(short8v*)(t0hi + o) = hi8;
    *(short8v*)(t0lo + o) = lo8;
  }
}

// ============ pooling ============
__global__ __launch_bounds__(256) void pool_init_kernel(float* __restrict__ gm, float* __restrict__ gsum, int* __restrict__ gcnt)
{
  int i = blockIdx.x * 256 + threadIdx.x;
  if (i < NB * HD) { ((int*)gm)[i] = 0xFF800000; gsum[i] = 0.f; }
  if (i < NB) gcnt[i] = 0;
}

__global__ __launch_bounds__(256) void pool_kernel(
    const float* __restrict__ h, const int* __restrict__ batch,
    float* __restrict__ gm, float* __restrict__ gsum, int* __restrict__ gcnt)
{
  int idx = blockIdx.x * 256 + threadIdx.x;
  if (idx >= NN * HD) return;
  int node = idx >> 7, c = idx & 127;
  int b = batch[node];
  float val = h[idx];
  atomicMax((int*)&gm[(size_t)b * HD + c], __float_as_int(val));  // post-ReLU >= 0
  atomicAdd(&gsum[(size_t)b * HD + c], val);
  if (c == 0) atomicAdd(&gcnt[b], 1);
}

// writes g fp32 [512][256] AND bf16 hi/lo split (head MFMA input)
__global__ __launch_bounds__(256) void pool_finalize_kernel(
    const float* __restrict__ gm, const float* __restrict__ gsum,
    const int* __restrict__ gcnt, float* __restrict__ g,
    __hip_bfloat16* __restrict__ ghi, __hip_bfloat16* __restrict__ glo)
{
  int idx = blockIdx.x * 256 + threadIdx.x;
  if (idx >= NB * HD) return;
  int b = idx >> 7, c = idx & 127;
  float mv = gm[idx];
  if (mv < -1e30f) mv = 0.f;
  float cf = (float)gcnt[b];
  float av = gsum[idx] / fmaxf(cf, 1.f);
  size_t o0 = (size_t)b * 256 + c;
  size_t o1 = o0 + 128;
  g[o0] = mv; g[o1] = av;
  __hip_bfloat16 h0 = __float2bfloat16(mv);
  __hip_bfloat16 h1 = __float2bfloat16(av);
  ghi[o0] = h0; glo[o0] = __float2bfloat16(mv - __bfloat162float(h0));
  ghi[o1] = h1; glo[o1] = __float2bfloat16(av - __bfloat162float(h1));
}

// ============ final head layer: [512,256] @ [256,1] + b ============
__global__ __launch_bounds__(256) void head4_kernel(
    const float* __restrict__ g3, const float* __restrict__ Wf2,
    const float* __restrict__ bf2, float* __restrict__ out)
{
  int w = threadIdx.x >> 6, lane = threadIdx.x & 63;
  int row = blockIdx.x * 4 + w;
  const float* r = g3 + (size_t)row * 256;
  float p = r[lane] * Wf2[lane] + r[64 + lane] * Wf2[64 + lane]
          + r[128 + lane] * Wf2[128 + lane] + r[192 + lane] * Wf2[192 + lane];
#pragma unroll
  for (int off = 32; off >= 1; off >>= 1) p += __shfl_xor(p, off);
  if (lane == 0) out[row] = p + bf2[0];
}

extern "C" void kernel_launch(void* const* d_in, const int* in_sizes, int n_in,
                              void* d_out, int out_size, void* d_ws, size_t ws_size,
                              hipStream_t stream)
{
  const float* x = (const float*)d_in[0];
  const int* edge_index = (const int*)d_in[1];
  const int* batch = (const int*)d_in[2];
  const int* src = edge_index;
  const int* dstv = edge_index + NE;

  const float *Wq[3], *bq[3], *Wk[3], *bk[3], *Wv[3], *bv[3], *Wsk[3], *bsk[3], *Wm[3], *bm[3];
  int base = 3;
  for (int l = 0; l < 3; ++l) {
    Wq[l]  = (const float*)d_in[base + 0]; bq[l]  = (const float*)d_in[base + 1];
    Wk[l]  = (const float*)d_in[base + 2]; bk[l]  = (const float*)d_in[base + 3];
    Wv[l]  = (const float*)d_in[base + 4]; bv[l]  = (const float*)d_in[base + 5];
    Wsk[l] = (const float*)d_in[base + 6]; bsk[l] = (const float*)d_in[base + 7];
    Wm[l]  = (const float*)d_in[base + 8]; bm[l]  = (const float*)d_in[base + 9];
    base += 10;
  }
  const float* Wg1 = (const float*)d_in[33]; const float* bg1 = (const float*)d_in[34];
  const float* Wg2 = (const float*)d_in[35]; const float* bg2 = (const float*)d_in[36];
  const float* Wf1 = (const float*)d_in[37]; const float* bf1 = (const float*)d_in[38];
  const float* Wf2 = (const float*)d_in[39]; const float* bf2 = (const float*)d_in[40];

  // ---- workspace layout ----
  char* p = (char*)d_ws;
  auto alloc = [&](size_t bytes) { char* r = p; p += (bytes + 255) & ~(size_t)255; return r; };
  float* qs   = (float*)alloc((size_t)MPAD * 1024 * 4);    // Q | S  fp32
  __half* kvh = (__half*)alloc((size_t)MPAD * 1024 * 2);   // K | V  fp16
  float* h    = (float*)alloc((size_t)NN * HD * 4);
  __hip_bfloat16* t0hi = (__hip_bfloat16*)alloc((size_t)MPAD * HC * 2);
  __hip_bfloat16* t0lo = (__hip_bfloat16*)alloc((size_t)MPAD * HC * 2);
  __hip_bfloat16* hhi  = (__hip_bfloat16*)alloc((size_t)MPAD * HD * 2);
  __hip_bfloat16* hlo  = (__hip_bfloat16*)alloc((size_t)MPAD * HD * 2);
  __hip_bfloat16* xhi  = (__hip_bfloat16*)alloc((size_t)MPAD * 64 * 2);
  __hip_bfloat16* xlo  = (__hip_bfloat16*)alloc((size_t)MPAD * 64 * 2);
  __hip_bfloat16* Wp_hi[3], *Wp_lo[3], *Wm_hi[3], *Wm_lo[3];
  Wp_hi[0] = (__hip_bfloat16*)alloc((size_t)2048 * 64 * 2);
  Wp_lo[0] = (__hip_bfloat16*)alloc((size_t)2048 * 64 * 2);
  for (int l = 1; l < 3; ++l) {
    Wp_hi[l] = (__hip_bfloat16*)alloc((size_t)2048 * 128 * 2);
    Wp_lo[l] = (__hip_bfloat16*)alloc((size_t)2048 * 128 * 2);
  }
  for (int l = 0; l < 3; ++l) {
    Wm_hi[l] = (__hip_bfloat16*)alloc((size_t)128 * 512 * 2);
    Wm_lo[l] = (__hip_bfloat16*)alloc((size_t)128 * 512 * 2);
  }
  __hip_bfloat16* Wg1_hi = (__hip_bfloat16*)alloc((size_t)1024 * 256 * 2);
  __hip_bfloat16* Wg1_lo = (__hip_bfloat16*)alloc((size_t)1024 * 256 * 2);
  __hip_bfloat16* Wg2_hi = (__hip_bfloat16*)alloc((size_t)512 * 1024 * 2);
  __hip_bfloat16* Wg2_lo = (__hip_bfloat16*)alloc((size_t)512 * 1024 * 2);
  __hip_bfloat16* Wf1_hi = (__hip_bfloat16*)alloc((size_t)256 * 512 * 2);
  __hip_bfloat16* Wf1_lo = (__hip_bfloat16*)alloc((size_t)256 * 512 * 2);
  float* bpack = (float*)alloc(3 * 2048 * 4);
  float* gm   = (float*)alloc((size_t)NB * HD * 4);
  float* gsum = (float*)alloc((size_t)NB * HD * 4);
  float* g    = (float*)alloc((size_t)NB * 256 * 4);
  __hip_bfloat16* ghi = (__hip_bfloat16*)alloc((size_t)NB * 256 * 2);
  __hip_bfloat16* glo = (__hip_bfloat16*)alloc((size_t)NB * 256 * 2);
  float* g1 = (float*)alloc((size_t)NB * 1024 * 4);
  __hip_bfloat16* g1hi = (__hip_bfloat16*)alloc((size_t)NB * 1024 * 2);
  __hip_bfloat16* g1lo = (__hip_bfloat16*)alloc((size_t)NB * 1024 * 2);
  float* g2 = (float*)alloc((size_t)NB * 512 * 4);
  __hip_bfloat16* g2hi = (__hip_bfloat16*)alloc((size_t)NB * 512 * 2);
  __hip_bfloat16* g2lo = (__hip_bfloat16*)alloc((size_t)NB * 512 * 2);
  float* g3 = (float*)alloc((size_t)NB * 256 * 4);
  __hip_bfloat16* g3hi = (__hip_bfloat16*)alloc((size_t)NB * 256 * 2);
  __hip_bfloat16* g3lo = (__hip_bfloat16*)alloc((size_t)NB * 256 * 2);
  int* icnt      = (int*)alloc(NN * 4);
  int* cursor    = (int*)alloc(NN * 4);
  int* row_start = (int*)alloc((NN + 1) * 4);
  int* edge_list = (int*)alloc((size_t)NE * 4);
  int* gcnt      = (int*)alloc(NB * 4);

  const int GR128 = (NN + 127) / 128;  // 157

  // ---- pack all weights/biases (one launch) ----
  PackArgs pa;
  for (int l = 0; l < 3; ++l) {
    pa.W[l * 4 + 0] = Wq[l];  pa.W[l * 4 + 1] = Wk[l];
    pa.W[l * 4 + 2] = Wv[l];  pa.W[l * 4 + 3] = Wsk[l];
    pa.b[l * 4 + 0] = bq[l];  pa.b[l * 4 + 1] = bk[l];
    pa.b[l * 4 + 2] = bv[l];  pa.b[l * 4 + 3] = bsk[l];
    pa.Wm[l] = Wm[l];
    pa.Wp_hi[l] = Wp_hi[l]; pa.Wp_lo[l] = Wp_lo[l];
    pa.Wm_hi[l] = Wm_hi[l]; pa.Wm_lo[l] = Wm_lo[l];
  }
  pa.Wg1 = Wg1; pa.Wg2 = Wg2; pa.Wf1 = Wf1;
  pa.Wg1_hi = Wg1_hi; pa.Wg1_lo = Wg1_lo;
  pa.Wg2_hi = Wg2_hi; pa.Wg2_lo = Wg2_lo;
  pa.Wf1_hi = Wf1_hi; pa.Wf1_lo = Wf1_lo;
  pa.bpack = bpack;
  pack_all_kernel<<<(1775616 + 255) / 256, 256, 0, stream>>>(pa);

  // ---- CSR build ----
  hipMemsetAsync(icnt, 0, sizeof(int) * NN, stream);
  hipMemsetAsync(cursor, 0, sizeof(int) * NN, stream);
  count_kernel<<<(NE + 255) / 256, 256, 0, stream>>>(dstv, icnt);
  scan_kernel<<<1, 1024, 0, stream>>>(icnt, row_start);
  scatter_kernel<<<(NE + 255) / 256, 256, 0, stream>>>(src, dstv, row_start, cursor, edge_list);

  // ---- input split ----
  split_x_kernel<<<(NN * 64 + 255) / 256, 256, 0, stream>>>(x, xhi, xlo);

  // ---- 3 TransformerConv layers ----
  for (int l = 0; l < 3; ++l) {
    int Kpad = (l == 0) ? 64 : 128;
    const __hip_bfloat16* Ahi = (l == 0) ? xhi : hhi;
    const __hip_bfloat16* Alo = (l == 0) ? xlo : hlo;

    gemm_mfma_kernel<2><<<dim3(GR128, 16), 256, 0, stream>>>(
        Ahi, Alo, Kpad, Wp_hi[l], Wp_lo[l], bpack + l * 2048, qs, 1024,
        nullptr, nullptr, kvh, NN, Kpad);

    attn_kernel<<<NN, 256, 0, stream>>>(qs, kvh, row_start, edge_list, t0hi, t0lo);

    gemm_mfma_kernel<1><<<dim3(GR128, 1), 256, 0, stream>>>(
        t0hi, t0lo, HC, Wm_hi[l], Wm_lo[l], bm[l], h, HD, hhi, hlo, nullptr, NN, HC);
  }

  // ---- pooling ----
  pool_init_kernel<<<(NB * HD + 255) / 256, 256, 0, stream>>>(gm, gsum, gcnt);
  pool_kernel<<<(NN * HD + 255) / 256, 256, 0, stream>>>(h, batch, gm, gsum, gcnt);
  pool_finalize_kernel<<<(NB * HD + 255) / 256, 256, 0, stream>>>(gm, gsum, gcnt, g, ghi, glo);

  // ---- MLP head via MFMA ----
  gemm_mfma_kernel<1><<<dim3(4, 8), 256, 0, stream>>>(
      ghi, glo, 256, Wg1_hi, Wg1_lo, bg1, g1, 1024, g1hi, g1lo, nullptr, NB, 256);
  gemm_mfma_kernel<1><<<dim3(4, 4), 256, 0, stream>>>(
      g1hi, g1lo, 1024, Wg2_hi, Wg2_lo, bg2, g2, 512, g2hi, g2lo, nullptr, NB, 1024);
  gemm_mfma_kernel<1><<<dim3(4, 2), 256, 0, stream>>>(
      g2hi, g2lo, 512, Wf1_hi, Wf1_lo, bf1, g3, 256, g3hi, g3lo, nullptr, NB, 512);
  head4_kernel<<<NB / 4, 256, 0, stream>>>(g3, Wf2, bf2, (float*)d_out);
}

// Round 6
// 732.110 us; speedup vs baseline: 2.8733x; 1.0649x over previous
//
#include <hip/hip_runtime.h>
#include <hip/hip_bf16.h>
#include <hip/hip_fp16.h>
#include <math.h>

#define NN 20000
#define MPAD 20096          // row padding for MFMA staging (mult of 128)
#define NE 320000
#define NB 512
#define FIN 43
#define HD 128
#define HC 512
#define ATT_SCALE 0.08838834764831843f
#define CHUNK 512

typedef __attribute__((ext_vector_type(8))) short bf16x8v;
typedef __attribute__((ext_vector_type(8))) short short8v;
typedef __attribute__((ext_vector_type(4))) float f32x4v;
typedef _Float16 half2_t __attribute__((ext_vector_type(2)));

__device__ __forceinline__ void gload16(void* lds, const void* g) {
  __builtin_amdgcn_global_load_lds(
      (const __attribute__((address_space(1))) void*)g,
      (__attribute__((address_space(3))) void*)lds, 16, 0, 0);
}

__device__ __forceinline__ float dot2acc(half2_t a, half2_t b, float c) {
#if __has_builtin(__builtin_amdgcn_fdot2)
  return __builtin_amdgcn_fdot2(a, b, c, false);
#else
  return c + (float)a[0] * (float)b[0] + (float)a[1] * (float)b[1];
#endif
}

// ============ split-bf16 MFMA GEMM, 128x128 tile ============
// MODE 1: relu, fp32 Y [M][ldY], bf16 hi/lo split Yhi/Ylo
// MODE 2: qkvs -> cols [0,512): fp32 Q -> Y[row*1024+col]
//                 cols [512,1024):  K head h=(col-512)>>7  -> kvh[row*1024 + h*256 + c]
//                 cols [1024,1536): V head h=(col-1024)>>7 -> kvh[row*1024 + h*256 + 128 + c]
//                 cols [1536,2048): fp32 S -> Y[row*1024+col-1024]
template<int MODE>
__global__ __launch_bounds__(256, 2) void gemm_mfma_kernel(
    const __hip_bfloat16* __restrict__ Ahi_, const __hip_bfloat16* __restrict__ Alo_, int ldA,
    const __hip_bfloat16* __restrict__ Bhi_, const __hip_bfloat16* __restrict__ Blo_,
    const float* __restrict__ bias,
    float* __restrict__ Y, int ldY,
    __hip_bfloat16* __restrict__ Yhi, __hip_bfloat16* __restrict__ Ylo,
    __half* __restrict__ kvh,
    int M, int K)
{
  __shared__ short Ah[128 * 64], Al[128 * 64], Bh[128 * 64], Bl[128 * 64];
  const short* Ahi = (const short*)Ahi_;
  const short* Alo = (const short*)Alo_;
  const short* Bhi = (const short*)Bhi_;
  const short* Blo = (const short*)Blo_;
  const int tid = threadIdx.x;
  const int w = tid >> 6, lane = tid & 63;
  const int rowBase = blockIdx.x * 128, colBase = blockIdx.y * 128;
  const int srow = lane >> 3;
  const int sw = ((lane & 7) ^ srow) << 3;
  const int lr = lane & 15, lg = lane >> 4;
  const int wr = w >> 1, wc = w & 1;

  f32x4v acc[4][4];
#pragma unroll
  for (int m = 0; m < 4; ++m)
#pragma unroll
    for (int n = 0; n < 4; ++n) acc[m][n] = (f32x4v){0.f, 0.f, 0.f, 0.f};

  for (int k0 = 0; k0 < K; k0 += 64) {
    if (k0) __syncthreads();
#pragma unroll
    for (int t = 0; t < 4; ++t) {
      int r0 = w * 32 + t * 8;
      size_t arow = (size_t)(rowBase + r0 + srow) * ldA + k0 + sw;
      size_t brow = (size_t)(colBase + r0 + srow) * K + k0 + sw;
      gload16(&Ah[r0 * 64], Ahi + arow);
      gload16(&Al[r0 * 64], Alo + arow);
      gload16(&Bh[r0 * 64], Bhi + brow);
      gload16(&Bl[r0 * 64], Blo + brow);
    }
    __syncthreads();
#pragma unroll
    for (int kk = 0; kk < 2; ++kk) {
      bf16x8v ah[4], al[4], bh[4], bl[4];
      int cbase = ((kk * 4 + lg) ^ (lr & 7)) * 8;
#pragma unroll
      for (int m = 0; m < 4; ++m) {
        int idx = (wr * 64 + m * 16 + lr) * 64 + cbase;
        ah[m] = *(const bf16x8v*)&Ah[idx];
        al[m] = *(const bf16x8v*)&Al[idx];
      }
#pragma unroll
      for (int n = 0; n < 4; ++n) {
        int idx = (wc * 64 + n * 16 + lr) * 64 + cbase;
        bh[n] = *(const bf16x8v*)&Bh[idx];
        bl[n] = *(const bf16x8v*)&Bl[idx];
      }
#pragma unroll
      for (int m = 0; m < 4; ++m)
#pragma unroll
        for (int n = 0; n < 4; ++n) {
          acc[m][n] = __builtin_amdgcn_mfma_f32_16x16x32_bf16(ah[m], bh[n], acc[m][n], 0, 0, 0);
          acc[m][n] = __builtin_amdgcn_mfma_f32_16x16x32_bf16(ah[m], bl[n], acc[m][n], 0, 0, 0);
          acc[m][n] = __builtin_amdgcn_mfma_f32_16x16x32_bf16(al[m], bh[n], acc[m][n], 0, 0, 0);
        }
    }
  }
#pragma unroll
  for (int m = 0; m < 4; ++m) {
#pragma unroll
    for (int n = 0; n < 4; ++n) {
      int col = colBase + wc * 64 + n * 16 + lr;
      float bb = bias[col];
#pragma unroll
      for (int r = 0; r < 4; ++r) {
        int row = rowBase + wr * 64 + m * 16 + lg * 4 + r;
        if (row < M) {
          float v = acc[m][n][r] + bb;
          if (MODE == 1) {
            v = fmaxf(v, 0.f);
            Y[(size_t)row * ldY + col] = v;
            __hip_bfloat16 hv = __float2bfloat16(v);
            Yhi[(size_t)row * ldY + col] = hv;
            Ylo[(size_t)row * ldY + col] = __float2bfloat16(v - __bfloat162float(hv));
          } else {
            if (col < 512) {
              Y[(size_t)row * 1024 + col] = v;
            } else if (col < 1024) {
              int cc = col - 512;
              kvh[(size_t)row * 1024 + (cc >> 7) * 256 + (cc & 127)] = __float2half(v);
            } else if (col < 1536) {
              int cc = col - 1024;
              kvh[(size_t)row * 1024 + (cc >> 7) * 256 + 128 + (cc & 127)] = __float2half(v);
            } else {
              Y[(size_t)row * 1024 + col - 1024] = v;
            }
          }
        }
      }
    }
  }
}

// ============ split-bf16 MFMA GEMM, 64x128 tile (proj + head: more blocks) ============
__global__ __launch_bounds__(256, 2) void gemm64_kernel(
    const __hip_bfloat16* __restrict__ Ahi_, const __hip_bfloat16* __restrict__ Alo_, int ldA,
    const __hip_bfloat16* __restrict__ Bhi_, const __hip_bfloat16* __restrict__ Blo_,
    const float* __restrict__ bias,
    float* __restrict__ Y, int ldY,
    __hip_bfloat16* __restrict__ Yhi, __hip_bfloat16* __restrict__ Ylo,
    int M, int K)
{
  __shared__ short Ah[64 * 64], Al[64 * 64], Bh[128 * 64], Bl[128 * 64];
  const short* Ahi = (const short*)Ahi_;
  const short* Alo = (const short*)Alo_;
  const short* Bhi = (const short*)Bhi_;
  const short* Blo = (const short*)Blo_;
  const int tid = threadIdx.x;
  const int w = tid >> 6, lane = tid & 63;
  const int rowBase = blockIdx.x * 64, colBase = blockIdx.y * 128;
  const int srow = lane >> 3;
  const int sw = ((lane & 7) ^ srow) << 3;
  const int lr = lane & 15, lg = lane >> 4;
  const int wr = w >> 1, wc = w & 1;

  f32x4v acc[2][4];
#pragma unroll
  for (int m = 0; m < 2; ++m)
#pragma unroll
    for (int n = 0; n < 4; ++n) acc[m][n] = (f32x4v){0.f, 0.f, 0.f, 0.f};

  for (int k0 = 0; k0 < K; k0 += 64) {
    if (k0) __syncthreads();
#pragma unroll
    for (int t = 0; t < 2; ++t) {
      int r0 = w * 16 + t * 8;
      size_t arow = (size_t)(rowBase + r0 + srow) * ldA + k0 + sw;
      gload16(&Ah[r0 * 64], Ahi + arow);
      gload16(&Al[r0 * 64], Alo + arow);
    }
#pragma unroll
    for (int t = 0; t < 4; ++t) {
      int r0 = w * 32 + t * 8;
      size_t brow = (size_t)(colBase + r0 + srow) * K + k0 + sw;
      gload16(&Bh[r0 * 64], Bhi + brow);
      gload16(&Bl[r0 * 64], Blo + brow);
    }
    __syncthreads();
#pragma unroll
    for (int kk = 0; kk < 2; ++kk) {
      bf16x8v ah[2], al[2], bh[4], bl[4];
      int cbase = ((kk * 4 + lg) ^ (lr & 7)) * 8;
#pragma unroll
      for (int m = 0; m < 2; ++m) {
        int idx = (wr * 32 + m * 16 + lr) * 64 + cbase;
        ah[m] = *(const bf16x8v*)&Ah[idx];
        al[m] = *(const bf16x8v*)&Al[idx];
      }
#pragma unroll
      for (int n = 0; n < 4; ++n) {
        int idx = (wc * 64 + n * 16 + lr) * 64 + cbase;
        bh[n] = *(const bf16x8v*)&Bh[idx];
        bl[n] = *(const bf16x8v*)&Bl[idx];
      }
#pragma unroll
      for (int m = 0; m < 2; ++m)
#pragma unroll
        for (int n = 0; n < 4; ++n) {
          acc[m][n] = __builtin_amdgcn_mfma_f32_16x16x32_bf16(ah[m], bh[n], acc[m][n], 0, 0, 0);
          acc[m][n] = __builtin_amdgcn_mfma_f32_16x16x32_bf16(ah[m], bl[n], acc[m][n], 0, 0, 0);
          acc[m][n] = __builtin_amdgcn_mfma_f32_16x16x32_bf16(al[m], bh[n], acc[m][n], 0, 0, 0);
        }
    }
  }
#pragma unroll
  for (int m = 0; m < 2; ++m) {
#pragma unroll
    for (int n = 0; n < 4; ++n) {
      int col = colBase + wc * 64 + n * 16 + lr;
      float bb = bias[col];
#pragma unroll
      for (int r = 0; r < 4; ++r) {
        int row = rowBase + wr * 32 + m * 16 + lg * 4 + r;
        if (row < M) {
          float v = fmaxf(acc[m][n][r] + bb, 0.f);
          Y[(size_t)row * ldY + col] = v;
          __hip_bfloat16 hv = __float2bfloat16(v);
          Yhi[(size_t)row * ldY + col] = hv;
          Ylo[(size_t)row * ldY + col] = __float2bfloat16(v - __bfloat162float(hv));
        }
      }
    }
  }
}

// ============ pack everything in one launch ============
struct PackArgs {
  const float* W[12];     // [l*4 + {q,k,v,s}]  shape [K][512]
  const float* b[12];
  const float* Wm[3];     // [512][128]
  const float *Wg1, *Wg2, *Wf1;
  __hip_bfloat16 *Wp_hi[3], *Wp_lo[3];   // [2048][Kpad]
  __hip_bfloat16 *Wm_hi[3], *Wm_lo[3];   // [128][512]
  __hip_bfloat16 *Wg1_hi, *Wg1_lo;       // [1024][256]
  __hip_bfloat16 *Wg2_hi, *Wg2_lo;       // [512][1024]
  __hip_bfloat16 *Wf1_hi, *Wf1_lo;       // [256][512]
  float* bpack;                           // [3][2048]
};

__global__ __launch_bounds__(256) void pack_all_kernel(PackArgs a)
{
  int idx = blockIdx.x * 256 + threadIdx.x;
  if (idx < 131072) {
    int n = idx >> 6, k = idx & 63;
    int mat = n >> 9, nn = n & 511;
    float v = (k < FIN) ? a.W[mat][(size_t)k * 512 + nn] : 0.f;
    __hip_bfloat16 h = __float2bfloat16(v);
    a.Wp_hi[0][idx] = h;
    a.Wp_lo[0][idx] = __float2bfloat16(v - __bfloat162float(h));
  } else if (idx < 655360) {
    int rel = idx - 131072;
    int l = 1 + (rel >> 18);
    int r2 = rel & 262143;
    int n = r2 >> 7, k = r2 & 127;
    int mat = n >> 9, nn = n & 511;
    float v = a.W[l * 4 + mat][(size_t)k * 512 + nn];
    __hip_bfloat16 h = __float2bfloat16(v);
    a.Wp_hi[l][r2] = h;
    a.Wp_lo[l][r2] = __float2bfloat16(v - __bfloat162float(h));
  } else if (idx < 851968) {
    int rel = idx - 655360;
    int l = rel >> 16;
    int r2 = rel & 65535;
    int n = r2 >> 9, k = r2 & 511;
    float v = a.Wm[l][(size_t)k * 128 + n];
    __hip_bfloat16 h = __float2bfloat16(v);
    a.Wm_hi[l][r2] = h;
    a.Wm_lo[l][r2] = __float2bfloat16(v - __bfloat162float(h));
  } else if (idx < 858112) {
    int rel = idx - 851968;
    int l = rel >> 11, c = rel & 2047;
    a.bpack[rel] = a.b[l * 4 + (c >> 9)][c & 511];
  } else if (idx < 1120256) {
    int rel = idx - 858112;
    int n = rel >> 8, k = rel & 255;
    float v = a.Wg1[(size_t)k * 1024 + n];
    __hip_bfloat16 h = __float2bfloat16(v);
    a.Wg1_hi[rel] = h;
    a.Wg1_lo[rel] = __float2bfloat16(v - __bfloat162float(h));
  } else if (idx < 1644544) {
    int rel = idx - 1120256;
    int n = rel >> 10, k = rel & 1023;
    float v = a.Wg2[(size_t)k * 512 + n];
    __hip_bfloat16 h = __float2bfloat16(v);
    a.Wg2_hi[rel] = h;
    a.Wg2_lo[rel] = __float2bfloat16(v - __bfloat162float(h));
  } else if (idx < 1775616) {
    int rel = idx - 1644544;
    int n = rel >> 9, k = rel & 511;
    float v = a.Wf1[(size_t)k * 256 + n];
    __hip_bfloat16 h = __float2bfloat16(v);
    a.Wf1_hi[rel] = h;
    a.Wf1_lo[rel] = __float2bfloat16(v - __bfloat162float(h));
  }
}

__global__ __launch_bounds__(256) void split_x_kernel(
    const float* __restrict__ x, __hip_bfloat16* __restrict__ hi, __hip_bfloat16* __restrict__ lo)
{
  int idx = blockIdx.x * 256 + threadIdx.x;
  if (idx >= NN * 64) return;
  int r = idx >> 6, c = idx & 63;
  float v = (c < FIN) ? x[(size_t)r * FIN + c] : 0.f;
  __hip_bfloat16 h = __float2bfloat16(v);
  hi[idx] = h;
  lo[idx] = __float2bfloat16(v - __bfloat162float(h));
}

// ============ CSR build over dst ============
__global__ __launch_bounds__(256) void count_kernel(const int* __restrict__ dst, int* __restrict__ cnt)
{
  int e = blockIdx.x * 256 + threadIdx.x;
  if (e < NE) atomicAdd(&cnt[dst[e]], 1);
}

__global__ __launch_bounds__(1024) void scan_kernel(const int* __restrict__ cnt, int* __restrict__ row_start)
{
  __shared__ int sums[1024];
  int t = threadIdx.x;
  const int per = (NN + 1023) / 1024;
  int beg = t * per;
  int end = beg + per; if (end > NN) end = NN; if (beg > NN) beg = NN;
  int s = 0;
  for (int i = beg; i < end; ++i) s += cnt[i];
  sums[t] = s;
  __syncthreads();
  for (int off = 1; off < 1024; off <<= 1) {
    int v = (t >= off) ? sums[t - off] : 0;
    __syncthreads();
    sums[t] += v;
    __syncthreads();
  }
  int prefix = (t == 0) ? 0 : sums[t - 1];
  for (int i = beg; i < end; ++i) { row_start[i] = prefix; prefix += cnt[i]; }
  if (t == 1023) row_start[NN] = prefix;
}

__global__ __launch_bounds__(256) void scatter_kernel(
    const int* __restrict__ src, const int* __restrict__ dst,
    const int* __restrict__ row_start,
    int* __restrict__ cursor, int* __restrict__ edge_list)
{
  int e = blockIdx.x * 256 + threadIdx.x;
  if (e < NE) {
    int d = dst[e];
    int p = atomicAdd(&cursor[d], 1);
    edge_list[row_start[d] + p] = src[e];
  }
}

// ============ fused attention: single-pass online softmax ============
// One block per dst node; wave w = head w; 16-lane subgroup keeps private (m,den,acc).
__global__ __launch_bounds__(256) void attn_kernel(
    const float* __restrict__ qs, const __half* __restrict__ kvh,
    const int* __restrict__ row_start, const int* __restrict__ edge_list,
    __hip_bfloat16* __restrict__ t0hi, __hip_bfloat16* __restrict__ t0lo)
{
  __shared__ int ssrc[CHUNK];
  const int node = blockIdx.x;
  const int tid = threadIdx.x;
  const int w = tid >> 6, lane = tid & 63;
  const int g4 = lane >> 4, sl = lane & 15;
  const int beg = row_start[node], end = row_start[node + 1];

  const float* qp = qs + (size_t)node * 1024 + w * 128 + 8 * sl;
  half2_t qh[4];
  {
    float4 qa = *(const float4*)qp;
    float4 qb = *(const float4*)(qp + 4);
    qh[0] = (half2_t){(_Float16)qa.x, (_Float16)qa.y};
    qh[1] = (half2_t){(_Float16)qa.z, (_Float16)qa.w};
    qh[2] = (half2_t){(_Float16)qb.x, (_Float16)qb.y};
    qh[3] = (half2_t){(_Float16)qb.z, (_Float16)qb.w};
  }

  float m = -INFINITY, den = 0.f;
  float a[8] = {0.f, 0.f, 0.f, 0.f, 0.f, 0.f, 0.f, 0.f};

  auto upd = [&](float p, const float4& vraw) {
    const __half2* vh = (const __half2*)&vraw;
    float2 f0 = __half22float2(vh[0]);
    float2 f1 = __half22float2(vh[1]);
    float2 f2 = __half22float2(vh[2]);
    float2 f3 = __half22float2(vh[3]);
    if (p > m) {
      float c = __expf(m - p);   // first edge: exp(-inf)=0
      den = den * c + 1.f;
      a[0] = a[0] * c + f0.x; a[1] = a[1] * c + f0.y;
      a[2] = a[2] * c + f1.x; a[3] = a[3] * c + f1.y;
      a[4] = a[4] * c + f2.x; a[5] = a[5] * c + f2.y;
      a[6] = a[6] * c + f3.x; a[7] = a[7] * c + f3.y;
      m = p;
    } else {
      float e = __expf(p - m);
      den += e;
      a[0] += e * f0.x; a[1] += e * f0.y;
      a[2] += e * f1.x; a[3] += e * f1.y;
      a[4] += e * f2.x; a[5] += e * f2.y;
      a[6] += e * f3.x; a[7] += e * f3.y;
    }
  };

  for (int c0 = beg; c0 < end; c0 += CHUNK) {
    int len = end - c0; if (len > CHUNK) len = CHUNK;
    __syncthreads();
    for (int i = tid; i < len; i += 256)
      ssrc[i] = edge_list[c0 + i];
    __syncthreads();

    // subgroup g4 takes edge pairs {2*g4, 2*g4+1}, stride 8
    for (int j = 2 * g4; j < len; j += 8) {
      int s0 = ssrc[j];
      bool has1 = (j + 1 < len);
      int s1 = has1 ? ssrc[j + 1] : s0;
      const __half* b0 = kvh + (size_t)s0 * 1024 + w * 256 + 8 * sl;
      const __half* b1 = kvh + (size_t)s1 * 1024 + w * 256 + 8 * sl;
      float4 k0 = *(const float4*)b0;
      float4 v0 = *(const float4*)(b0 + 128);
      float4 k1 = *(const float4*)b1;
      float4 v1 = *(const float4*)(b1 + 128);

      const half2_t* kh0 = (const half2_t*)&k0;
      const half2_t* kh1 = (const half2_t*)&k1;
      float p0 = 0.f, p1 = 0.f;
#pragma unroll
      for (int i = 0; i < 4; ++i) {
        p0 = dot2acc(qh[i], kh0[i], p0);
        p1 = dot2acc(qh[i], kh1[i], p1);
      }
#pragma unroll
      for (int off = 8; off >= 1; off >>= 1) {
        p0 += __shfl_xor(p0, off);
        p1 += __shfl_xor(p1, off);
      }
      p0 *= ATT_SCALE; p1 *= ATT_SCALE;
      upd(p0, v0);
      if (has1) upd(p1, v1);
    }
  }

  // combine the 4 subgroups (online-softmax merge)
  float m2 = fmaxf(m, __shfl_xor(m, 16));
  float mAll = fmaxf(m2, __shfl_xor(m2, 32));
  float scale = (m == -INFINITY) ? 0.f : __expf(m - mAll);
  den *= scale;
  den += __shfl_xor(den, 16);
  den += __shfl_xor(den, 32);
#pragma unroll
  for (int i = 0; i < 8; ++i) {
    a[i] *= scale;
    a[i] += __shfl_xor(a[i], 16);
    a[i] += __shfl_xor(a[i], 32);
  }

  if (g4 == 0) {
    float inv = 1.f / fmaxf(den, 1e-16f);
    const float* sp = qs + (size_t)node * 1024 + 512 + w * 128 + 8 * sl;
    short8v hi8, lo8;
#pragma unroll
    for (int i = 0; i < 8; ++i) {
      float v = a[i] * inv + sp[i];
      __hip_bfloat16 hv = __float2bfloat16(v);
      __hip_bfloat16 lv = __float2bfloat16(v - __bfloat162float(hv));
      hi8[i] = *(short*)&hv;
      lo8[i] = *(short*)&lv;
    }
    size_t o = (size_t)node * HC + w * 128 + 8 * sl;
    *(short8v*)(t0hi + o) = hi8;
    *(short8v*)(t0lo + o) = lo8;
  }
}

// ============ pooling (run-compressed: batch is sorted) ============
__global__ __launch_bounds__(256) void pool_init_kernel(float* __restrict__ gm, float* __restrict__ gsum, int* __restrict__ gcnt)
{
  int i = blockIdx.x * 256 + threadIdx.x;
  if (i < NB * HD) { ((int*)gm)[i] = 0xFF800000; gsum[i] = 0.f; }
  if (i < NB) gcnt[i] = 0;
}

#define PN 32  // nodes per block
__global__ __launch_bounds__(256) void pool_kernel(
    const float* __restrict__ h, const int* __restrict__ batch,
    float* __restrict__ gm, float* __restrict__ gsum, int* __restrict__ gcnt)
{
  __shared__ int sbatch[PN];
  const int base = blockIdx.x * PN;
  const int tid = threadIdx.x;
  if (tid < PN) {
    int n = base + tid;
    sbatch[tid] = (n < NN) ? batch[n] : -1;
  }
  __syncthreads();
  const int c = tid & 127;
  const int half = tid >> 7;
  const int i0 = half * (PN / 2), i1 = i0 + PN / 2;

  float sum = 0.f, mx = -INFINITY;
  int cur = sbatch[i0];
  bool any = false;
  for (int i = i0; i < i1; ++i) {
    int n = base + i;
    if (n >= NN) break;
    int b = sbatch[i];
    if (b != cur) {
      if (any) {
        atomicAdd(&gsum[(size_t)cur * HD + c], sum);
        atomicMax((int*)&gm[(size_t)cur * HD + c], __float_as_int(mx));
      }
      sum = 0.f; mx = -INFINITY; cur = b; any = false;
    }
    float val = h[(size_t)n * HD + c];
    sum += val; mx = fmaxf(mx, val);
    any = true;
  }
  if (any && cur >= 0) {
    atomicAdd(&gsum[(size_t)cur * HD + c], sum);
    atomicMax((int*)&gm[(size_t)cur * HD + c], __float_as_int(mx));
  }
  if (c == 0) {
    int cnt = 0; int cb = sbatch[i0];
    for (int i = i0; i < i1; ++i) {
      int n = base + i;
      if (n >= NN) break;
      if (sbatch[i] != cb) {
        if (cnt > 0 && cb >= 0) atomicAdd(&gcnt[cb], cnt);
        cnt = 0; cb = sbatch[i];
      }
      cnt++;
    }
    if (cnt > 0 && cb >= 0) atomicAdd(&gcnt[cb], cnt);
  }
}

__global__ __launch_bounds__(256) void pool_finalize_kernel(
    const float* __restrict__ gm, const float* __restrict__ gsum,
    const int* __restrict__ gcnt, float* __restrict__ g,
    __hip_bfloat16* __restrict__ ghi, __hip_bfloat16* __restrict__ glo)
{
  int idx = blockIdx.x * 256 + threadIdx.x;
  if (idx >= NB * HD) return;
  int b = idx >> 7, c = idx & 127;
  float mv = gm[idx];
  if (mv < -1e30f) mv = 0.f;
  float cf = (float)gcnt[b];
  float av = gsum[idx] / fmaxf(cf, 1.f);
  size_t o0 = (size_t)b * 256 + c;
  size_t o1 = o0 + 128;
  g[o0] = mv; g[o1] = av;
  __hip_bfloat16 h0 = __float2bfloat16(mv);
  __hip_bfloat16 h1 = __float2bfloat16(av);
  ghi[o0] = h0; glo[o0] = __float2bfloat16(mv - __bfloat162float(h0));
  ghi[o1] = h1; glo[o1] = __float2bfloat16(av - __bfloat162float(h1));
}

// ============ final head layer: [512,256] @ [256,1] + b ============
__global__ __launch_bounds__(256) void head4_kernel(
    const float* __restrict__ g3, const float* __restrict__ Wf2,
    const float* __restrict__ bf2, float* __restrict__ out)
{
  int w = threadIdx.x >> 6, lane = threadIdx.x & 63;
  int row = blockIdx.x * 4 + w;
  const float* r = g3 + (size_t)row * 256;
  float p = r[lane] * Wf2[lane] + r[64 + lane] * Wf2[64 + lane]
          + r[128 + lane] * Wf2[128 + lane] + r[192 + lane] * Wf2[192 + lane];
#pragma unroll
  for (int off = 32; off >= 1; off >>= 1) p += __shfl_xor(p, off);
  if (lane == 0) out[row] = p + bf2[0];
}

extern "C" void kernel_launch(void* const* d_in, const int* in_sizes, int n_in,
                              void* d_out, int out_size, void* d_ws, size_t ws_size,
                              hipStream_t stream)
{
  const float* x = (const float*)d_in[0];
  const int* edge_index = (const int*)d_in[1];
  const int* batch = (const int*)d_in[2];
  const int* src = edge_index;
  const int* dstv = edge_index + NE;

  const float *Wq[3], *bq[3], *Wk[3], *bk[3], *Wv[3], *bv[3], *Wsk[3], *bsk[3], *Wm[3], *bm[3];
  int base = 3;
  for (int l = 0; l < 3; ++l) {
    Wq[l]  = (const float*)d_in[base + 0]; bq[l]  = (const float*)d_in[base + 1];
    Wk[l]  = (const float*)d_in[base + 2]; bk[l]  = (const float*)d_in[base + 3];
    Wv[l]  = (const float*)d_in[base + 4]; bv[l]  = (const float*)d_in[base + 5];
    Wsk[l] = (const float*)d_in[base + 6]; bsk[l] = (const float*)d_in[base + 7];
    Wm[l]  = (const float*)d_in[base + 8]; bm[l]  = (const float*)d_in[base + 9];
    base += 10;
  }
  const float* Wg1 = (const float*)d_in[33]; const float* bg1 = (const float*)d_in[34];
  const float* Wg2 = (const float*)d_in[35]; const float* bg2 = (const float*)d_in[36];
  const float* Wf1 = (const float*)d_in[37]; const float* bf1 = (const float*)d_in[38];
  const float* Wf2 = (const float*)d_in[39]; const float* bf2 = (const float*)d_in[40];

  // ---- workspace layout ----
  char* p = (char*)d_ws;
  auto alloc = [&](size_t bytes) { char* r = p; p += (bytes + 255) & ~(size_t)255; return r; };
  float* qs   = (float*)alloc((size_t)MPAD * 1024 * 4);    // Q | S  fp32
  __half* kvh = (__half*)alloc((size_t)MPAD * 1024 * 2);   // per head: K(128)|V(128) fp16
  float* h    = (float*)alloc((size_t)NN * HD * 4);
  __hip_bfloat16* t0hi = (__hip_bfloat16*)alloc((size_t)MPAD * HC * 2);
  __hip_bfloat16* t0lo = (__hip_bfloat16*)alloc((size_t)MPAD * HC * 2);
  __hip_bfloat16* hhi  = (__hip_bfloat16*)alloc((size_t)MPAD * HD * 2);
  __hip_bfloat16* hlo  = (__hip_bfloat16*)alloc((size_t)MPAD * HD * 2);
  __hip_bfloat16* xhi  = (__hip_bfloat16*)alloc((size_t)MPAD * 64 * 2);
  __hip_bfloat16* xlo  = (__hip_bfloat16*)alloc((size_t)MPAD * 64 * 2);
  __hip_bfloat16* Wp_hi[3], *Wp_lo[3], *Wm_hi[3], *Wm_lo[3];
  Wp_hi[0] = (__hip_bfloat16*)alloc((size_t)2048 * 64 * 2);
  Wp_lo[0] = (__hip_bfloat16*)alloc((size_t)2048 * 64 * 2);
  for (int l = 1; l < 3; ++l) {
    Wp_hi[l] = (__hip_bfloat16*)alloc((size_t)2048 * 128 * 2);
    Wp_lo[l] = (__hip_bfloat16*)alloc((size_t)2048 * 128 * 2);
  }
  for (int l = 0; l < 3; ++l) {
    Wm_hi[l] = (__hip_bfloat16*)alloc((size_t)128 * 512 * 2);
    Wm_lo[l] = (__hip_bfloat16*)alloc((size_t)128 * 512 * 2);
  }
  __hip_bfloat16* Wg1_hi = (__hip_bfloat16*)alloc((size_t)1024 * 256 * 2);
  __hip_bfloat16* Wg1_lo = (__hip_bfloat16*)alloc((size_t)1024 * 256 * 2);
  __hip_bfloat16* Wg2_hi = (__hip_bfloat16*)alloc((size_t)512 * 1024 * 2);
  __hip_bfloat16* Wg2_lo = (__hip_bfloat16*)alloc((size_t)512 * 1024 * 2);
  __hip_bfloat16* Wf1_hi = (__hip_bfloat16*)alloc((size_t)256 * 512 * 2);
  __hip_bfloat16* Wf1_lo = (__hip_bfloat16*)alloc((size_t)256 * 512 * 2);
  float* bpack = (float*)alloc(3 * 2048 * 4);
  float* gm   = (float*)alloc((size_t)NB * HD * 4);
  float* gsum = (float*)alloc((size_t)NB * HD * 4);
  float* g    = (float*)alloc((size_t)NB * 256 * 4);
  __hip_bfloat16* ghi = (__hip_bfloat16*)alloc((size_t)NB * 256 * 2);
  __hip_bfloat16* glo = (__hip_bfloat16*)alloc((size_t)NB * 256 * 2);
  float* g1 = (float*)alloc((size_t)NB * 1024 * 4);
  __hip_bfloat16* g1hi = (__hip_bfloat16*)alloc((size_t)NB * 1024 * 2);
  __hip_bfloat16* g1lo = (__hip_bfloat16*)alloc((size_t)NB * 1024 * 2);
  float* g2 = (float*)alloc((size_t)NB * 512 * 4);
  __hip_bfloat16* g2hi = (__hip_bfloat16*)alloc((size_t)NB * 512 * 2);
  __hip_bfloat16* g2lo = (__hip_bfloat16*)alloc((size_t)NB * 512 * 2);
  float* g3 = (float*)alloc((size_t)NB * 256 * 4);
  __hip_bfloat16* g3hi = (__hip_bfloat16*)alloc((size_t)NB * 256 * 2);
  __hip_bfloat16* g3lo = (__hip_bfloat16*)alloc((size_t)NB * 256 * 2);
  int* icnt      = (int*)alloc(NN * 4);
  int* cursor    = (int*)alloc(NN * 4);
  int* row_start = (int*)alloc((NN + 1) * 4);
  int* edge_list = (int*)alloc((size_t)NE * 4);
  int* gcnt      = (int*)alloc(NB * 4);

  const int GR128 = (NN + 127) / 128;  // 157
  const int GR64  = (NN + 63) / 64;    // 313

  // ---- pack all weights/biases ----
  PackArgs pa;
  for (int l = 0; l < 3; ++l) {
    pa.W[l * 4 + 0] = Wq[l];  pa.W[l * 4 + 1] = Wk[l];
    pa.W[l * 4 + 2] = Wv[l];  pa.W[l * 4 + 3] = Wsk[l];
    pa.b[l * 4 + 0] = bq[l];  pa.b[l * 4 + 1] = bk[l];
    pa.b[l * 4 + 2] = bv[l];  pa.b[l * 4 + 3] = bsk[l];
    pa.Wm[l] = Wm[l];
    pa.Wp_hi[l] = Wp_hi[l]; pa.Wp_lo[l] = Wp_lo[l];
    pa.Wm_hi[l] = Wm_hi[l]; pa.Wm_lo[l] = Wm_lo[l];
  }
  pa.Wg1 = Wg1; pa.Wg2 = Wg2; pa.Wf1 = Wf1;
  pa.Wg1_hi = Wg1_hi; pa.Wg1_lo = Wg1_lo;
  pa.Wg2_hi = Wg2_hi; pa.Wg2_lo = Wg2_lo;
  pa.Wf1_hi = Wf1_hi; pa.Wf1_lo = Wf1_lo;
  pa.bpack = bpack;
  pack_all_kernel<<<(1775616 + 255) / 256, 256, 0, stream>>>(pa);

  // ---- CSR build ----
  hipMemsetAsync(icnt, 0, sizeof(int) * NN, stream);
  hipMemsetAsync(cursor, 0, sizeof(int) * NN, stream);
  count_kernel<<<(NE + 255) / 256, 256, 0, stream>>>(dstv, icnt);
  scan_kernel<<<1, 1024, 0, stream>>>(icnt, row_start);
  scatter_kernel<<<(NE + 255) / 256, 256, 0, stream>>>(src, dstv, row_start, cursor, edge_list);

  // ---- input split ----
  split_x_kernel<<<(NN * 64 + 255) / 256, 256, 0, stream>>>(x, xhi, xlo);

  // ---- 3 TransformerConv layers ----
  for (int l = 0; l < 3; ++l) {
    int Kpad = (l == 0) ? 64 : 128;
    const __hip_bfloat16* Ahi = (l == 0) ? xhi : hhi;
    const __hip_bfloat16* Alo = (l == 0) ? xlo : hlo;

    gemm_mfma_kernel<2><<<dim3(GR128, 16), 256, 0, stream>>>(
        Ahi, Alo, Kpad, Wp_hi[l], Wp_lo[l], bpack + l * 2048, qs, 1024,
        nullptr, nullptr, kvh, NN, Kpad);

    attn_kernel<<<NN, 256, 0, stream>>>(qs, kvh, row_start, edge_list, t0hi, t0lo);

    gemm64_kernel<<<dim3(GR64, 1), 256, 0, stream>>>(
        t0hi, t0lo, HC, Wm_hi[l], Wm_lo[l], bm[l], h, HD, hhi, hlo, NN, HC);
  }

  // ---- pooling ----
  pool_init_kernel<<<(NB * HD + 255) / 256, 256, 0, stream>>>(gm, gsum, gcnt);
  pool_kernel<<<(NN + PN - 1) / PN, 256, 0, stream>>>(h, batch, gm, gsum, gcnt);
  pool_finalize_kernel<<<(NB * HD + 255) / 256, 256, 0, stream>>>(gm, gsum, gcnt, g, ghi, glo);

  // ---- MLP head via MFMA (64-row tiles) ----
  gemm64_kernel<<<dim3(8, 8), 256, 0, stream>>>(
      ghi, glo, 256, Wg1_hi, Wg1_lo, bg1, g1, 1024, g1hi, g1lo, NB, 256);
  gemm64_kernel<<<dim3(8, 4), 256, 0, stream>>>(
      g1hi, g1lo, 1024, Wg2_hi, Wg2_lo, bg2, g2, 512, g2hi, g2lo, NB, 1024);
  gemm64_kernel<<<dim3(8, 2), 256, 0, stream>>>(
      g2hi, g2lo, 512, Wf1_hi, Wf1_lo, bf1, g3, 256, g3hi, g3lo, NB, 512);
  head4_kernel<<<NB / 4, 256, 0, stream>>>(g3, Wf2, bf2, (float*)d_out);
}

// Round 7
// 713.725 us; speedup vs baseline: 2.9473x; 1.0258x over previous
//
#include <hip/hip_runtime.h>
#include <hip/hip_bf16.h>
#include <hip/hip_fp16.h>
#include <math.h>

#define NN 20000
#define MPAD 20096          // row padding for MFMA staging (mult of 128)
#define NE 320000
#define NB 512
#define FIN 43
#define HD 128
#define HC 512
#define ATT_SCALE 0.08838834764831843f
#define CHUNK 512

typedef __attribute__((ext_vector_type(8))) short bf16x8v;
typedef __attribute__((ext_vector_type(8))) short short8v;
typedef __attribute__((ext_vector_type(4))) float f32x4v;
typedef _Float16 half2_t __attribute__((ext_vector_type(2)));

__device__ __forceinline__ void gload16(void* lds, const void* g) {
  __builtin_amdgcn_global_load_lds(
      (const __attribute__((address_space(1))) void*)g,
      (__attribute__((address_space(3))) void*)lds, 16, 0, 0);
}

__device__ __forceinline__ float dot2acc(half2_t a, half2_t b, float c) {
#if __has_builtin(__builtin_amdgcn_fdot2)
  return __builtin_amdgcn_fdot2(a, b, c, false);
#else
  return c + (float)a[0] * (float)b[0] + (float)a[1] * (float)b[1];
#endif
}

// ============ split-bf16 MFMA GEMM, 128x128 tile ============
// MODE 1: relu, fp32 Y [M][ldY], bf16 hi/lo split Yhi/Ylo
// MODE 2: qkvs (grid is COL-FASTEST: blockIdx.x = col-block, blockIdx.y = row-block)
//         cols [0,512): fp32 Q -> Y[row*1024+col]
//         cols [512,1024):  K head h -> kvh[row*1024 + h*256 + c]
//         cols [1024,1536): V head h -> kvh[row*1024 + h*256 + 128 + c]
//         cols [1536,2048): fp32 S -> Y[row*1024+col-1024]
template<int MODE>
__global__ __launch_bounds__(256, 2) void gemm_mfma_kernel(
    const __hip_bfloat16* __restrict__ Ahi_, const __hip_bfloat16* __restrict__ Alo_, int ldA,
    const __hip_bfloat16* __restrict__ Bhi_, const __hip_bfloat16* __restrict__ Blo_,
    const float* __restrict__ bias,
    float* __restrict__ Y, int ldY,
    __hip_bfloat16* __restrict__ Yhi, __hip_bfloat16* __restrict__ Ylo,
    __half* __restrict__ kvh,
    int M, int K)
{
  __shared__ short Ah[128 * 64], Al[128 * 64], Bh[128 * 64], Bl[128 * 64];
  const short* Ahi = (const short*)Ahi_;
  const short* Alo = (const short*)Alo_;
  const short* Bhi = (const short*)Bhi_;
  const short* Blo = (const short*)Blo_;
  const int tid = threadIdx.x;
  const int w = tid >> 6, lane = tid & 63;
  const int bx = (MODE == 2) ? blockIdx.y : blockIdx.x;   // row-block
  const int by = (MODE == 2) ? blockIdx.x : blockIdx.y;   // col-block
  const int rowBase = bx * 128, colBase = by * 128;
  const int srow = lane >> 3;
  const int sw = ((lane & 7) ^ srow) << 3;
  const int lr = lane & 15, lg = lane >> 4;
  const int wr = w >> 1, wc = w & 1;

  f32x4v acc[4][4];
#pragma unroll
  for (int m = 0; m < 4; ++m)
#pragma unroll
    for (int n = 0; n < 4; ++n) acc[m][n] = (f32x4v){0.f, 0.f, 0.f, 0.f};

  for (int k0 = 0; k0 < K; k0 += 64) {
    if (k0) __syncthreads();
#pragma unroll
    for (int t = 0; t < 4; ++t) {
      int r0 = w * 32 + t * 8;
      size_t arow = (size_t)(rowBase + r0 + srow) * ldA + k0 + sw;
      size_t brow = (size_t)(colBase + r0 + srow) * K + k0 + sw;
      gload16(&Ah[r0 * 64], Ahi + arow);
      gload16(&Al[r0 * 64], Alo + arow);
      gload16(&Bh[r0 * 64], Bhi + brow);
      gload16(&Bl[r0 * 64], Blo + brow);
    }
    __syncthreads();
#pragma unroll
    for (int kk = 0; kk < 2; ++kk) {
      bf16x8v ah[4], al[4], bh[4], bl[4];
      int cbase = ((kk * 4 + lg) ^ (lr & 7)) * 8;
#pragma unroll
      for (int m = 0; m < 4; ++m) {
        int idx = (wr * 64 + m * 16 + lr) * 64 + cbase;
        ah[m] = *(const bf16x8v*)&Ah[idx];
        al[m] = *(const bf16x8v*)&Al[idx];
      }
#pragma unroll
      for (int n = 0; n < 4; ++n) {
        int idx = (wc * 64 + n * 16 + lr) * 64 + cbase;
        bh[n] = *(const bf16x8v*)&Bh[idx];
        bl[n] = *(const bf16x8v*)&Bl[idx];
      }
#pragma unroll
      for (int m = 0; m < 4; ++m)
#pragma unroll
        for (int n = 0; n < 4; ++n) {
          acc[m][n] = __builtin_amdgcn_mfma_f32_16x16x32_bf16(ah[m], bh[n], acc[m][n], 0, 0, 0);
          acc[m][n] = __builtin_amdgcn_mfma_f32_16x16x32_bf16(ah[m], bl[n], acc[m][n], 0, 0, 0);
          acc[m][n] = __builtin_amdgcn_mfma_f32_16x16x32_bf16(al[m], bh[n], acc[m][n], 0, 0, 0);
        }
    }
  }
#pragma unroll
  for (int m = 0; m < 4; ++m) {
#pragma unroll
    for (int n = 0; n < 4; ++n) {
      int col = colBase + wc * 64 + n * 16 + lr;
      float bb = bias[col];
#pragma unroll
      for (int r = 0; r < 4; ++r) {
        int row = rowBase + wr * 64 + m * 16 + lg * 4 + r;
        if (row < M) {
          float v = acc[m][n][r] + bb;
          if (MODE == 1) {
            v = fmaxf(v, 0.f);
            Y[(size_t)row * ldY + col] = v;
            __hip_bfloat16 hv = __float2bfloat16(v);
            Yhi[(size_t)row * ldY + col] = hv;
            Ylo[(size_t)row * ldY + col] = __float2bfloat16(v - __bfloat162float(hv));
          } else {
            if (col < 512) {
              Y[(size_t)row * 1024 + col] = v;
            } else if (col < 1024) {
              int cc = col - 512;
              kvh[(size_t)row * 1024 + (cc >> 7) * 256 + (cc & 127)] = __float2half(v);
            } else if (col < 1536) {
              int cc = col - 1024;
              kvh[(size_t)row * 1024 + (cc >> 7) * 256 + 128 + (cc & 127)] = __float2half(v);
            } else {
              Y[(size_t)row * 1024 + col - 1024] = v;
            }
          }
        }
      }
    }
  }
}

// ============ split-bf16 MFMA GEMM, 64x128 tile (proj + head) ============
__global__ __launch_bounds__(256, 2) void gemm64_kernel(
    const __hip_bfloat16* __restrict__ Ahi_, const __hip_bfloat16* __restrict__ Alo_, int ldA,
    const __hip_bfloat16* __restrict__ Bhi_, const __hip_bfloat16* __restrict__ Blo_,
    const float* __restrict__ bias,
    float* __restrict__ Y, int ldY,
    __hip_bfloat16* __restrict__ Yhi, __hip_bfloat16* __restrict__ Ylo,
    int M, int K)
{
  __shared__ short Ah[64 * 64], Al[64 * 64], Bh[128 * 64], Bl[128 * 64];
  const short* Ahi = (const short*)Ahi_;
  const short* Alo = (const short*)Alo_;
  const short* Bhi = (const short*)Bhi_;
  const short* Blo = (const short*)Blo_;
  const int tid = threadIdx.x;
  const int w = tid >> 6, lane = tid & 63;
  const int rowBase = blockIdx.x * 64, colBase = blockIdx.y * 128;
  const int srow = lane >> 3;
  const int sw = ((lane & 7) ^ srow) << 3;
  const int lr = lane & 15, lg = lane >> 4;
  const int wr = w >> 1, wc = w & 1;

  f32x4v acc[2][4];
#pragma unroll
  for (int m = 0; m < 2; ++m)
#pragma unroll
    for (int n = 0; n < 4; ++n) acc[m][n] = (f32x4v){0.f, 0.f, 0.f, 0.f};

  for (int k0 = 0; k0 < K; k0 += 64) {
    if (k0) __syncthreads();
#pragma unroll
    for (int t = 0; t < 2; ++t) {
      int r0 = w * 16 + t * 8;
      size_t arow = (size_t)(rowBase + r0 + srow) * ldA + k0 + sw;
      gload16(&Ah[r0 * 64], Ahi + arow);
      gload16(&Al[r0 * 64], Alo + arow);
    }
#pragma unroll
    for (int t = 0; t < 4; ++t) {
      int r0 = w * 32 + t * 8;
      size_t brow = (size_t)(colBase + r0 + srow) * K + k0 + sw;
      gload16(&Bh[r0 * 64], Bhi + brow);
      gload16(&Bl[r0 * 64], Blo + brow);
    }
    __syncthreads();
#pragma unroll
    for (int kk = 0; kk < 2; ++kk) {
      bf16x8v ah[2], al[2], bh[4], bl[4];
      int cbase = ((kk * 4 + lg) ^ (lr & 7)) * 8;
#pragma unroll
      for (int m = 0; m < 2; ++m) {
        int idx = (wr * 32 + m * 16 + lr) * 64 + cbase;
        ah[m] = *(const bf16x8v*)&Ah[idx];
        al[m] = *(const bf16x8v*)&Al[idx];
      }
#pragma unroll
      for (int n = 0; n < 4; ++n) {
        int idx = (wc * 64 + n * 16 + lr) * 64 + cbase;
        bh[n] = *(const bf16x8v*)&Bh[idx];
        bl[n] = *(const bf16x8v*)&Bl[idx];
      }
#pragma unroll
      for (int m = 0; m < 2; ++m)
#pragma unroll
        for (int n = 0; n < 4; ++n) {
          acc[m][n] = __builtin_amdgcn_mfma_f32_16x16x32_bf16(ah[m], bh[n], acc[m][n], 0, 0, 0);
          acc[m][n] = __builtin_amdgcn_mfma_f32_16x16x32_bf16(ah[m], bl[n], acc[m][n], 0, 0, 0);
          acc[m][n] = __builtin_amdgcn_mfma_f32_16x16x32_bf16(al[m], bh[n], acc[m][n], 0, 0, 0);
        }
    }
  }
#pragma unroll
  for (int m = 0; m < 2; ++m) {
#pragma unroll
    for (int n = 0; n < 4; ++n) {
      int col = colBase + wc * 64 + n * 16 + lr;
      float bb = bias[col];
#pragma unroll
      for (int r = 0; r < 4; ++r) {
        int row = rowBase + wr * 32 + m * 16 + lg * 4 + r;
        if (row < M) {
          float v = fmaxf(acc[m][n][r] + bb, 0.f);
          Y[(size_t)row * ldY + col] = v;
          __hip_bfloat16 hv = __float2bfloat16(v);
          Yhi[(size_t)row * ldY + col] = hv;
          Ylo[(size_t)row * ldY + col] = __float2bfloat16(v - __bfloat162float(hv));
        }
      }
    }
  }
}

// ============ pack everything in one launch ============
struct PackArgs {
  const float* W[12];     // [l*4 + {q,k,v,s}]  shape [K][512]
  const float* b[12];
  const float* Wm[3];     // [512][128]
  const float *Wg1, *Wg2, *Wf1;
  __hip_bfloat16 *Wp_hi[3], *Wp_lo[3];   // [2048][Kpad]
  __hip_bfloat16 *Wm_hi[3], *Wm_lo[3];   // [128][512]
  __hip_bfloat16 *Wg1_hi, *Wg1_lo;       // [1024][256]
  __hip_bfloat16 *Wg2_hi, *Wg2_lo;       // [512][1024]
  __hip_bfloat16 *Wf1_hi, *Wf1_lo;       // [256][512]
  float* bpack;                           // [3][2048]
};

__global__ __launch_bounds__(256) void pack_all_kernel(PackArgs a)
{
  int idx = blockIdx.x * 256 + threadIdx.x;
  if (idx < 131072) {
    int n = idx >> 6, k = idx & 63;
    int mat = n >> 9, nn = n & 511;
    float v = (k < FIN) ? a.W[mat][(size_t)k * 512 + nn] : 0.f;
    __hip_bfloat16 h = __float2bfloat16(v);
    a.Wp_hi[0][idx] = h;
    a.Wp_lo[0][idx] = __float2bfloat16(v - __bfloat162float(h));
  } else if (idx < 655360) {
    int rel = idx - 131072;
    int l = 1 + (rel >> 18);
    int r2 = rel & 262143;
    int n = r2 >> 7, k = r2 & 127;
    int mat = n >> 9, nn = n & 511;
    float v = a.W[l * 4 + mat][(size_t)k * 512 + nn];
    __hip_bfloat16 h = __float2bfloat16(v);
    a.Wp_hi[l][r2] = h;
    a.Wp_lo[l][r2] = __float2bfloat16(v - __bfloat162float(h));
  } else if (idx < 851968) {
    int rel = idx - 655360;
    int l = rel >> 16;
    int r2 = rel & 65535;
    int n = r2 >> 9, k = r2 & 511;
    float v = a.Wm[l][(size_t)k * 128 + n];
    __hip_bfloat16 h = __float2bfloat16(v);
    a.Wm_hi[l][r2] = h;
    a.Wm_lo[l][r2] = __float2bfloat16(v - __bfloat162float(h));
  } else if (idx < 858112) {
    int rel = idx - 851968;
    int l = rel >> 11, c = rel & 2047;
    a.bpack[rel] = a.b[l * 4 + (c >> 9)][c & 511];
  } else if (idx < 1120256) {
    int rel = idx - 858112;
    int n = rel >> 8, k = rel & 255;
    float v = a.Wg1[(size_t)k * 1024 + n];
    __hip_bfloat16 h = __float2bfloat16(v);
    a.Wg1_hi[rel] = h;
    a.Wg1_lo[rel] = __float2bfloat16(v - __bfloat162float(h));
  } else if (idx < 1644544) {
    int rel = idx - 1120256;
    int n = rel >> 10, k = rel & 1023;
    float v = a.Wg2[(size_t)k * 512 + n];
    __hip_bfloat16 h = __float2bfloat16(v);
    a.Wg2_hi[rel] = h;
    a.Wg2_lo[rel] = __float2bfloat16(v - __bfloat162float(h));
  } else if (idx < 1775616) {
    int rel = idx - 1644544;
    int n = rel >> 9, k = rel & 511;
    float v = a.Wf1[(size_t)k * 256 + n];
    __hip_bfloat16 h = __float2bfloat16(v);
    a.Wf1_hi[rel] = h;
    a.Wf1_lo[rel] = __float2bfloat16(v - __bfloat162float(h));
  }
}

__global__ __launch_bounds__(256) void split_x_kernel(
    const float* __restrict__ x, __hip_bfloat16* __restrict__ hi, __hip_bfloat16* __restrict__ lo)
{
  int idx = blockIdx.x * 256 + threadIdx.x;
  if (idx >= NN * 64) return;
  int r = idx >> 6, c = idx & 63;
  float v = (c < FIN) ? x[(size_t)r * FIN + c] : 0.f;
  __hip_bfloat16 h = __float2bfloat16(v);
  hi[idx] = h;
  lo[idx] = __float2bfloat16(v - __bfloat162float(h));
}

// ============ CSR build over dst ============
__global__ __launch_bounds__(256) void count_kernel(const int* __restrict__ dst, int* __restrict__ cnt)
{
  int e = blockIdx.x * 256 + threadIdx.x;
  if (e < NE) atomicAdd(&cnt[dst[e]], 1);
}

__global__ __launch_bounds__(1024) void scan_kernel(const int* __restrict__ cnt, int* __restrict__ row_start)
{
  __shared__ int sums[1024];
  int t = threadIdx.x;
  const int per = (NN + 1023) / 1024;
  int beg = t * per;
  int end = beg + per; if (end > NN) end = NN; if (beg > NN) beg = NN;
  int s = 0;
  for (int i = beg; i < end; ++i) s += cnt[i];
  sums[t] = s;
  __syncthreads();
  for (int off = 1; off < 1024; off <<= 1) {
    int v = (t >= off) ? sums[t - off] : 0;
    __syncthreads();
    sums[t] += v;
    __syncthreads();
  }
  int prefix = (t == 0) ? 0 : sums[t - 1];
  for (int i = beg; i < end; ++i) { row_start[i] = prefix; prefix += cnt[i]; }
  if (t == 1023) row_start[NN] = prefix;
}

__global__ __launch_bounds__(256) void scatter_kernel(
    const int* __restrict__ src, const int* __restrict__ dst,
    const int* __restrict__ row_start,
    int* __restrict__ cursor, int* __restrict__ edge_list)
{
  int e = blockIdx.x * 256 + threadIdx.x;
  if (e < NE) {
    int d = dst[e];
    int p = atomicAdd(&cursor[d], 1);
    edge_list[row_start[d] + p] = src[e];
  }
}

// ============ fused attention: single-pass, defer-max, 4-edge unroll ============
// One block per dst node; wave w = head w; 16-lane subgroup keeps private (m,den,acc).
__global__ __launch_bounds__(256) void attn_kernel(
    const float* __restrict__ qs, const __half* __restrict__ kvh,
    const int* __restrict__ row_start, const int* __restrict__ edge_list,
    __hip_bfloat16* __restrict__ t0hi, __hip_bfloat16* __restrict__ t0lo)
{
  __shared__ int ssrc[CHUNK];
  const int node = blockIdx.x;
  const int tid = threadIdx.x;
  const int w = tid >> 6, lane = tid & 63;
  const int g4 = lane >> 4, sl = lane & 15;
  const int beg = row_start[node], end = row_start[node + 1];

  const float* qp = qs + (size_t)node * 1024 + w * 128 + 8 * sl;
  half2_t qh[4];
  {
    float4 qa = *(const float4*)qp;
    float4 qb = *(const float4*)(qp + 4);
    qh[0] = (half2_t){(_Float16)qa.x, (_Float16)qa.y};
    qh[1] = (half2_t){(_Float16)qa.z, (_Float16)qa.w};
    qh[2] = (half2_t){(_Float16)qb.x, (_Float16)qb.y};
    qh[3] = (half2_t){(_Float16)qb.z, (_Float16)qb.w};
  }

  float m = -INFINITY, den = 0.f;
  float a[8] = {0.f, 0.f, 0.f, 0.f, 0.f, 0.f, 0.f, 0.f};

  // defer-max: rescale only when p exceeds m by >8; terms bounded by e^8.
  auto upd = [&](float p, const float4& vraw) {
    const __half2* vh = (const __half2*)&vraw;
    float2 f0 = __half22float2(vh[0]);
    float2 f1 = __half22float2(vh[1]);
    float2 f2 = __half22float2(vh[2]);
    float2 f3 = __half22float2(vh[3]);
    if (__builtin_expect(p > m + 8.f, 0)) {
      float c = __expf(m - p);   // m=-inf first time -> 0
      den = den * c + 1.f;
      a[0] = a[0] * c + f0.x; a[1] = a[1] * c + f0.y;
      a[2] = a[2] * c + f1.x; a[3] = a[3] * c + f1.y;
      a[4] = a[4] * c + f2.x; a[5] = a[5] * c + f2.y;
      a[6] = a[6] * c + f3.x; a[7] = a[7] * c + f3.y;
      m = p;
    } else {
      float e = __expf(p - m);
      den += e;
      a[0] += e * f0.x; a[1] += e * f0.y;
      a[2] += e * f1.x; a[3] += e * f1.y;
      a[4] += e * f2.x; a[5] += e * f2.y;
      a[6] += e * f3.x; a[7] += e * f3.y;
    }
  };

  for (int c0 = beg; c0 < end; c0 += CHUNK) {
    int len = end - c0; if (len > CHUNK) len = CHUNK;
    __syncthreads();
    for (int i = tid; i < len; i += 256)
      ssrc[i] = edge_list[c0 + i];
    __syncthreads();

    // subgroup g4 takes edges {4*g4 .. 4*g4+3}, stride 16
    for (int j = 4 * g4; j < len; j += 16) {
      bool h1 = (j + 1 < len), h2 = (j + 2 < len), h3 = (j + 3 < len);
      int s0 = ssrc[j];
      int s1 = h1 ? ssrc[j + 1] : s0;
      int s2 = h2 ? ssrc[j + 2] : s0;
      int s3 = h3 ? ssrc[j + 3] : s0;
      const __half* b0 = kvh + (size_t)s0 * 1024 + w * 256 + 8 * sl;
      const __half* b1 = kvh + (size_t)s1 * 1024 + w * 256 + 8 * sl;
      const __half* b2 = kvh + (size_t)s2 * 1024 + w * 256 + 8 * sl;
      const __half* b3 = kvh + (size_t)s3 * 1024 + w * 256 + 8 * sl;
      float4 k0 = *(const float4*)b0;
      float4 k1 = *(const float4*)b1;
      float4 k2 = *(const float4*)b2;
      float4 k3 = *(const float4*)b3;
      float4 v0 = *(const float4*)(b0 + 128);
      float4 v1 = *(const float4*)(b1 + 128);
      float4 v2 = *(const float4*)(b2 + 128);
      float4 v3 = *(const float4*)(b3 + 128);

      const half2_t* kh0 = (const half2_t*)&k0;
      const half2_t* kh1 = (const half2_t*)&k1;
      const half2_t* kh2 = (const half2_t*)&k2;
      const half2_t* kh3 = (const half2_t*)&k3;
      float p0 = 0.f, p1 = 0.f, p2 = 0.f, p3 = 0.f;
#pragma unroll
      for (int i = 0; i < 4; ++i) {
        p0 = dot2acc(qh[i], kh0[i], p0);
        p1 = dot2acc(qh[i], kh1[i], p1);
        p2 = dot2acc(qh[i], kh2[i], p2);
        p3 = dot2acc(qh[i], kh3[i], p3);
      }
#pragma unroll
      for (int off = 8; off >= 1; off >>= 1) {
        p0 += __shfl_xor(p0, off);
        p1 += __shfl_xor(p1, off);
        p2 += __shfl_xor(p2, off);
        p3 += __shfl_xor(p3, off);
      }
      p0 *= ATT_SCALE; p1 *= ATT_SCALE; p2 *= ATT_SCALE; p3 *= ATT_SCALE;
      upd(p0, v0);
      if (h1) upd(p1, v1);
      if (h2) upd(p2, v2);
      if (h3) upd(p3, v3);
    }
  }

  // combine the 4 subgroups (online-softmax merge; m's are deferred maxima)
  float m2 = fmaxf(m, __shfl_xor(m, 16));
  float mAll = fmaxf(m2, __shfl_xor(m2, 32));
  float scale = (m == -INFINITY) ? 0.f : __expf(m - mAll);
  den *= scale;
  den += __shfl_xor(den, 16);
  den += __shfl_xor(den, 32);
#pragma unroll
  for (int i = 0; i < 8; ++i) {
    a[i] *= scale;
    a[i] += __shfl_xor(a[i], 16);
    a[i] += __shfl_xor(a[i], 32);
  }

  if (g4 == 0) {
    float inv = 1.f / fmaxf(den, 1e-16f);
    const float* sp = qs + (size_t)node * 1024 + 512 + w * 128 + 8 * sl;
    short8v hi8, lo8;
#pragma unroll
    for (int i = 0; i < 8; ++i) {
      float v = a[i] * inv + sp[i];
      __hip_bfloat16 hv = __float2bfloat16(v);
      __hip_bfloat16 lv = __float2bfloat16(v - __bfloat162float(hv));
      hi8[i] = *(short*)&hv;
      lo8[i] = *(short*)&lv;
    }
    size_t o = (size_t)node * HC + w * 128 + 8 * sl;
    *(short8v*)(t0hi + o) = hi8;
    *(short8v*)(t0lo + o) = lo8;
  }
}

// ============ pooling (run-compressed: batch is sorted) ============
__global__ __launch_bounds__(256) void pool_init_kernel(float* __restrict__ gm, float* __restrict__ gsum, int* __restrict__ gcnt)
{
  int i = blockIdx.x * 256 + threadIdx.x;
  if (i < NB * HD) { ((int*)gm)[i] = 0xFF800000; gsum[i] = 0.f; }
  if (i < NB) gcnt[i] = 0;
}

#define PN 32  // nodes per block
__global__ __launch_bounds__(256) void pool_kernel(
    const float* __restrict__ h, const int* __restrict__ batch,
    float* __restrict__ gm, float* __restrict__ gsum, int* __restrict__ gcnt)
{
  __shared__ int sbatch[PN];
  const int base = blockIdx.x * PN;
  const int tid = threadIdx.x;
  if (tid < PN) {
    int n = base + tid;
    sbatch[tid] = (n < NN) ? batch[n] : -1;
  }
  __syncthreads();
  const int c = tid & 127;
  const int half = tid >> 7;
  const int i0 = half * (PN / 2), i1 = i0 + PN / 2;

  float sum = 0.f, mx = -INFINITY;
  int cur = sbatch[i0];
  bool any = false;
  for (int i = i0; i < i1; ++i) {
    int n = base + i;
    if (n >= NN) break;
    int b = sbatch[i];
    if (b != cur) {
      if (any) {
        atomicAdd(&gsum[(size_t)cur * HD + c], sum);
        atomicMax((int*)&gm[(size_t)cur * HD + c], __float_as_int(mx));
      }
      sum = 0.f; mx = -INFINITY; cur = b; any = false;
    }
    float val = h[(size_t)n * HD + c];
    sum += val; mx = fmaxf(mx, val);
    any = true;
  }
  if (any && cur >= 0) {
    atomicAdd(&gsum[(size_t)cur * HD + c], sum);
    atomicMax((int*)&gm[(size_t)cur * HD + c], __float_as_int(mx));
  }
  if (c == 0) {
    int cnt = 0; int cb = sbatch[i0];
    for (int i = i0; i < i1; ++i) {
      int n = base + i;
      if (n >= NN) break;
      if (sbatch[i] != cb) {
        if (cnt > 0 && cb >= 0) atomicAdd(&gcnt[cb], cnt);
        cnt = 0; cb = sbatch[i];
      }
      cnt++;
    }
    if (cnt > 0 && cb >= 0) atomicAdd(&gcnt[cb], cnt);
  }
}

__global__ __launch_bounds__(256) void pool_finalize_kernel(
    const float* __restrict__ gm, const float* __restrict__ gsum,
    const int* __restrict__ gcnt, float* __restrict__ g,
    __hip_bfloat16* __restrict__ ghi, __hip_bfloat16* __restrict__ glo)
{
  int idx = blockIdx.x * 256 + threadIdx.x;
  if (idx >= NB * HD) return;
  int b = idx >> 7, c = idx & 127;
  float mv = gm[idx];
  if (mv < -1e30f) mv = 0.f;
  float cf = (float)gcnt[b];
  float av = gsum[idx] / fmaxf(cf, 1.f);
  size_t o0 = (size_t)b * 256 + c;
  size_t o1 = o0 + 128;
  g[o0] = mv; g[o1] = av;
  __hip_bfloat16 h0 = __float2bfloat16(mv);
  __hip_bfloat16 h1 = __float2bfloat16(av);
  ghi[o0] = h0; glo[o0] = __float2bfloat16(mv - __bfloat162float(h0));
  ghi[o1] = h1; glo[o1] = __float2bfloat16(av - __bfloat162float(h1));
}

// ============ final head layer: [512,256] @ [256,1] + b ============
__global__ __launch_bounds__(256) void head4_kernel(
    const float* __restrict__ g3, const float* __restrict__ Wf2,
    const float* __restrict__ bf2, float* __restrict__ out)
{
  int w = threadIdx.x >> 6, lane = threadIdx.x & 63;
  int row = blockIdx.x * 4 + w;
  const float* r = g3 + (size_t)row * 256;
  float p = r[lane] * Wf2[lane] + r[64 + lane] * Wf2[64 + lane]
          + r[128 + lane] * Wf2[128 + lane] + r[192 + lane] * Wf2[192 + lane];
#pragma unroll
  for (int off = 32; off >= 1; off >>= 1) p += __shfl_xor(p, off);
  if (lane == 0) out[row] = p + bf2[0];
}

extern "C" void kernel_launch(void* const* d_in, const int* in_sizes, int n_in,
                              void* d_out, int out_size, void* d_ws, size_t ws_size,
                              hipStream_t stream)
{
  const float* x = (const float*)d_in[0];
  const int* edge_index = (const int*)d_in[1];
  const int* batch = (const int*)d_in[2];
  const int* src = edge_index;
  const int* dstv = edge_index + NE;

  const float *Wq[3], *bq[3], *Wk[3], *bk[3], *Wv[3], *bv[3], *Wsk[3], *bsk[3], *Wm[3], *bm[3];
  int base = 3;
  for (int l = 0; l < 3; ++l) {
    Wq[l]  = (const float*)d_in[base + 0]; bq[l]  = (const float*)d_in[base + 1];
    Wk[l]  = (const float*)d_in[base + 2]; bk[l]  = (const float*)d_in[base + 3];
    Wv[l]  = (const float*)d_in[base + 4]; bv[l]  = (const float*)d_in[base + 5];
    Wsk[l] = (const float*)d_in[base + 6]; bsk[l] = (const float*)d_in[base + 7];
    Wm[l]  = (const float*)d_in[base + 8]; bm[l]  = (const float*)d_in[base + 9];
    base += 10;
  }
  const float* Wg1 = (const float*)d_in[33]; const float* bg1 = (const float*)d_in[34];
  const float* Wg2 = (const float*)d_in[35]; const float* bg2 = (const float*)d_in[36];
  const float* Wf1 = (const float*)d_in[37]; const float* bf1 = (const float*)d_in[38];
  const float* Wf2 = (const float*)d_in[39]; const float* bf2 = (const float*)d_in[40];

  // ---- workspace layout ----
  char* p = (char*)d_ws;
  auto alloc = [&](size_t bytes) { char* r = p; p += (bytes + 255) & ~(size_t)255; return r; };
  float* qs   = (float*)alloc((size_t)MPAD * 1024 * 4);    // Q | S  fp32
  __half* kvh = (__half*)alloc((size_t)MPAD * 1024 * 2);   // per head: K(128)|V(128) fp16
  float* h    = (float*)alloc((size_t)NN * HD * 4);
  __hip_bfloat16* t0hi = (__hip_bfloat16*)alloc((size_t)MPAD * HC * 2);
  __hip_bfloat16* t0lo = (__hip_bfloat16*)alloc((size_t)MPAD * HC * 2);
  __hip_bfloat16* hhi  = (__hip_bfloat16*)alloc((size_t)MPAD * HD * 2);
  __hip_bfloat16* hlo  = (__hip_bfloat16*)alloc((size_t)MPAD * HD * 2);
  __hip_bfloat16* xhi  = (__hip_bfloat16*)alloc((size_t)MPAD * 64 * 2);
  __hip_bfloat16* xlo  = (__hip_bfloat16*)alloc((size_t)MPAD * 64 * 2);
  __hip_bfloat16* Wp_hi[3], *Wp_lo[3], *Wm_hi[3], *Wm_lo[3];
  Wp_hi[0] = (__hip_bfloat16*)alloc((size_t)2048 * 64 * 2);
  Wp_lo[0] = (__hip_bfloat16*)alloc((size_t)2048 * 64 * 2);
  for (int l = 1; l < 3; ++l) {
    Wp_hi[l] = (__hip_bfloat16*)alloc((size_t)2048 * 128 * 2);
    Wp_lo[l] = (__hip_bfloat16*)alloc((size_t)2048 * 128 * 2);
  }
  for (int l = 0; l < 3; ++l) {
    Wm_hi[l] = (__hip_bfloat16*)alloc((size_t)128 * 512 * 2);
    Wm_lo[l] = (__hip_bfloat16*)alloc((size_t)128 * 512 * 2);
  }
  __hip_bfloat16* Wg1_hi = (__hip_bfloat16*)alloc((size_t)1024 * 256 * 2);
  __hip_bfloat16* Wg1_lo = (__hip_bfloat16*)alloc((size_t)1024 * 256 * 2);
  __hip_bfloat16* Wg2_hi = (__hip_bfloat16*)alloc((size_t)512 * 1024 * 2);
  __hip_bfloat16* Wg2_lo = (__hip_bfloat16*)alloc((size_t)512 * 1024 * 2);
  __hip_bfloat16* Wf1_hi = (__hip_bfloat16*)alloc((size_t)256 * 512 * 2);
  __hip_bfloat16* Wf1_lo = (__hip_bfloat16*)alloc((size_t)256 * 512 * 2);
  float* bpack = (float*)alloc(3 * 2048 * 4);
  float* gm   = (float*)alloc((size_t)NB * HD * 4);
  float* gsum = (float*)alloc((size_t)NB * HD * 4);
  float* g    = (float*)alloc((size_t)NB * 256 * 4);
  __hip_bfloat16* ghi = (__hip_bfloat16*)alloc((size_t)NB * 256 * 2);
  __hip_bfloat16* glo = (__hip_bfloat16*)alloc((size_t)NB * 256 * 2);
  float* g1 = (float*)alloc((size_t)NB * 1024 * 4);
  __hip_bfloat16* g1hi = (__hip_bfloat16*)alloc((size_t)NB * 1024 * 2);
  __hip_bfloat16* g1lo = (__hip_bfloat16*)alloc((size_t)NB * 1024 * 2);
  float* g2 = (float*)alloc((size_t)NB * 512 * 4);
  __hip_bfloat16* g2hi = (__hip_bfloat16*)alloc((size_t)NB * 512 * 2);
  __hip_bfloat16* g2lo = (__hip_bfloat16*)alloc((size_t)NB * 512 * 2);
  float* g3 = (float*)alloc((size_t)NB * 256 * 4);
  __hip_bfloat16* g3hi = (__hip_bfloat16*)alloc((size_t)NB * 256 * 2);
  __hip_bfloat16* g3lo = (__hip_bfloat16*)alloc((size_t)NB * 256 * 2);
  int* icnt      = (int*)alloc(NN * 4);
  int* cursor    = (int*)alloc(NN * 4);
  int* row_start = (int*)alloc((NN + 1) * 4);
  int* edge_list = (int*)alloc((size_t)NE * 4);
  int* gcnt      = (int*)alloc(NB * 4);

  const int GR128 = (NN + 127) / 128;  // 157
  const int GR64  = (NN + 63) / 64;    // 313

  // ---- pack all weights/biases ----
  PackArgs pa;
  for (int l = 0; l < 3; ++l) {
    pa.W[l * 4 + 0] = Wq[l];  pa.W[l * 4 + 1] = Wk[l];
    pa.W[l * 4 + 2] = Wv[l];  pa.W[l * 4 + 3] = Wsk[l];
    pa.b[l * 4 + 0] = bq[l];  pa.b[l * 4 + 1] = bk[l];
    pa.b[l * 4 + 2] = bv[l];  pa.b[l * 4 + 3] = bsk[l];
    pa.Wm[l] = Wm[l];
    pa.Wp_hi[l] = Wp_hi[l]; pa.Wp_lo[l] = Wp_lo[l];
    pa.Wm_hi[l] = Wm_hi[l]; pa.Wm_lo[l] = Wm_lo[l];
  }
  pa.Wg1 = Wg1; pa.Wg2 = Wg2; pa.Wf1 = Wf1;
  pa.Wg1_hi = Wg1_hi; pa.Wg1_lo = Wg1_lo;
  pa.Wg2_hi = Wg2_hi; pa.Wg2_lo = Wg2_lo;
  pa.Wf1_hi = Wf1_hi; pa.Wf1_lo = Wf1_lo;
  pa.bpack = bpack;
  pack_all_kernel<<<(1775616 + 255) / 256, 256, 0, stream>>>(pa);

  // ---- CSR build ----
  hipMemsetAsync(icnt, 0, sizeof(int) * NN, stream);
  hipMemsetAsync(cursor, 0, sizeof(int) * NN, stream);
  count_kernel<<<(NE + 255) / 256, 256, 0, stream>>>(dstv, icnt);
  scan_kernel<<<1, 1024, 0, stream>>>(icnt, row_start);
  scatter_kernel<<<(NE + 255) / 256, 256, 0, stream>>>(src, dstv, row_start, cursor, edge_list);

  // ---- input split ----
  split_x_kernel<<<(NN * 64 + 255) / 256, 256, 0, stream>>>(x, xhi, xlo);

  // ---- 3 TransformerConv layers ----
  for (int l = 0; l < 3; ++l) {
    int Kpad = (l == 0) ? 64 : 128;
    const __hip_bfloat16* Ahi = (l == 0) ? xhi : hhi;
    const __hip_bfloat16* Alo = (l == 0) ? xlo : hlo;

    // col-fastest grid: the 16 col-blocks sharing an A row-block are consecutive bids
    gemm_mfma_kernel<2><<<dim3(16, GR128), 256, 0, stream>>>(
        Ahi, Alo, Kpad, Wp_hi[l], Wp_lo[l], bpack + l * 2048, qs, 1024,
        nullptr, nullptr, kvh, NN, Kpad);

    attn_kernel<<<NN, 256, 0, stream>>>(qs, kvh, row_start, edge_list, t0hi, t0lo);

    gemm64_kernel<<<dim3(GR64, 1), 256, 0, stream>>>(
        t0hi, t0lo, HC, Wm_hi[l], Wm_lo[l], bm[l], h, HD, hhi, hlo, NN, HC);
  }

  // ---- pooling ----
  pool_init_kernel<<<(NB * HD + 255) / 256, 256, 0, stream>>>(gm, gsum, gcnt);
  pool_kernel<<<(NN + PN - 1) / PN, 256, 0, stream>>>(h, batch, gm, gsum, gcnt);
  pool_finalize_kernel<<<(NB * HD + 255) / 256, 256, 0, stream>>>(gm, gsum, gcnt, g, ghi, glo);

  // ---- MLP head via MFMA (64-row tiles) ----
  gemm64_kernel<<<dim3(8, 8), 256, 0, stream>>>(
      ghi, glo, 256, Wg1_hi, Wg1_lo, bg1, g1, 1024, g1hi, g1lo, NB, 256);
  gemm64_kernel<<<dim3(8, 4), 256, 0, stream>>>(
      g1hi, g1lo, 1024, Wg2_hi, Wg2_lo, bg2, g2, 512, g2hi, g2lo, NB, 1024);
  gemm64_kernel<<<dim3(8, 2), 256, 0, stream>>>(
      g2hi, g2lo, 512, Wf1_hi, Wf1_lo, bf1, g3, 256, g3hi, g3lo, NB, 512);
  head4_kernel<<<NB / 4, 256, 0, stream>>>(g3, Wf2, bf2, (float*)d_out);
}

// Round 8
// 713.587 us; speedup vs baseline: 2.9478x; 1.0002x over previous
//
#include <hip/hip_runtime.h>
#include <hip/hip_bf16.h>
#include <hip/hip_fp16.h>
#include <math.h>

#define NN 20000
#define MPAD 20096          // row padding for MFMA staging (mult of 128)
#define NE 320000
#define NB 512
#define FIN 43
#define HD 128
#define HC 512
#define ATT_SCALE 0.08838834764831843f

typedef __attribute__((ext_vector_type(8))) short bf16x8v;
typedef __attribute__((ext_vector_type(8))) short short8v;
typedef __attribute__((ext_vector_type(4))) float f32x4v;
typedef _Float16 half2_t __attribute__((ext_vector_type(2)));

__device__ __forceinline__ void gload16(void* lds, const void* g) {
  __builtin_amdgcn_global_load_lds(
      (const __attribute__((address_space(1))) void*)g,
      (__attribute__((address_space(3))) void*)lds, 16, 0, 0);
}

__device__ __forceinline__ float dot2acc(half2_t a, half2_t b, float c) {
#if __has_builtin(__builtin_amdgcn_fdot2)
  return __builtin_amdgcn_fdot2(a, b, c, false);
#else
  return c + (float)a[0] * (float)b[0] + (float)a[1] * (float)b[1];
#endif
}

// ============ split-bf16 MFMA GEMM, 128x128 tile ============
// MODE 1: relu, fp32 Y [M][ldY], bf16 hi/lo split Yhi/Ylo
// MODE 2: qkvs (grid COL-FASTEST: blockIdx.x = col-block, blockIdx.y = row-block)
//         cols [0,512):    fp16 Q -> qh[row*512+col]            (qh passed via Yhi)
//         cols [512,1024): K head h -> kvh[row*1024 + h*256 + c]
//         cols [1024,1536):V head h -> kvh[row*1024 + h*256 + 128 + c]
//         cols [1536,2048):fp32 S -> Y[row*512 + col-1536]      (Y = ss)
template<int MODE>
__global__ __launch_bounds__(256, 2) void gemm_mfma_kernel(
    const __hip_bfloat16* __restrict__ Ahi_, const __hip_bfloat16* __restrict__ Alo_, int ldA,
    const __hip_bfloat16* __restrict__ Bhi_, const __hip_bfloat16* __restrict__ Blo_,
    const float* __restrict__ bias,
    float* __restrict__ Y, int ldY,
    __hip_bfloat16* __restrict__ Yhi, __hip_bfloat16* __restrict__ Ylo,
    __half* __restrict__ kvh,
    int M, int K)
{
  __shared__ short Ah[128 * 64], Al[128 * 64], Bh[128 * 64], Bl[128 * 64];
  const short* Ahi = (const short*)Ahi_;
  const short* Alo = (const short*)Alo_;
  const short* Bhi = (const short*)Bhi_;
  const short* Blo = (const short*)Blo_;
  const int tid = threadIdx.x;
  const int w = tid >> 6, lane = tid & 63;
  const int bx = (MODE == 2) ? blockIdx.y : blockIdx.x;   // row-block
  const int by = (MODE == 2) ? blockIdx.x : blockIdx.y;   // col-block
  const int rowBase = bx * 128, colBase = by * 128;
  const int srow = lane >> 3;
  const int sw = ((lane & 7) ^ srow) << 3;
  const int lr = lane & 15, lg = lane >> 4;
  const int wr = w >> 1, wc = w & 1;

  f32x4v acc[4][4];
#pragma unroll
  for (int m = 0; m < 4; ++m)
#pragma unroll
    for (int n = 0; n < 4; ++n) acc[m][n] = (f32x4v){0.f, 0.f, 0.f, 0.f};

  for (int k0 = 0; k0 < K; k0 += 64) {
    if (k0) __syncthreads();
#pragma unroll
    for (int t = 0; t < 4; ++t) {
      int r0 = w * 32 + t * 8;
      size_t arow = (size_t)(rowBase + r0 + srow) * ldA + k0 + sw;
      size_t brow = (size_t)(colBase + r0 + srow) * K + k0 + sw;
      gload16(&Ah[r0 * 64], Ahi + arow);
      gload16(&Al[r0 * 64], Alo + arow);
      gload16(&Bh[r0 * 64], Bhi + brow);
      gload16(&Bl[r0 * 64], Blo + brow);
    }
    __syncthreads();
#pragma unroll
    for (int kk = 0; kk < 2; ++kk) {
      bf16x8v ah[4], al[4], bh[4], bl[4];
      int cbase = ((kk * 4 + lg) ^ (lr & 7)) * 8;
#pragma unroll
      for (int m = 0; m < 4; ++m) {
        int idx = (wr * 64 + m * 16 + lr) * 64 + cbase;
        ah[m] = *(const bf16x8v*)&Ah[idx];
        al[m] = *(const bf16x8v*)&Al[idx];
      }
#pragma unroll
      for (int n = 0; n < 4; ++n) {
        int idx = (wc * 64 + n * 16 + lr) * 64 + cbase;
        bh[n] = *(const bf16x8v*)&Bh[idx];
        bl[n] = *(const bf16x8v*)&Bl[idx];
      }
#pragma unroll
      for (int m = 0; m < 4; ++m)
#pragma unroll
        for (int n = 0; n < 4; ++n) {
          acc[m][n] = __builtin_amdgcn_mfma_f32_16x16x32_bf16(ah[m], bh[n], acc[m][n], 0, 0, 0);
          acc[m][n] = __builtin_amdgcn_mfma_f32_16x16x32_bf16(ah[m], bl[n], acc[m][n], 0, 0, 0);
          acc[m][n] = __builtin_amdgcn_mfma_f32_16x16x32_bf16(al[m], bh[n], acc[m][n], 0, 0, 0);
        }
    }
  }
#pragma unroll
  for (int m = 0; m < 4; ++m) {
#pragma unroll
    for (int n = 0; n < 4; ++n) {
      int col = colBase + wc * 64 + n * 16 + lr;
      float bb = bias[col];
#pragma unroll
      for (int r = 0; r < 4; ++r) {
        int row = rowBase + wr * 64 + m * 16 + lg * 4 + r;
        if (row < M) {
          float v = acc[m][n][r] + bb;
          if (MODE == 1) {
            v = fmaxf(v, 0.f);
            Y[(size_t)row * ldY + col] = v;
            __hip_bfloat16 hv = __float2bfloat16(v);
            Yhi[(size_t)row * ldY + col] = hv;
            Ylo[(size_t)row * ldY + col] = __float2bfloat16(v - __bfloat162float(hv));
          } else {
            if (col < 512) {
              ((__half*)Yhi)[(size_t)row * 512 + col] = __float2half(v);
            } else if (col < 1024) {
              int cc = col - 512;
              kvh[(size_t)row * 1024 + (cc >> 7) * 256 + (cc & 127)] = __float2half(v);
            } else if (col < 1536) {
              int cc = col - 1024;
              kvh[(size_t)row * 1024 + (cc >> 7) * 256 + 128 + (cc & 127)] = __float2half(v);
            } else {
              Y[(size_t)row * 512 + col - 1536] = v;
            }
          }
        }
      }
    }
  }
}

// ============ split-bf16 MFMA GEMM, 64x128 tile (proj + head) ============
__global__ __launch_bounds__(256, 2) void gemm64_kernel(
    const __hip_bfloat16* __restrict__ Ahi_, const __hip_bfloat16* __restrict__ Alo_, int ldA,
    const __hip_bfloat16* __restrict__ Bhi_, const __hip_bfloat16* __restrict__ Blo_,
    const float* __restrict__ bias,
    float* __restrict__ Y, int ldY,
    __hip_bfloat16* __restrict__ Yhi, __hip_bfloat16* __restrict__ Ylo,
    int M, int K)
{
  __shared__ short Ah[64 * 64], Al[64 * 64], Bh[128 * 64], Bl[128 * 64];
  const short* Ahi = (const short*)Ahi_;
  const short* Alo = (const short*)Alo_;
  const short* Bhi = (const short*)Bhi_;
  const short* Blo = (const short*)Blo_;
  const int tid = threadIdx.x;
  const int w = tid >> 6, lane = tid & 63;
  const int rowBase = blockIdx.x * 64, colBase = blockIdx.y * 128;
  const int srow = lane >> 3;
  const int sw = ((lane & 7) ^ srow) << 3;
  const int lr = lane & 15, lg = lane >> 4;
  const int wr = w >> 1, wc = w & 1;

  f32x4v acc[2][4];
#pragma unroll
  for (int m = 0; m < 2; ++m)
#pragma unroll
    for (int n = 0; n < 4; ++n) acc[m][n] = (f32x4v){0.f, 0.f, 0.f, 0.f};

  for (int k0 = 0; k0 < K; k0 += 64) {
    if (k0) __syncthreads();
#pragma unroll
    for (int t = 0; t < 2; ++t) {
      int r0 = w * 16 + t * 8;
      size_t arow = (size_t)(rowBase + r0 + srow) * ldA + k0 + sw;
      gload16(&Ah[r0 * 64], Ahi + arow);
      gload16(&Al[r0 * 64], Alo + arow);
    }
#pragma unroll
    for (int t = 0; t < 4; ++t) {
      int r0 = w * 32 + t * 8;
      size_t brow = (size_t)(colBase + r0 + srow) * K + k0 + sw;
      gload16(&Bh[r0 * 64], Bhi + brow);
      gload16(&Bl[r0 * 64], Blo + brow);
    }
    __syncthreads();
#pragma unroll
    for (int kk = 0; kk < 2; ++kk) {
      bf16x8v ah[2], al[2], bh[4], bl[4];
      int cbase = ((kk * 4 + lg) ^ (lr & 7)) * 8;
#pragma unroll
      for (int m = 0; m < 2; ++m) {
        int idx = (wr * 32 + m * 16 + lr) * 64 + cbase;
        ah[m] = *(const bf16x8v*)&Ah[idx];
        al[m] = *(const bf16x8v*)&Al[idx];
      }
#pragma unroll
      for (int n = 0; n < 4; ++n) {
        int idx = (wc * 64 + n * 16 + lr) * 64 + cbase;
        bh[n] = *(const bf16x8v*)&Bh[idx];
        bl[n] = *(const bf16x8v*)&Bl[idx];
      }
#pragma unroll
      for (int m = 0; m < 2; ++m)
#pragma unroll
        for (int n = 0; n < 4; ++n) {
          acc[m][n] = __builtin_amdgcn_mfma_f32_16x16x32_bf16(ah[m], bh[n], acc[m][n], 0, 0, 0);
          acc[m][n] = __builtin_amdgcn_mfma_f32_16x16x32_bf16(ah[m], bl[n], acc[m][n], 0, 0, 0);
          acc[m][n] = __builtin_amdgcn_mfma_f32_16x16x32_bf16(al[m], bh[n], acc[m][n], 0, 0, 0);
        }
    }
  }
#pragma unroll
  for (int m = 0; m < 2; ++m) {
#pragma unroll
    for (int n = 0; n < 4; ++n) {
      int col = colBase + wc * 64 + n * 16 + lr;
      float bb = bias[col];
#pragma unroll
      for (int r = 0; r < 4; ++r) {
        int row = rowBase + wr * 32 + m * 16 + lg * 4 + r;
        if (row < M) {
          float v = fmaxf(acc[m][n][r] + bb, 0.f);
          Y[(size_t)row * ldY + col] = v;
          __hip_bfloat16 hv = __float2bfloat16(v);
          Yhi[(size_t)row * ldY + col] = hv;
          Ylo[(size_t)row * ldY + col] = __float2bfloat16(v - __bfloat162float(hv));
        }
      }
    }
  }
}

// ============ pack everything in one launch ============
struct PackArgs {
  const float* W[12];     // [l*4 + {q,k,v,s}]  shape [K][512]
  const float* b[12];
  const float* Wm[3];     // [512][128]
  const float *Wg1, *Wg2, *Wf1;
  __hip_bfloat16 *Wp_hi[3], *Wp_lo[3];   // [2048][Kpad]
  __hip_bfloat16 *Wm_hi[3], *Wm_lo[3];   // [128][512]
  __hip_bfloat16 *Wg1_hi, *Wg1_lo;       // [1024][256]
  __hip_bfloat16 *Wg2_hi, *Wg2_lo;       // [512][1024]
  __hip_bfloat16 *Wf1_hi, *Wf1_lo;       // [256][512]
  float* bpack;                           // [3][2048]
};

__global__ __launch_bounds__(256) void pack_all_kernel(PackArgs a)
{
  int idx = blockIdx.x * 256 + threadIdx.x;
  if (idx < 131072) {
    int n = idx >> 6, k = idx & 63;
    int mat = n >> 9, nn = n & 511;
    float v = (k < FIN) ? a.W[mat][(size_t)k * 512 + nn] : 0.f;
    __hip_bfloat16 h = __float2bfloat16(v);
    a.Wp_hi[0][idx] = h;
    a.Wp_lo[0][idx] = __float2bfloat16(v - __bfloat162float(h));
  } else if (idx < 655360) {
    int rel = idx - 131072;
    int l = 1 + (rel >> 18);
    int r2 = rel & 262143;
    int n = r2 >> 7, k = r2 & 127;
    int mat = n >> 9, nn = n & 511;
    float v = a.W[l * 4 + mat][(size_t)k * 512 + nn];
    __hip_bfloat16 h = __float2bfloat16(v);
    a.Wp_hi[l][r2] = h;
    a.Wp_lo[l][r2] = __float2bfloat16(v - __bfloat162float(h));
  } else if (idx < 851968) {
    int rel = idx - 655360;
    int l = rel >> 16;
    int r2 = rel & 65535;
    int n = r2 >> 9, k = r2 & 511;
    float v = a.Wm[l][(size_t)k * 128 + n];
    __hip_bfloat16 h = __float2bfloat16(v);
    a.Wm_hi[l][r2] = h;
    a.Wm_lo[l][r2] = __float2bfloat16(v - __bfloat162float(h));
  } else if (idx < 858112) {
    int rel = idx - 851968;
    int l = rel >> 11, c = rel & 2047;
    a.bpack[rel] = a.b[l * 4 + (c >> 9)][c & 511];
  } else if (idx < 1120256) {
    int rel = idx - 858112;
    int n = rel >> 8, k = rel & 255;
    float v = a.Wg1[(size_t)k * 1024 + n];
    __hip_bfloat16 h = __float2bfloat16(v);
    a.Wg1_hi[rel] = h;
    a.Wg1_lo[rel] = __float2bfloat16(v - __bfloat162float(h));
  } else if (idx < 1644544) {
    int rel = idx - 1120256;
    int n = rel >> 10, k = rel & 1023;
    float v = a.Wg2[(size_t)k * 512 + n];
    __hip_bfloat16 h = __float2bfloat16(v);
    a.Wg2_hi[rel] = h;
    a.Wg2_lo[rel] = __float2bfloat16(v - __bfloat162float(h));
  } else if (idx < 1775616) {
    int rel = idx - 1644544;
    int n = rel >> 9, k = rel & 511;
    float v = a.Wf1[(size_t)k * 256 + n];
    __hip_bfloat16 h = __float2bfloat16(v);
    a.Wf1_hi[rel] = h;
    a.Wf1_lo[rel] = __float2bfloat16(v - __bfloat162float(h));
  }
}

__global__ __launch_bounds__(256) void split_x_kernel(
    const float* __restrict__ x, __hip_bfloat16* __restrict__ hi, __hip_bfloat16* __restrict__ lo)
{
  int idx = blockIdx.x * 256 + threadIdx.x;
  if (idx >= NN * 64) return;
  int r = idx >> 6, c = idx & 63;
  float v = (c < FIN) ? x[(size_t)r * FIN + c] : 0.f;
  __hip_bfloat16 h = __float2bfloat16(v);
  hi[idx] = h;
  lo[idx] = __float2bfloat16(v - __bfloat162float(h));
}

// ============ CSR build over dst ============
__global__ __launch_bounds__(256) void count_kernel(const int* __restrict__ dst, int* __restrict__ cnt)
{
  int e = blockIdx.x * 256 + threadIdx.x;
  if (e < NE) atomicAdd(&cnt[dst[e]], 1);
}

__global__ __launch_bounds__(1024) void scan_kernel(const int* __restrict__ cnt, int* __restrict__ row_start)
{
  __shared__ int sums[1024];
  int t = threadIdx.x;
  const int per = (NN + 1023) / 1024;
  int beg = t * per;
  int end = beg + per; if (end > NN) end = NN; if (beg > NN) beg = NN;
  int s = 0;
  for (int i = beg; i < end; ++i) s += cnt[i];
  sums[t] = s;
  __syncthreads();
  for (int off = 1; off < 1024; off <<= 1) {
    int v = (t >= off) ? sums[t - off] : 0;
    __syncthreads();
    sums[t] += v;
    __syncthreads();
  }
  int prefix = (t == 0) ? 0 : sums[t - 1];
  for (int i = beg; i < end; ++i) { row_start[i] = prefix; prefix += cnt[i]; }
  if (t == 1023) row_start[NN] = prefix;
}

__global__ __launch_bounds__(256) void scatter_kernel(
    const int* __restrict__ src, const int* __restrict__ dst,
    const int* __restrict__ row_start,
    int* __restrict__ cursor, int* __restrict__ edge_list)
{
  int e = blockIdx.x * 256 + threadIdx.x;
  if (e < NE) {
    int d = dst[e];
    int p = atomicAdd(&cursor[d], 1);
    edge_list[row_start[d] + p] = src[e];
  }
}

// ============ fused attention: single-pass, defer-max, barrier-free ============
// One block per dst node; wave w = head w; 16-lane subgroup keeps private (m,den,acc).
// Edge ids read directly from edge_list (broadcast within subgroup) — no LDS, no barriers.
__global__ __launch_bounds__(256) void attn_kernel(
    const __half* __restrict__ qh16, const float* __restrict__ ss,
    const __half* __restrict__ kvh,
    const int* __restrict__ row_start, const int* __restrict__ edge_list,
    __hip_bfloat16* __restrict__ t0hi, __hip_bfloat16* __restrict__ t0lo)
{
  const int node = blockIdx.x;
  const int tid = threadIdx.x;
  const int w = tid >> 6, lane = tid & 63;
  const int g4 = lane >> 4, sl = lane & 15;
  const int beg = row_start[node], cnt = row_start[node + 1] - beg;

  float4 qraw = *(const float4*)(qh16 + (size_t)node * 512 + w * 128 + 8 * sl);
  const half2_t* qh = (const half2_t*)&qraw;

  float m = -INFINITY, den = 0.f;
  float a[8] = {0.f, 0.f, 0.f, 0.f, 0.f, 0.f, 0.f, 0.f};

  // defer-max: rescale only when p exceeds m by >8; terms bounded by e^8.
  auto upd = [&](float p, const float4& vraw) {
    const __half2* vh = (const __half2*)&vraw;
    float2 f0 = __half22float2(vh[0]);
    float2 f1 = __half22float2(vh[1]);
    float2 f2 = __half22float2(vh[2]);
    float2 f3 = __half22float2(vh[3]);
    if (__builtin_expect(p > m + 8.f, 0)) {
      float c = __expf(m - p);   // m=-inf first time -> 0
      den = den * c + 1.f;
      a[0] = a[0] * c + f0.x; a[1] = a[1] * c + f0.y;
      a[2] = a[2] * c + f1.x; a[3] = a[3] * c + f1.y;
      a[4] = a[4] * c + f2.x; a[5] = a[5] * c + f2.y;
      a[6] = a[6] * c + f3.x; a[7] = a[7] * c + f3.y;
      m = p;
    } else {
      float e = __expf(p - m);
      den += e;
      a[0] += e * f0.x; a[1] += e * f0.y;
      a[2] += e * f1.x; a[3] += e * f1.y;
      a[4] += e * f2.x; a[5] += e * f2.y;
      a[6] += e * f3.x; a[7] += e * f3.y;
    }
  };

  const int* el = edge_list + beg;
  // subgroup g4 owns edges {4*g4 .. 4*g4+3}, stride 16
  for (int j = 4 * g4; j < cnt; j += 16) {
    bool h1 = (j + 1 < cnt), h2 = (j + 2 < cnt), h3 = (j + 3 < cnt);
    int s0 = el[j];
    int s1 = h1 ? el[j + 1] : s0;
    int s2 = h2 ? el[j + 2] : s0;
    int s3 = h3 ? el[j + 3] : s0;
    const __half* b0 = kvh + (size_t)s0 * 1024 + w * 256 + 8 * sl;
    const __half* b1 = kvh + (size_t)s1 * 1024 + w * 256 + 8 * sl;
    const __half* b2 = kvh + (size_t)s2 * 1024 + w * 256 + 8 * sl;
    const __half* b3 = kvh + (size_t)s3 * 1024 + w * 256 + 8 * sl;
    float4 k0 = *(const float4*)b0;
    float4 k1 = *(const float4*)b1;
    float4 k2 = *(const float4*)b2;
    float4 k3 = *(const float4*)b3;
    float4 v0 = *(const float4*)(b0 + 128);
    float4 v1 = *(const float4*)(b1 + 128);
    float4 v2 = *(const float4*)(b2 + 128);
    float4 v3 = *(const float4*)(b3 + 128);

    const half2_t* kh0 = (const half2_t*)&k0;
    const half2_t* kh1 = (const half2_t*)&k1;
    const half2_t* kh2 = (const half2_t*)&k2;
    const half2_t* kh3 = (const half2_t*)&k3;
    float p0 = 0.f, p1 = 0.f, p2 = 0.f, p3 = 0.f;
#pragma unroll
    for (int i = 0; i < 4; ++i) {
      p0 = dot2acc(qh[i], kh0[i], p0);
      p1 = dot2acc(qh[i], kh1[i], p1);
      p2 = dot2acc(qh[i], kh2[i], p2);
      p3 = dot2acc(qh[i], kh3[i], p3);
    }
#pragma unroll
    for (int off = 8; off >= 1; off >>= 1) {
      p0 += __shfl_xor(p0, off);
      p1 += __shfl_xor(p1, off);
      p2 += __shfl_xor(p2, off);
      p3 += __shfl_xor(p3, off);
    }
    p0 *= ATT_SCALE; p1 *= ATT_SCALE; p2 *= ATT_SCALE; p3 *= ATT_SCALE;
    upd(p0, v0);
    if (h1) upd(p1, v1);
    if (h2) upd(p2, v2);
    if (h3) upd(p3, v3);
  }

  // combine the 4 subgroups (online-softmax merge; m's are deferred maxima)
  float m2 = fmaxf(m, __shfl_xor(m, 16));
  float mAll = fmaxf(m2, __shfl_xor(m2, 32));
  float scale = (m == -INFINITY) ? 0.f : __expf(m - mAll);
  den *= scale;
  den += __shfl_xor(den, 16);
  den += __shfl_xor(den, 32);
#pragma unroll
  for (int i = 0; i < 8; ++i) {
    a[i] *= scale;
    a[i] += __shfl_xor(a[i], 16);
    a[i] += __shfl_xor(a[i], 32);
  }

  if (g4 == 0) {
    float inv = 1.f / fmaxf(den, 1e-16f);
    const float* sp = ss + (size_t)node * 512 + w * 128 + 8 * sl;
    short8v hi8, lo8;
#pragma unroll
    for (int i = 0; i < 8; ++i) {
      float v = a[i] * inv + sp[i];
      __hip_bfloat16 hv = __float2bfloat16(v);
      __hip_bfloat16 lv = __float2bfloat16(v - __bfloat162float(hv));
      hi8[i] = *(short*)&hv;
      lo8[i] = *(short*)&lv;
    }
    size_t o = (size_t)node * HC + w * 128 + 8 * sl;
    *(short8v*)(t0hi + o) = hi8;
    *(short8v*)(t0lo + o) = lo8;
  }
}

// ============ pooling (run-compressed: batch is sorted) ============
__global__ __launch_bounds__(256) void pool_init_kernel(float* __restrict__ gm, float* __restrict__ gsum, int* __restrict__ gcnt)
{
  int i = blockIdx.x * 256 + threadIdx.x;
  if (i < NB * HD) { ((int*)gm)[i] = 0xFF800000; gsum[i] = 0.f; }
  if (i < NB) gcnt[i] = 0;
}

#define PN 32  // nodes per block
__global__ __launch_bounds__(256) void pool_kernel(
    const float* __restrict__ h, const int* __restrict__ batch,
    float* __restrict__ gm, float* __restrict__ gsum, int* __restrict__ gcnt)
{
  __shared__ int sbatch[PN];
  const int base = blockIdx.x * PN;
  const int tid = threadIdx.x;
  if (tid < PN) {
    int n = base + tid;
    sbatch[tid] = (n < NN) ? batch[n] : -1;
  }
  __syncthreads();
  const int c = tid & 127;
  const int half = tid >> 7;
  const int i0 = half * (PN / 2), i1 = i0 + PN / 2;

  float sum = 0.f, mx = -INFINITY;
  int cur = sbatch[i0];
  bool any = false;
  for (int i = i0; i < i1; ++i) {
    int n = base + i;
    if (n >= NN) break;
    int b = sbatch[i];
    if (b != cur) {
      if (any) {
        atomicAdd(&gsum[(size_t)cur * HD + c], sum);
        atomicMax((int*)&gm[(size_t)cur * HD + c], __float_as_int(mx));
      }
      sum = 0.f; mx = -INFINITY; cur = b; any = false;
    }
    float val = h[(size_t)n * HD + c];
    sum += val; mx = fmaxf(mx, val);
    any = true;
  }
  if (any && cur >= 0) {
    atomicAdd(&gsum[(size_t)cur * HD + c], sum);
    atomicMax((int*)&gm[(size_t)cur * HD + c], __float_as_int(mx));
  }
  if (c == 0) {
    int cnt = 0; int cb = sbatch[i0];
    for (int i = i0; i < i1; ++i) {
      int n = base + i;
      if (n >= NN) break;
      if (sbatch[i] != cb) {
        if (cnt > 0 && cb >= 0) atomicAdd(&gcnt[cb], cnt);
        cnt = 0; cb = sbatch[i];
      }
      cnt++;
    }
    if (cnt > 0 && cb >= 0) atomicAdd(&gcnt[cb], cnt);
  }
}

__global__ __launch_bounds__(256) void pool_finalize_kernel(
    const float* __restrict__ gm, const float* __restrict__ gsum,
    const int* __restrict__ gcnt, float* __restrict__ g,
    __hip_bfloat16* __restrict__ ghi, __hip_bfloat16* __restrict__ glo)
{
  int idx = blockIdx.x * 256 + threadIdx.x;
  if (idx >= NB * HD) return;
  int b = idx >> 7, c = idx & 127;
  float mv = gm[idx];
  if (mv < -1e30f) mv = 0.f;
  float cf = (float)gcnt[b];
  float av = gsum[idx] / fmaxf(cf, 1.f);
  size_t o0 = (size_t)b * 256 + c;
  size_t o1 = o0 + 128;
  g[o0] = mv; g[o1] = av;
  __hip_bfloat16 h0 = __float2bfloat16(mv);
  __hip_bfloat16 h1 = __float2bfloat16(av);
  ghi[o0] = h0; glo[o0] = __float2bfloat16(mv - __bfloat162float(h0));
  ghi[o1] = h1; glo[o1] = __float2bfloat16(av - __bfloat162float(h1));
}

// ============ final head layer: [512,256] @ [256,1] + b ============
__global__ __launch_bounds__(256) void head4_kernel(
    const float* __restrict__ g3, const float* __restrict__ Wf2,
    const float* __restrict__ bf2, float* __restrict__ out)
{
  int w = threadIdx.x >> 6, lane = threadIdx.x & 63;
  int row = blockIdx.x * 4 + w;
  const float* r = g3 + (size_t)row * 256;
  float p = r[lane] * Wf2[lane] + r[64 + lane] * Wf2[64 + lane]
          + r[128 + lane] * Wf2[128 + lane] + r[192 + lane] * Wf2[192 + lane];
#pragma unroll
  for (int off = 32; off >= 1; off >>= 1) p += __shfl_xor(p, off);
  if (lane == 0) out[row] = p + bf2[0];
}

extern "C" void kernel_launch(void* const* d_in, const int* in_sizes, int n_in,
                              void* d_out, int out_size, void* d_ws, size_t ws_size,
                              hipStream_t stream)
{
  const float* x = (const float*)d_in[0];
  const int* edge_index = (const int*)d_in[1];
  const int* batch = (const int*)d_in[2];
  const int* src = edge_index;
  const int* dstv = edge_index + NE;

  const float *Wq[3], *bq[3], *Wk[3], *bk[3], *Wv[3], *bv[3], *Wsk[3], *bsk[3], *Wm[3], *bm[3];
  int base = 3;
  for (int l = 0; l < 3; ++l) {
    Wq[l]  = (const float*)d_in[base + 0]; bq[l]  = (const float*)d_in[base + 1];
    Wk[l]  = (const float*)d_in[base + 2]; bk[l]  = (const float*)d_in[base + 3];
    Wv[l]  = (const float*)d_in[base + 4]; bv[l]  = (const float*)d_in[base + 5];
    Wsk[l] = (const float*)d_in[base + 6]; bsk[l] = (const float*)d_in[base + 7];
    Wm[l]  = (const float*)d_in[base + 8]; bm[l]  = (const float*)d_in[base + 9];
    base += 10;
  }
  const float* Wg1 = (const float*)d_in[33]; const float* bg1 = (const float*)d_in[34];
  const float* Wg2 = (const float*)d_in[35]; const float* bg2 = (const float*)d_in[36];
  const float* Wf1 = (const float*)d_in[37]; const float* bf1 = (const float*)d_in[38];
  const float* Wf2 = (const float*)d_in[39]; const float* bf2 = (const float*)d_in[40];

  // ---- workspace layout ----
  char* p = (char*)d_ws;
  auto alloc = [&](size_t bytes) { char* r = p; p += (bytes + 255) & ~(size_t)255; return r; };
  __half* qh16 = (__half*)alloc((size_t)MPAD * 512 * 2);   // Q fp16
  float* ss    = (float*)alloc((size_t)MPAD * 512 * 4);    // S fp32
  __half* kvh  = (__half*)alloc((size_t)MPAD * 1024 * 2);  // per head: K(128)|V(128) fp16
  float* h    = (float*)alloc((size_t)NN * HD * 4);
  __hip_bfloat16* t0hi = (__hip_bfloat16*)alloc((size_t)MPAD * HC * 2);
  __hip_bfloat16* t0lo = (__hip_bfloat16*)alloc((size_t)MPAD * HC * 2);
  __hip_bfloat16* hhi  = (__hip_bfloat16*)alloc((size_t)MPAD * HD * 2);
  __hip_bfloat16* hlo  = (__hip_bfloat16*)alloc((size_t)MPAD * HD * 2);
  __hip_bfloat16* xhi  = (__hip_bfloat16*)alloc((size_t)MPAD * 64 * 2);
  __hip_bfloat16* xlo  = (__hip_bfloat16*)alloc((size_t)MPAD * 64 * 2);
  __hip_bfloat16* Wp_hi[3], *Wp_lo[3], *Wm_hi[3], *Wm_lo[3];
  Wp_hi[0] = (__hip_bfloat16*)alloc((size_t)2048 * 64 * 2);
  Wp_lo[0] = (__hip_bfloat16*)alloc((size_t)2048 * 64 * 2);
  for (int l = 1; l < 3; ++l) {
    Wp_hi[l] = (__hip_bfloat16*)alloc((size_t)2048 * 128 * 2);
    Wp_lo[l] = (__hip_bfloat16*)alloc((size_t)2048 * 128 * 2);
  }
  for (int l = 0; l < 3; ++l) {
    Wm_hi[l] = (__hip_bfloat16*)alloc((size_t)128 * 512 * 2);
    Wm_lo[l] = (__hip_bfloat16*)alloc((size_t)128 * 512 * 2);
  }
  __hip_bfloat16* Wg1_hi = (__hip_bfloat16*)alloc((size_t)1024 * 256 * 2);
  __hip_bfloat16* Wg1_lo = (__hip_bfloat16*)alloc((size_t)1024 * 256 * 2);
  __hip_bfloat16* Wg2_hi = (__hip_bfloat16*)alloc((size_t)512 * 1024 * 2);
  __hip_bfloat16* Wg2_lo = (__hip_bfloat16*)alloc((size_t)512 * 1024 * 2);
  __hip_bfloat16* Wf1_hi = (__hip_bfloat16*)alloc((size_t)256 * 512 * 2);
  __hip_bfloat16* Wf1_lo = (__hip_bfloat16*)alloc((size_t)256 * 512 * 2);
  float* bpack = (float*)alloc(3 * 2048 * 4);
  float* gm   = (float*)alloc((size_t)NB * HD * 4);
  float* gsum = (float*)alloc((size_t)NB * HD * 4);
  float* g    = (float*)alloc((size_t)NB * 256 * 4);
  __hip_bfloat16* ghi = (__hip_bfloat16*)alloc((size_t)NB * 256 * 2);
  __hip_bfloat16* glo = (__hip_bfloat16*)alloc((size_t)NB * 256 * 2);
  float* g1 = (float*)alloc((size_t)NB * 1024 * 4);
  __hip_bfloat16* g1hi = (__hip_bfloat16*)alloc((size_t)NB * 1024 * 2);
  __hip_bfloat16* g1lo = (__hip_bfloat16*)alloc((size_t)NB * 1024 * 2);
  float* g2 = (float*)alloc((size_t)NB * 512 * 4);
  __hip_bfloat16* g2hi = (__hip_bfloat16*)alloc((size_t)NB * 512 * 2);
  __hip_bfloat16* g2lo = (__hip_bfloat16*)alloc((size_t)NB * 512 * 2);
  float* g3 = (float*)alloc((size_t)NB * 256 * 4);
  __hip_bfloat16* g3hi = (__hip_bfloat16*)alloc((size_t)NB * 256 * 2);
  __hip_bfloat16* g3lo = (__hip_bfloat16*)alloc((size_t)NB * 256 * 2);
  int* icnt      = (int*)alloc(NN * 4);
  int* cursor    = (int*)alloc(NN * 4);
  int* row_start = (int*)alloc((NN + 1) * 4);
  int* edge_list = (int*)alloc((size_t)NE * 4);
  int* gcnt      = (int*)alloc(NB * 4);

  const int GR128 = (NN + 127) / 128;  // 157
  const int GR64  = (NN + 63) / 64;    // 313

  // ---- pack all weights/biases ----
  PackArgs pa;
  for (int l = 0; l < 3; ++l) {
    pa.W[l * 4 + 0] = Wq[l];  pa.W[l * 4 + 1] = Wk[l];
    pa.W[l * 4 + 2] = Wv[l];  pa.W[l * 4 + 3] = Wsk[l];
    pa.b[l * 4 + 0] = bq[l];  pa.b[l * 4 + 1] = bk[l];
    pa.b[l * 4 + 2] = bv[l];  pa.b[l * 4 + 3] = bsk[l];
    pa.Wm[l] = Wm[l];
    pa.Wp_hi[l] = Wp_hi[l]; pa.Wp_lo[l] = Wp_lo[l];
    pa.Wm_hi[l] = Wm_hi[l]; pa.Wm_lo[l] = Wm_lo[l];
  }
  pa.Wg1 = Wg1; pa.Wg2 = Wg2; pa.Wf1 = Wf1;
  pa.Wg1_hi = Wg1_hi; pa.Wg1_lo = Wg1_lo;
  pa.Wg2_hi = Wg2_hi; pa.Wg2_lo = Wg2_lo;
  pa.Wf1_hi = Wf1_hi; pa.Wf1_lo = Wf1_lo;
  pa.bpack = bpack;
  pack_all_kernel<<<(1775616 + 255) / 256, 256, 0, stream>>>(pa);

  // ---- CSR build ----
  hipMemsetAsync(icnt, 0, sizeof(int) * NN, stream);
  hipMemsetAsync(cursor, 0, sizeof(int) * NN, stream);
  count_kernel<<<(NE + 255) / 256, 256, 0, stream>>>(dstv, icnt);
  scan_kernel<<<1, 1024, 0, stream>>>(icnt, row_start);
  scatter_kernel<<<(NE + 255) / 256, 256, 0, stream>>>(src, dstv, row_start, cursor, edge_list);

  // ---- input split ----
  split_x_kernel<<<(NN * 64 + 255) / 256, 256, 0, stream>>>(x, xhi, xlo);

  // ---- 3 TransformerConv layers ----
  for (int l = 0; l < 3; ++l) {
    int Kpad = (l == 0) ? 64 : 128;
    const __hip_bfloat16* Ahi = (l == 0) ? xhi : hhi;
    const __hip_bfloat16* Alo = (l == 0) ? xlo : hlo;

    // col-fastest grid: the 16 col-blocks sharing an A row-block are consecutive bids
    gemm_mfma_kernel<2><<<dim3(16, GR128), 256, 0, stream>>>(
        Ahi, Alo, Kpad, Wp_hi[l], Wp_lo[l], bpack + l * 2048, ss, 512,
        (__hip_bfloat16*)qh16, nullptr, kvh, NN, Kpad);

    attn_kernel<<<NN, 256, 0, stream>>>(qh16, ss, kvh, row_start, edge_list, t0hi, t0lo);

    gemm64_kernel<<<dim3(GR64, 1), 256, 0, stream>>>(
        t0hi, t0lo, HC, Wm_hi[l], Wm_lo[l], bm[l], h, HD, hhi, hlo, NN, HC);
  }

  // ---- pooling ----
  pool_init_kernel<<<(NB * HD + 255) / 256, 256, 0, stream>>>(gm, gsum, gcnt);
  pool_kernel<<<(NN + PN - 1) / PN, 256, 0, stream>>>(h, batch, gm, gsum, gcnt);
  pool_finalize_kernel<<<(NB * HD + 255) / 256, 256, 0, stream>>>(gm, gsum, gcnt, g, ghi, glo);

  // ---- MLP head via MFMA (64-row tiles) ----
  gemm64_kernel<<<dim3(8, 8), 256, 0, stream>>>(
      ghi, glo, 256, Wg1_hi, Wg1_lo, bg1, g1, 1024, g1hi, g1lo, NB, 256);
  gemm64_kernel<<<dim3(8, 4), 256, 0, stream>>>(
      g1hi, g1lo, 1024, Wg2_hi, Wg2_lo, bg2, g2, 512, g2hi, g2lo, NB, 1024);
  gemm64_kernel<<<dim3(8, 2), 256, 0, stream>>>(
      g2hi, g2lo, 512, Wf1_hi, Wf1_lo, bf1, g3, 256, g3hi, g3lo, NB, 512);
  head4_kernel<<<NB / 4, 256, 0, stream>>>(g3, Wf2, bf2, (float*)d_out);
}

// Round 9
// 663.122 us; speedup vs baseline: 3.1722x; 1.0761x over previous
//
#include <hip/hip_runtime.h>
#include <hip/hip_bf16.h>
#include <hip/hip_fp16.h>
#include <math.h>

#define NN 20000
#define MPAD 20096          // row padding for MFMA staging (mult of 128)
#define NE 320000
#define NB 512
#define FIN 43
#define HD 128
#define HC 512
#define ATT_SCALE 0.08838834764831843f

typedef __attribute__((ext_vector_type(8))) short bf16x8v;
typedef __attribute__((ext_vector_type(8))) short short8v;
typedef __attribute__((ext_vector_type(4))) float f32x4v;
typedef _Float16 half2_t __attribute__((ext_vector_type(2)));

__device__ __forceinline__ void gload16(void* lds, const void* g) {
  __builtin_amdgcn_global_load_lds(
      (const __attribute__((address_space(1))) void*)g,
      (__attribute__((address_space(3))) void*)lds, 16, 0, 0);
}

__device__ __forceinline__ float dot2acc(half2_t a, half2_t b, float c) {
#if __has_builtin(__builtin_amdgcn_fdot2)
  return __builtin_amdgcn_fdot2(a, b, c, false);
#else
  return c + (float)a[0] * (float)b[0] + (float)a[1] * (float)b[1];
#endif
}

// ============ qkv GEMM, 128x128 tile (grid COL-FASTEST: x=col-block, y=row-block) ============
// cols [0,512):    fp16 Q -> qh16[row*512+col]
// cols [512,1024): K head h -> kvh[row*1024 + h*256 + c]
// cols [1024,1536):V head h -> kvh[row*1024 + h*256 + 128 + c]
__global__ __launch_bounds__(256, 2) void gemm_qkv_kernel(
    const __hip_bfloat16* __restrict__ Ahi_, const __hip_bfloat16* __restrict__ Alo_, int ldA,
    const __hip_bfloat16* __restrict__ Bhi_, const __hip_bfloat16* __restrict__ Blo_,
    const float* __restrict__ bias,
    __half* __restrict__ qh16, __half* __restrict__ kvh,
    int M, int K)
{
  __shared__ short Ah[128 * 64], Al[128 * 64], Bh[128 * 64], Bl[128 * 64];
  const short* Ahi = (const short*)Ahi_;
  const short* Alo = (const short*)Alo_;
  const short* Bhi = (const short*)Bhi_;
  const short* Blo = (const short*)Blo_;
  const int tid = threadIdx.x;
  const int w = tid >> 6, lane = tid & 63;
  const int rowBase = blockIdx.y * 128, colBase = blockIdx.x * 128;
  const int srow = lane >> 3;
  const int sw = ((lane & 7) ^ srow) << 3;
  const int lr = lane & 15, lg = lane >> 4;
  const int wr = w >> 1, wc = w & 1;

  f32x4v acc[4][4];
#pragma unroll
  for (int m = 0; m < 4; ++m)
#pragma unroll
    for (int n = 0; n < 4; ++n) acc[m][n] = (f32x4v){0.f, 0.f, 0.f, 0.f};

  for (int k0 = 0; k0 < K; k0 += 64) {
    if (k0) __syncthreads();
#pragma unroll
    for (int t = 0; t < 4; ++t) {
      int r0 = w * 32 + t * 8;
      size_t arow = (size_t)(rowBase + r0 + srow) * ldA + k0 + sw;
      size_t brow = (size_t)(colBase + r0 + srow) * K + k0 + sw;
      gload16(&Ah[r0 * 64], Ahi + arow);
      gload16(&Al[r0 * 64], Alo + arow);
      gload16(&Bh[r0 * 64], Bhi + brow);
      gload16(&Bl[r0 * 64], Blo + brow);
    }
    __syncthreads();
#pragma unroll
    for (int kk = 0; kk < 2; ++kk) {
      bf16x8v ah[4], al[4], bh[4], bl[4];
      int cbase = ((kk * 4 + lg) ^ (lr & 7)) * 8;
#pragma unroll
      for (int m = 0; m < 4; ++m) {
        int idx = (wr * 64 + m * 16 + lr) * 64 + cbase;
        ah[m] = *(const bf16x8v*)&Ah[idx];
        al[m] = *(const bf16x8v*)&Al[idx];
      }
#pragma unroll
      for (int n = 0; n < 4; ++n) {
        int idx = (wc * 64 + n * 16 + lr) * 64 + cbase;
        bh[n] = *(const bf16x8v*)&Bh[idx];
        bl[n] = *(const bf16x8v*)&Bl[idx];
      }
#pragma unroll
      for (int m = 0; m < 4; ++m)
#pragma unroll
        for (int n = 0; n < 4; ++n) {
          acc[m][n] = __builtin_amdgcn_mfma_f32_16x16x32_bf16(ah[m], bh[n], acc[m][n], 0, 0, 0);
          acc[m][n] = __builtin_amdgcn_mfma_f32_16x16x32_bf16(ah[m], bl[n], acc[m][n], 0, 0, 0);
          acc[m][n] = __builtin_amdgcn_mfma_f32_16x16x32_bf16(al[m], bh[n], acc[m][n], 0, 0, 0);
        }
    }
  }
#pragma unroll
  for (int m = 0; m < 4; ++m) {
#pragma unroll
    for (int n = 0; n < 4; ++n) {
      int col = colBase + wc * 64 + n * 16 + lr;
      float bb = bias[col];
#pragma unroll
      for (int r = 0; r < 4; ++r) {
        int row = rowBase + wr * 64 + m * 16 + lg * 4 + r;
        if (row < M) {
          float v = acc[m][n][r] + bb;
          if (col < 512) {
            qh16[(size_t)row * 512 + col] = __float2half(v);
          } else if (col < 1024) {
            int cc = col - 512;
            kvh[(size_t)row * 1024 + (cc >> 7) * 256 + (cc & 127)] = __float2half(v);
          } else {
            int cc = col - 1024;
            kvh[(size_t)row * 1024 + (cc >> 7) * 256 + 128 + (cc & 127)] = __float2half(v);
          }
        }
      }
    }
  }
}

// ============ split-bf16 MFMA GEMM, 64x128 tile, two A sources along K ============
// A covers k in [0,Ksplit), A2 covers k in [Ksplit,K). relu; fp32 Y optional; bf16 split out.
__global__ __launch_bounds__(256, 2) void gemm64_kernel(
    const __hip_bfloat16* __restrict__ Ahi_, const __hip_bfloat16* __restrict__ Alo_, int ldA,
    int Ksplit,
    const __hip_bfloat16* __restrict__ A2hi_, const __hip_bfloat16* __restrict__ A2lo_, int ldA2,
    const __hip_bfloat16* __restrict__ Bhi_, const __hip_bfloat16* __restrict__ Blo_,
    const float* __restrict__ bias,
    float* __restrict__ Y, int ldY,
    __hip_bfloat16* __restrict__ Yhi, __hip_bfloat16* __restrict__ Ylo,
    int M, int K)
{
  __shared__ short Ah[64 * 64], Al[64 * 64], Bh[128 * 64], Bl[128 * 64];
  const short* Bhi = (const short*)Bhi_;
  const short* Blo = (const short*)Blo_;
  const int tid = threadIdx.x;
  const int w = tid >> 6, lane = tid & 63;
  const int rowBase = blockIdx.x * 64, colBase = blockIdx.y * 128;
  const int srow = lane >> 3;
  const int sw = ((lane & 7) ^ srow) << 3;
  const int lr = lane & 15, lg = lane >> 4;
  const int wr = w >> 1, wc = w & 1;

  f32x4v acc[2][4];
#pragma unroll
  for (int m = 0; m < 2; ++m)
#pragma unroll
    for (int n = 0; n < 4; ++n) acc[m][n] = (f32x4v){0.f, 0.f, 0.f, 0.f};

  for (int k0 = 0; k0 < K; k0 += 64) {
    if (k0) __syncthreads();
    const short* sAh;
    const short* sAl;
    int ldS, kloc;
    if (k0 < Ksplit) { sAh = (const short*)Ahi_;  sAl = (const short*)Alo_;  ldS = ldA;  kloc = k0; }
    else             { sAh = (const short*)A2hi_; sAl = (const short*)A2lo_; ldS = ldA2; kloc = k0 - Ksplit; }
#pragma unroll
    for (int t = 0; t < 2; ++t) {
      int r0 = w * 16 + t * 8;
      size_t arow = (size_t)(rowBase + r0 + srow) * ldS + kloc + sw;
      gload16(&Ah[r0 * 64], sAh + arow);
      gload16(&Al[r0 * 64], sAl + arow);
    }
#pragma unroll
    for (int t = 0; t < 4; ++t) {
      int r0 = w * 32 + t * 8;
      size_t brow = (size_t)(colBase + r0 + srow) * K + k0 + sw;
      gload16(&Bh[r0 * 64], Bhi + brow);
      gload16(&Bl[r0 * 64], Blo + brow);
    }
    __syncthreads();
#pragma unroll
    for (int kk = 0; kk < 2; ++kk) {
      bf16x8v ah[2], al[2], bh[4], bl[4];
      int cbase = ((kk * 4 + lg) ^ (lr & 7)) * 8;
#pragma unroll
      for (int m = 0; m < 2; ++m) {
        int idx = (wr * 32 + m * 16 + lr) * 64 + cbase;
        ah[m] = *(const bf16x8v*)&Ah[idx];
        al[m] = *(const bf16x8v*)&Al[idx];
      }
#pragma unroll
      for (int n = 0; n < 4; ++n) {
        int idx = (wc * 64 + n * 16 + lr) * 64 + cbase;
        bh[n] = *(const bf16x8v*)&Bh[idx];
        bl[n] = *(const bf16x8v*)&Bl[idx];
      }
#pragma unroll
      for (int m = 0; m < 2; ++m)
#pragma unroll
        for (int n = 0; n < 4; ++n) {
          acc[m][n] = __builtin_amdgcn_mfma_f32_16x16x32_bf16(ah[m], bh[n], acc[m][n], 0, 0, 0);
          acc[m][n] = __builtin_amdgcn_mfma_f32_16x16x32_bf16(ah[m], bl[n], acc[m][n], 0, 0, 0);
          acc[m][n] = __builtin_amdgcn_mfma_f32_16x16x32_bf16(al[m], bh[n], acc[m][n], 0, 0, 0);
        }
    }
  }
#pragma unroll
  for (int m = 0; m < 2; ++m) {
#pragma unroll
    for (int n = 0; n < 4; ++n) {
      int col = colBase + wc * 64 + n * 16 + lr;
      float bb = bias[col];
#pragma unroll
      for (int r = 0; r < 4; ++r) {
        int row = rowBase + wr * 32 + m * 16 + lg * 4 + r;
        if (row < M) {
          float v = fmaxf(acc[m][n][r] + bb, 0.f);
          if (Y) Y[(size_t)row * ldY + col] = v;
          __hip_bfloat16 hv = __float2bfloat16(v);
          Yhi[(size_t)row * ldY + col] = hv;
          Ylo[(size_t)row * ldY + col] = __float2bfloat16(v - __bfloat162float(hv));
        }
      }
    }
  }
}

// ============ Wsm = Ws@Wm fold (skip path into proj) ============
struct WsmArgs {
  const float* Ws[3];   // [din][512]
  const float* Wm[3];   // [512][128]
  const float* bs[3];   // [512]
  const float* bm[3];   // [128]
  __hip_bfloat16 *Wmx_hi[3], *Wmx_lo[3];  // [128][KP]  KP=576(l0)/640
  float* bm2;           // [3][128]
};

__global__ __launch_bounds__(256) void wsm_kernel(WsmArgs a)
{
  int idx = blockIdx.x * 256 + threadIdx.x;
  if (idx < 3 * 128 * 128) {
    int l = idx >> 14, r = idx & 16383;
    int n = r >> 7, d = r & 127;
    int K2pad = (l == 0) ? 64 : 128;
    if (d >= K2pad) return;
    int din = (l == 0) ? FIN : 128;
    float v = 0.f;
    if (d < din) {
      const float* ws = a.Ws[l] + (size_t)d * 512;
      const float* wm = a.Wm[l];
      for (int j = 0; j < 512; ++j) v += ws[j] * wm[(size_t)j * 128 + n];
    }
    int KP = 512 + K2pad;
    __hip_bfloat16 h = __float2bfloat16(v);
    a.Wmx_hi[l][(size_t)n * KP + 512 + d] = h;
    a.Wmx_lo[l][(size_t)n * KP + 512 + d] = __float2bfloat16(v - __bfloat162float(h));
  } else {
    int r = idx - 3 * 128 * 128;
    if (r >= 384) return;
    int l = r >> 7, n = r & 127;
    float v = a.bm[l][n];
    const float* bs = a.bs[l];
    const float* wm = a.Wm[l];
    for (int j = 0; j < 512; ++j) v += bs[j] * wm[(size_t)j * 128 + n];
    a.bm2[l * 128 + n] = v;
  }
}

// ============ pack everything in one launch ============
struct PackArgs {
  const float* W[9];      // [l*3 + {q,k,v}]  shape [K][512]
  const float* b[9];
  const float* Wm[3];     // [512][128]
  const float *Wg1, *Wg2, *Wf1;
  __hip_bfloat16 *Wp_hi[3], *Wp_lo[3];    // [1536][Kpad]
  __hip_bfloat16 *Wmx_hi[3], *Wmx_lo[3];  // [128][KP] (k<512 part)
  __hip_bfloat16 *Wg1_hi, *Wg1_lo;        // [1024][256]
  __hip_bfloat16 *Wg2_hi, *Wg2_lo;        // [512][1024]
  __hip_bfloat16 *Wf1_hi, *Wf1_lo;        // [256][512]
  float* bpack;                            // [3][1536]
};

// segments: [0,98304) l0 qkv | [98304,491520) l1,l2 qkv | [491520,688128) proj Wm
//           [688128,692736) qkv biases | [692736,954880) Wg1 | [954880,1479168) Wg2
//           [1479168,1610240) Wf1
__global__ __launch_bounds__(256) void pack_all_kernel(PackArgs a)
{
  int idx = blockIdx.x * 256 + threadIdx.x;
  if (idx < 98304) {
    int n = idx >> 6, k = idx & 63;
    int mat = n >> 9, nn = n & 511;
    float v = (k < FIN) ? a.W[mat][(size_t)k * 512 + nn] : 0.f;
    __hip_bfloat16 h = __float2bfloat16(v);
    a.Wp_hi[0][idx] = h;
    a.Wp_lo[0][idx] = __float2bfloat16(v - __bfloat162float(h));
  } else if (idx < 491520) {
    int rel = idx - 98304;
    int l = 1 + rel / 196608;
    int r2 = rel % 196608;
    int n = r2 >> 7, k = r2 & 127;
    int mat = n >> 9, nn = n & 511;
    float v = a.W[l * 3 + mat][(size_t)k * 512 + nn];
    __hip_bfloat16 h = __float2bfloat16(v);
    a.Wp_hi[l][r2] = h;
    a.Wp_lo[l][r2] = __float2bfloat16(v - __bfloat162float(h));
  } else if (idx < 688128) {
    int rel = idx - 491520;
    int l = rel >> 16;
    int r2 = rel & 65535;
    int n = r2 >> 9, k = r2 & 511;
    float v = a.Wm[l][(size_t)k * 128 + n];
    int KP = (l == 0) ? 576 : 640;
    __hip_bfloat16 h = __float2bfloat16(v);
    a.Wmx_hi[l][(size_t)n * KP + k] = h;
    a.Wmx_lo[l][(size_t)n * KP + k] = __float2bfloat16(v - __bfloat162float(h));
  } else if (idx < 692736) {
    int rel = idx - 688128;
    int l = rel / 1536, c = rel % 1536;
    a.bpack[rel] = a.b[l * 3 + (c >> 9)][c & 511];
  } else if (idx < 954880) {
    int rel = idx - 692736;
    int n = rel >> 8, k = rel & 255;
    float v = a.Wg1[(size_t)k * 1024 + n];
    __hip_bfloat16 h = __float2bfloat16(v);
    a.Wg1_hi[rel] = h;
    a.Wg1_lo[rel] = __float2bfloat16(v - __bfloat162float(h));
  } else if (idx < 1479168) {
    int rel = idx - 954880;
    int n = rel >> 10, k = rel & 1023;
    float v = a.Wg2[(size_t)k * 512 + n];
    __hip_bfloat16 h = __float2bfloat16(v);
    a.Wg2_hi[rel] = h;
    a.Wg2_lo[rel] = __float2bfloat16(v - __bfloat162float(h));
  } else if (idx < 1610240) {
    int rel = idx - 1479168;
    int n = rel >> 9, k = rel & 511;
    float v = a.Wf1[(size_t)k * 256 + n];
    __hip_bfloat16 h = __float2bfloat16(v);
    a.Wf1_hi[rel] = h;
    a.Wf1_lo[rel] = __float2bfloat16(v - __bfloat162float(h));
  }
}

__global__ __launch_bounds__(256) void split_x_kernel(
    const float* __restrict__ x, __hip_bfloat16* __restrict__ hi, __hip_bfloat16* __restrict__ lo)
{
  int idx = blockIdx.x * 256 + threadIdx.x;
  if (idx >= NN * 64) return;
  int r = idx >> 6, c = idx & 63;
  float v = (c < FIN) ? x[(size_t)r * FIN + c] : 0.f;
  __hip_bfloat16 h = __float2bfloat16(v);
  hi[idx] = h;
  lo[idx] = __float2bfloat16(v - __bfloat162float(h));
}

// ============ CSR build over dst ============
__global__ __launch_bounds__(256) void count_kernel(const int* __restrict__ dst, int* __restrict__ cnt)
{
  int e = blockIdx.x * 256 + threadIdx.x;
  if (e < NE) atomicAdd(&cnt[dst[e]], 1);
}

__global__ __launch_bounds__(1024) void scan_kernel(const int* __restrict__ cnt, int* __restrict__ row_start)
{
  __shared__ int sums[1024];
  int t = threadIdx.x;
  const int per = (NN + 1023) / 1024;
  int beg = t * per;
  int end = beg + per; if (end > NN) end = NN; if (beg > NN) beg = NN;
  int s = 0;
  for (int i = beg; i < end; ++i) s += cnt[i];
  sums[t] = s;
  __syncthreads();
  for (int off = 1; off < 1024; off <<= 1) {
    int v = (t >= off) ? sums[t - off] : 0;
    __syncthreads();
    sums[t] += v;
    __syncthreads();
  }
  int prefix = (t == 0) ? 0 : sums[t - 1];
  for (int i = beg; i < end; ++i) { row_start[i] = prefix; prefix += cnt[i]; }
  if (t == 1023) row_start[NN] = prefix;
}

__global__ __launch_bounds__(256) void scatter_kernel(
    const int* __restrict__ src, const int* __restrict__ dst,
    const int* __restrict__ row_start,
    int* __restrict__ cursor, int* __restrict__ edge_list)
{
  int e = blockIdx.x * 256 + threadIdx.x;
  if (e < NE) {
    int d = dst[e];
    int p = atomicAdd(&cursor[d], 1);
    edge_list[row_start[d] + p] = src[e];
  }
}

// ============ fused attention: single-pass, defer-max, barrier-free ============
__global__ __launch_bounds__(256) void attn_kernel(
    const __half* __restrict__ qh16, const __half* __restrict__ kvh,
    const int* __restrict__ row_start, const int* __restrict__ edge_list,
    __hip_bfloat16* __restrict__ t0hi, __hip_bfloat16* __restrict__ t0lo)
{
  const int node = blockIdx.x;
  const int tid = threadIdx.x;
  const int w = tid >> 6, lane = tid & 63;
  const int g4 = lane >> 4, sl = lane & 15;
  const int beg = row_start[node], cnt = row_start[node + 1] - beg;

  float4 qraw = *(const float4*)(qh16 + (size_t)node * 512 + w * 128 + 8 * sl);
  const half2_t* qh = (const half2_t*)&qraw;

  float m = -INFINITY, den = 0.f;
  float a[8] = {0.f, 0.f, 0.f, 0.f, 0.f, 0.f, 0.f, 0.f};

  auto upd = [&](float p, const float4& vraw) {
    const __half2* vh = (const __half2*)&vraw;
    float2 f0 = __half22float2(vh[0]);
    float2 f1 = __half22float2(vh[1]);
    float2 f2 = __half22float2(vh[2]);
    float2 f3 = __half22float2(vh[3]);
    if (__builtin_expect(p > m + 8.f, 0)) {
      float c = __expf(m - p);   // m=-inf first time -> 0
      den = den * c + 1.f;
      a[0] = a[0] * c + f0.x; a[1] = a[1] * c + f0.y;
      a[2] = a[2] * c + f1.x; a[3] = a[3] * c + f1.y;
      a[4] = a[4] * c + f2.x; a[5] = a[5] * c + f2.y;
      a[6] = a[6] * c + f3.x; a[7] = a[7] * c + f3.y;
      m = p;
    } else {
      float e = __expf(p - m);
      den += e;
      a[0] += e * f0.x; a[1] += e * f0.y;
      a[2] += e * f1.x; a[3] += e * f1.y;
      a[4] += e * f2.x; a[5] += e * f2.y;
      a[6] += e * f3.x; a[7] += e * f3.y;
    }
  };

  const int* el = edge_list + beg;
  for (int j = 4 * g4; j < cnt; j += 16) {
    bool h1 = (j + 1 < cnt), h2 = (j + 2 < cnt), h3 = (j + 3 < cnt);
    int s0 = el[j];
    int s1 = h1 ? el[j + 1] : s0;
    int s2 = h2 ? el[j + 2] : s0;
    int s3 = h3 ? el[j + 3] : s0;
    const __half* b0 = kvh + (size_t)s0 * 1024 + w * 256 + 8 * sl;
    const __half* b1 = kvh + (size_t)s1 * 1024 + w * 256 + 8 * sl;
    const __half* b2 = kvh + (size_t)s2 * 1024 + w * 256 + 8 * sl;
    const __half* b3 = kvh + (size_t)s3 * 1024 + w * 256 + 8 * sl;
    float4 k0 = *(const float4*)b0;
    float4 k1 = *(const float4*)b1;
    float4 k2 = *(const float4*)b2;
    float4 k3 = *(const float4*)b3;
    float4 v0 = *(const float4*)(b0 + 128);
    float4 v1 = *(const float4*)(b1 + 128);
    float4 v2 = *(const float4*)(b2 + 128);
    float4 v3 = *(const float4*)(b3 + 128);

    const half2_t* kh0 = (const half2_t*)&k0;
    const half2_t* kh1 = (const half2_t*)&k1;
    const half2_t* kh2 = (const half2_t*)&k2;
    const half2_t* kh3 = (const half2_t*)&k3;
    float p0 = 0.f, p1 = 0.f, p2 = 0.f, p3 = 0.f;
#pragma unroll
    for (int i = 0; i < 4; ++i) {
      p0 = dot2acc(qh[i], kh0[i], p0);
      p1 = dot2acc(qh[i], kh1[i], p1);
      p2 = dot2acc(qh[i], kh2[i], p2);
      p3 = dot2acc(qh[i], kh3[i], p3);
    }
#pragma unroll
    for (int off = 8; off >= 1; off >>= 1) {
      p0 += __shfl_xor(p0, off);
      p1 += __shfl_xor(p1, off);
      p2 += __shfl_xor(p2, off);
      p3 += __shfl_xor(p3, off);
    }
    p0 *= ATT_SCALE; p1 *= ATT_SCALE; p2 *= ATT_SCALE; p3 *= ATT_SCALE;
    upd(p0, v0);
    if (h1) upd(p1, v1);
    if (h2) upd(p2, v2);
    if (h3) upd(p3, v3);
  }

  // combine the 4 subgroups (online-softmax merge; m's are deferred maxima)
  float m2 = fmaxf(m, __shfl_xor(m, 16));
  float mAll = fmaxf(m2, __shfl_xor(m2, 32));
  float scale = (m == -INFINITY) ? 0.f : __expf(m - mAll);
  den *= scale;
  den += __shfl_xor(den, 16);
  den += __shfl_xor(den, 32);
#pragma unroll
  for (int i = 0; i < 8; ++i) {
    a[i] *= scale;
    a[i] += __shfl_xor(a[i], 16);
    a[i] += __shfl_xor(a[i], 32);
  }

  if (g4 == 0) {
    float inv = 1.f / fmaxf(den, 1e-16f);
    short8v hi8, lo8;
#pragma unroll
    for (int i = 0; i < 8; ++i) {
      float v = a[i] * inv;
      __hip_bfloat16 hv = __float2bfloat16(v);
      __hip_bfloat16 lv = __float2bfloat16(v - __bfloat162float(hv));
      hi8[i] = *(short*)&hv;
      lo8[i] = *(short*)&lv;
    }
    size_t o = (size_t)node * HC + w * 128 + 8 * sl;
    *(short8v*)(t0hi + o) = hi8;
    *(short8v*)(t0lo + o) = lo8;
  }
}

// ============ pooling (run-compressed: batch is sorted) ============
__global__ __launch_bounds__(256) void pool_init_kernel(float* __restrict__ gm, float* __restrict__ gsum, int* __restrict__ gcnt)
{
  int i = blockIdx.x * 256 + threadIdx.x;
  if (i < NB * HD) { ((int*)gm)[i] = 0xFF800000; gsum[i] = 0.f; }
  if (i < NB) gcnt[i] = 0;
}

#define PN 32  // nodes per block
__global__ __launch_bounds__(256) void pool_kernel(
    const float* __restrict__ h, const int* __restrict__ batch,
    float* __restrict__ gm, float* __restrict__ gsum, int* __restrict__ gcnt)
{
  __shared__ int sbatch[PN];
  const int base = blockIdx.x * PN;
  const int tid = threadIdx.x;
  if (tid < PN) {
    int n = base + tid;
    sbatch[tid] = (n < NN) ? batch[n] : -1;
  }
  __syncthreads();
  const int c = tid & 127;
  const int half = tid >> 7;
  const int i0 = half * (PN / 2), i1 = i0 + PN / 2;

  float sum = 0.f, mx = -INFINITY;
  int cur = sbatch[i0];
  bool any = false;
  for (int i = i0; i < i1; ++i) {
    int n = base + i;
    if (n >= NN) break;
    int b = sbatch[i];
    if (b != cur) {
      if (any) {
        atomicAdd(&gsum[(size_t)cur * HD + c], sum);
        atomicMax((int*)&gm[(size_t)cur * HD + c], __float_as_int(mx));
      }
      sum = 0.f; mx = -INFINITY; cur = b; any = false;
    }
    float val = h[(size_t)n * HD + c];
    sum += val; mx = fmaxf(mx, val);
    any = true;
  }
  if (any && cur >= 0) {
    atomicAdd(&gsum[(size_t)cur * HD + c], sum);
    atomicMax((int*)&gm[(size_t)cur * HD + c], __float_as_int(mx));
  }
  if (c == 0) {
    int cnt = 0; int cb = sbatch[i0];
    for (int i = i0; i < i1; ++i) {
      int n = base + i;
      if (n >= NN) break;
      if (sbatch[i] != cb) {
        if (cnt > 0 && cb >= 0) atomicAdd(&gcnt[cb], cnt);
        cnt = 0; cb = sbatch[i];
      }
      cnt++;
    }
    if (cnt > 0 && cb >= 0) atomicAdd(&gcnt[cb], cnt);
  }
}

__global__ __launch_bounds__(256) void pool_finalize_kernel(
    const float* __restrict__ gm, const float* __restrict__ gsum,
    const int* __restrict__ gcnt,
    __hip_bfloat16* __restrict__ ghi, __hip_bfloat16* __restrict__ glo)
{
  int idx = blockIdx.x * 256 + threadIdx.x;
  if (idx >= NB * HD) return;
  int b = idx >> 7, c = idx & 127;
  float mv = gm[idx];
  if (mv < -1e30f) mv = 0.f;
  float cf = (float)gcnt[b];
  float av = gsum[idx] / fmaxf(cf, 1.f);
  size_t o0 = (size_t)b * 256 + c;
  size_t o1 = o0 + 128;
  __hip_bfloat16 h0 = __float2bfloat16(mv);
  __hip_bfloat16 h1 = __float2bfloat16(av);
  ghi[o0] = h0; glo[o0] = __float2bfloat16(mv - __bfloat162float(h0));
  ghi[o1] = h1; glo[o1] = __float2bfloat16(av - __bfloat162float(h1));
}

// ============ final head layer: [512,256] @ [256,1] + b ============
__global__ __launch_bounds__(256) void head4_kernel(
    const float* __restrict__ g3, const float* __restrict__ Wf2,
    const float* __restrict__ bf2, float* __restrict__ out)
{
  int w = threadIdx.x >> 6, lane = threadIdx.x & 63;
  int row = blockIdx.x * 4 + w;
  const float* r = g3 + (size_t)row * 256;
  float p = r[lane] * Wf2[lane] + r[64 + lane] * Wf2[64 + lane]
          + r[128 + lane] * Wf2[128 + lane] + r[192 + lane] * Wf2[192 + lane];
#pragma unroll
  for (int off = 32; off >= 1; off >>= 1) p += __shfl_xor(p, off);
  if (lane == 0) out[row] = p + bf2[0];
}

extern "C" void kernel_launch(void* const* d_in, const int* in_sizes, int n_in,
                              void* d_out, int out_size, void* d_ws, size_t ws_size,
                              hipStream_t stream)
{
  const float* x = (const float*)d_in[0];
  const int* edge_index = (const int*)d_in[1];
  const int* batch = (const int*)d_in[2];
  const int* src = edge_index;
  const int* dstv = edge_index + NE;

  const float *Wq[3], *bq[3], *Wk[3], *bk[3], *Wv[3], *bv[3], *Wsk[3], *bsk[3], *Wm[3], *bm[3];
  int base = 3;
  for (int l = 0; l < 3; ++l) {
    Wq[l]  = (const float*)d_in[base + 0]; bq[l]  = (const float*)d_in[base + 1];
    Wk[l]  = (const float*)d_in[base + 2]; bk[l]  = (const float*)d_in[base + 3];
    Wv[l]  = (const float*)d_in[base + 4]; bv[l]  = (const float*)d_in[base + 5];
    Wsk[l] = (const float*)d_in[base + 6]; bsk[l] = (const float*)d_in[base + 7];
    Wm[l]  = (const float*)d_in[base + 8]; bm[l]  = (const float*)d_in[base + 9];
    base += 10;
  }
  const float* Wg1 = (const float*)d_in[33]; const float* bg1 = (const float*)d_in[34];
  const float* Wg2 = (const float*)d_in[35]; const float* bg2 = (const float*)d_in[36];
  const float* Wf1 = (const float*)d_in[37]; const float* bf1 = (const float*)d_in[38];
  const float* Wf2 = (const float*)d_in[39]; const float* bf2 = (const float*)d_in[40];

  // ---- workspace layout ----
  char* p = (char*)d_ws;
  auto alloc = [&](size_t bytes) { char* r = p; p += (bytes + 255) & ~(size_t)255; return r; };
  __half* qh16 = (__half*)alloc((size_t)MPAD * 512 * 2);   // Q fp16
  __half* kvh  = (__half*)alloc((size_t)MPAD * 1024 * 2);  // per head: K(128)|V(128) fp16
  float* h    = (float*)alloc((size_t)NN * HD * 4);        // last-layer h fp32 (pooling)
  __hip_bfloat16* t0hi = (__hip_bfloat16*)alloc((size_t)MPAD * HC * 2);
  __hip_bfloat16* t0lo = (__hip_bfloat16*)alloc((size_t)MPAD * HC * 2);
  __hip_bfloat16* hAhi = (__hip_bfloat16*)alloc((size_t)MPAD * HD * 2);
  __hip_bfloat16* hAlo = (__hip_bfloat16*)alloc((size_t)MPAD * HD * 2);
  __hip_bfloat16* hBhi = (__hip_bfloat16*)alloc((size_t)MPAD * HD * 2);
  __hip_bfloat16* hBlo = (__hip_bfloat16*)alloc((size_t)MPAD * HD * 2);
  __hip_bfloat16* xhi  = (__hip_bfloat16*)alloc((size_t)MPAD * 64 * 2);
  __hip_bfloat16* xlo  = (__hip_bfloat16*)alloc((size_t)MPAD * 64 * 2);
  __hip_bfloat16 *Wp_hi[3], *Wp_lo[3], *Wmx_hi[3], *Wmx_lo[3];
  Wp_hi[0] = (__hip_bfloat16*)alloc((size_t)1536 * 64 * 2);
  Wp_lo[0] = (__hip_bfloat16*)alloc((size_t)1536 * 64 * 2);
  for (int l = 1; l < 3; ++l) {
    Wp_hi[l] = (__hip_bfloat16*)alloc((size_t)1536 * 128 * 2);
    Wp_lo[l] = (__hip_bfloat16*)alloc((size_t)1536 * 128 * 2);
  }
  for (int l = 0; l < 3; ++l) {
    int KP = (l == 0) ? 576 : 640;
    Wmx_hi[l] = (__hip_bfloat16*)alloc((size_t)128 * KP * 2);
    Wmx_lo[l] = (__hip_bfloat16*)alloc((size_t)128 * KP * 2);
  }
  __hip_bfloat16* Wg1_hi = (__hip_bfloat16*)alloc((size_t)1024 * 256 * 2);
  __hip_bfloat16* Wg1_lo = (__hip_bfloat16*)alloc((size_t)1024 * 256 * 2);
  __hip_bfloat16* Wg2_hi = (__hip_bfloat16*)alloc((size_t)512 * 1024 * 2);
  __hip_bfloat16* Wg2_lo = (__hip_bfloat16*)alloc((size_t)512 * 1024 * 2);
  __hip_bfloat16* Wf1_hi = (__hip_bfloat16*)alloc((size_t)256 * 512 * 2);
  __hip_bfloat16* Wf1_lo = (__hip_bfloat16*)alloc((size_t)256 * 512 * 2);
  float* bpack = (float*)alloc(3 * 1536 * 4);
  float* bm2   = (float*)alloc(3 * 128 * 4);
  float* gm   = (float*)alloc((size_t)NB * HD * 4);
  float* gsum = (float*)alloc((size_t)NB * HD * 4);
  __hip_bfloat16* ghi = (__hip_bfloat16*)alloc((size_t)NB * 256 * 2);
  __hip_bfloat16* glo = (__hip_bfloat16*)alloc((size_t)NB * 256 * 2);
  __hip_bfloat16* g1hi = (__hip_bfloat16*)alloc((size_t)NB * 1024 * 2);
  __hip_bfloat16* g1lo = (__hip_bfloat16*)alloc((size_t)NB * 1024 * 2);
  __hip_bfloat16* g2hi = (__hip_bfloat16*)alloc((size_t)NB * 512 * 2);
  __hip_bfloat16* g2lo = (__hip_bfloat16*)alloc((size_t)NB * 512 * 2);
  float* g3 = (float*)alloc((size_t)NB * 256 * 4);
  __hip_bfloat16* g3hi = (__hip_bfloat16*)alloc((size_t)NB * 256 * 2);
  __hip_bfloat16* g3lo = (__hip_bfloat16*)alloc((size_t)NB * 256 * 2);
  int* icnt      = (int*)alloc(NN * 4);
  int* cursor    = (int*)alloc(NN * 4);
  int* row_start = (int*)alloc((NN + 1) * 4);
  int* edge_list = (int*)alloc((size_t)NE * 4);
  int* gcnt      = (int*)alloc(NB * 4);

  const int GR128 = (NN + 127) / 128;  // 157
  const int GR64  = (NN + 63) / 64;    // 313

  // ---- pack weights + compute Wsm fold ----
  PackArgs pa;
  for (int l = 0; l < 3; ++l) {
    pa.W[l * 3 + 0] = Wq[l];  pa.W[l * 3 + 1] = Wk[l];  pa.W[l * 3 + 2] = Wv[l];
    pa.b[l * 3 + 0] = bq[l];  pa.b[l * 3 + 1] = bk[l];  pa.b[l * 3 + 2] = bv[l];
    pa.Wm[l] = Wm[l];
    pa.Wp_hi[l] = Wp_hi[l]; pa.Wp_lo[l] = Wp_lo[l];
    pa.Wmx_hi[l] = Wmx_hi[l]; pa.Wmx_lo[l] = Wmx_lo[l];
  }
  pa.Wg1 = Wg1; pa.Wg2 = Wg2; pa.Wf1 = Wf1;
  pa.Wg1_hi = Wg1_hi; pa.Wg1_lo = Wg1_lo;
  pa.Wg2_hi = Wg2_hi; pa.Wg2_lo = Wg2_lo;
  pa.Wf1_hi = Wf1_hi; pa.Wf1_lo = Wf1_lo;
  pa.bpack = bpack;
  pack_all_kernel<<<(1610240 + 255) / 256, 256, 0, stream>>>(pa);

  WsmArgs wa;
  for (int l = 0; l < 3; ++l) {
    wa.Ws[l] = Wsk[l]; wa.Wm[l] = Wm[l]; wa.bs[l] = bsk[l]; wa.bm[l] = bm[l];
    wa.Wmx_hi[l] = Wmx_hi[l]; wa.Wmx_lo[l] = Wmx_lo[l];
  }
  wa.bm2 = bm2;
  wsm_kernel<<<(3 * 128 * 128 + 384 + 255) / 256, 256, 0, stream>>>(wa);

  // ---- CSR build ----
  hipMemsetAsync(icnt, 0, sizeof(int) * NN, stream);
  hipMemsetAsync(cursor, 0, sizeof(int) * NN, stream);
  count_kernel<<<(NE + 255) / 256, 256, 0, stream>>>(dstv, icnt);
  scan_kernel<<<1, 1024, 0, stream>>>(icnt, row_start);
  scatter_kernel<<<(NE + 255) / 256, 256, 0, stream>>>(src, dstv, row_start, cursor, edge_list);

  // ---- input split ----
  split_x_kernel<<<(NN * 64 + 255) / 256, 256, 0, stream>>>(x, xhi, xlo);

  // ---- 3 TransformerConv layers ----
  const __hip_bfloat16* Ain_hi = xhi;
  const __hip_bfloat16* Ain_lo = xlo;
  int KpadIn = 64;
  for (int l = 0; l < 3; ++l) {
    __hip_bfloat16* Hout_hi = (l & 1) ? hBhi : hAhi;
    __hip_bfloat16* Hout_lo = (l & 1) ? hBlo : hAlo;

    gemm_qkv_kernel<<<dim3(12, GR128), 256, 0, stream>>>(
        Ain_hi, Ain_lo, KpadIn, Wp_hi[l], Wp_lo[l], bpack + l * 1536,
        qh16, kvh, NN, KpadIn);

    attn_kernel<<<NN, 256, 0, stream>>>(qh16, kvh, row_start, edge_list, t0hi, t0lo);

    // proj: h = relu( t0@Wm + Ain@Wsm + bm2 ), A covers k<512 (t0), A2 = layer input
    gemm64_kernel<<<dim3(GR64, 1), 256, 0, stream>>>(
        t0hi, t0lo, HC, 512, Ain_hi, Ain_lo, KpadIn,
        Wmx_hi[l], Wmx_lo[l], bm2 + l * 128,
        (l == 2) ? h : nullptr, HD, Hout_hi, Hout_lo, NN, 512 + KpadIn);

    Ain_hi = Hout_hi; Ain_lo = Hout_lo; KpadIn = 128;
  }

  // ---- pooling ----
  pool_init_kernel<<<(NB * HD + 255) / 256, 256, 0, stream>>>(gm, gsum, gcnt);
  pool_kernel<<<(NN + PN - 1) / PN, 256, 0, stream>>>(h, batch, gm, gsum, gcnt);
  pool_finalize_kernel<<<(NB * HD + 255) / 256, 256, 0, stream>>>(gm, gsum, gcnt, ghi, glo);

  // ---- MLP head via MFMA (64-row tiles; single A source: Ksplit = K) ----
  gemm64_kernel<<<dim3(8, 8), 256, 0, stream>>>(
      ghi, glo, 256, 256, ghi, glo, 256,
      Wg1_hi, Wg1_lo, bg1, nullptr, 1024, g1hi, g1lo, NB, 256);
  gemm64_kernel<<<dim3(8, 4), 256, 0, stream>>>(
      g1hi, g1lo, 1024, 1024, g1hi, g1lo, 1024,
      Wg2_hi, Wg2_lo, bg2, nullptr, 512, g2hi, g2lo, NB, 1024);
  gemm64_kernel<<<dim3(8, 2), 256, 0, stream>>>(
      g2hi, g2lo, 512, 512, g2hi, g2lo, 512,
      Wf1_hi, Wf1_lo, bf1, g3, 256, g3hi, g3lo, NB, 512);
  head4_kernel<<<NB / 4, 256, 0, stream>>>(g3, Wf2, bf2, (float*)d_out);
}

// Round 10
// 614.549 us; speedup vs baseline: 3.4229x; 1.0790x over previous
//
#include <hip/hip_runtime.h>
#include <hip/hip_bf16.h>
#include <hip/hip_fp16.h>
#include <math.h>

#define NN 20000
#define MPAD 20096          // row padding for MFMA staging (mult of 128)
#define NE 320000
#define NB 512
#define FIN 43
#define HD 128
#define HC 512
#define ATT_SCALE 0.08838834764831843f

typedef __attribute__((ext_vector_type(8))) short bf16x8v;
typedef __attribute__((ext_vector_type(8))) short short8v;
typedef __attribute__((ext_vector_type(4))) float f32x4v;
typedef _Float16 half2_t __attribute__((ext_vector_type(2)));

__device__ __forceinline__ void gload16(void* lds, const void* g) {
  __builtin_amdgcn_global_load_lds(
      (const __attribute__((address_space(1))) void*)g,
      (__attribute__((address_space(3))) void*)lds, 16, 0, 0);
}

__device__ __forceinline__ float dot2acc(half2_t a, half2_t b, float c) {
#if __has_builtin(__builtin_amdgcn_fdot2)
  return __builtin_amdgcn_fdot2(a, b, c, false);
#else
  return c + (float)a[0] * (float)b[0] + (float)a[1] * (float)b[1];
#endif
}

// ============ qkv GEMM, 128x128 tile (grid COL-FASTEST: x=col-block, y=row-block) ============
// cols [0,512):    fp16 Q -> qh16[row*512+col]
// cols [512,1024): K head h -> kvh[row*1024 + h*256 + c]
// cols [1024,1536):V head h -> kvh[row*1024 + h*256 + 128 + c]
__global__ __launch_bounds__(256, 2) void gemm_qkv_kernel(
    const __hip_bfloat16* __restrict__ Ahi_, const __hip_bfloat16* __restrict__ Alo_, int ldA,
    const __hip_bfloat16* __restrict__ Bhi_, const __hip_bfloat16* __restrict__ Blo_,
    const float* __restrict__ bias,
    __half* __restrict__ qh16, __half* __restrict__ kvh,
    int M, int K)
{
  __shared__ short Ah[128 * 64], Al[128 * 64], Bh[128 * 64], Bl[128 * 64];
  const short* Ahi = (const short*)Ahi_;
  const short* Alo = (const short*)Alo_;
  const short* Bhi = (const short*)Bhi_;
  const short* Blo = (const short*)Blo_;
  const int tid = threadIdx.x;
  const int w = tid >> 6, lane = tid & 63;
  const int rowBase = blockIdx.y * 128, colBase = blockIdx.x * 128;
  const int srow = lane >> 3;
  const int sw = ((lane & 7) ^ srow) << 3;
  const int lr = lane & 15, lg = lane >> 4;
  const int wr = w >> 1, wc = w & 1;

  f32x4v acc[4][4];
#pragma unroll
  for (int m = 0; m < 4; ++m)
#pragma unroll
    for (int n = 0; n < 4; ++n) acc[m][n] = (f32x4v){0.f, 0.f, 0.f, 0.f};

  for (int k0 = 0; k0 < K; k0 += 64) {
    if (k0) __syncthreads();
#pragma unroll
    for (int t = 0; t < 4; ++t) {
      int r0 = w * 32 + t * 8;
      size_t arow = (size_t)(rowBase + r0 + srow) * ldA + k0 + sw;
      size_t brow = (size_t)(colBase + r0 + srow) * K + k0 + sw;
      gload16(&Ah[r0 * 64], Ahi + arow);
      gload16(&Al[r0 * 64], Alo + arow);
      gload16(&Bh[r0 * 64], Bhi + brow);
      gload16(&Bl[r0 * 64], Blo + brow);
    }
    __syncthreads();
#pragma unroll
    for (int kk = 0; kk < 2; ++kk) {
      bf16x8v ah[4], al[4], bh[4], bl[4];
      int cbase = ((kk * 4 + lg) ^ (lr & 7)) * 8;
#pragma unroll
      for (int m = 0; m < 4; ++m) {
        int idx = (wr * 64 + m * 16 + lr) * 64 + cbase;
        ah[m] = *(const bf16x8v*)&Ah[idx];
        al[m] = *(const bf16x8v*)&Al[idx];
      }
#pragma unroll
      for (int n = 0; n < 4; ++n) {
        int idx = (wc * 64 + n * 16 + lr) * 64 + cbase;
        bh[n] = *(const bf16x8v*)&Bh[idx];
        bl[n] = *(const bf16x8v*)&Bl[idx];
      }
#pragma unroll
      for (int m = 0; m < 4; ++m)
#pragma unroll
        for (int n = 0; n < 4; ++n) {
          acc[m][n] = __builtin_amdgcn_mfma_f32_16x16x32_bf16(ah[m], bh[n], acc[m][n], 0, 0, 0);
          acc[m][n] = __builtin_amdgcn_mfma_f32_16x16x32_bf16(ah[m], bl[n], acc[m][n], 0, 0, 0);
          acc[m][n] = __builtin_amdgcn_mfma_f32_16x16x32_bf16(al[m], bh[n], acc[m][n], 0, 0, 0);
        }
    }
  }
#pragma unroll
  for (int m = 0; m < 4; ++m) {
#pragma unroll
    for (int n = 0; n < 4; ++n) {
      int col = colBase + wc * 64 + n * 16 + lr;
      float bb = bias[col];
#pragma unroll
      for (int r = 0; r < 4; ++r) {
        int row = rowBase + wr * 64 + m * 16 + lg * 4 + r;
        if (row < M) {
          float v = acc[m][n][r] + bb;
          if (col < 512) {
            qh16[(size_t)row * 512 + col] = __float2half(v);
          } else if (col < 1024) {
            int cc = col - 512;
            kvh[(size_t)row * 1024 + (cc >> 7) * 256 + (cc & 127)] = __float2half(v);
          } else {
            int cc = col - 1024;
            kvh[(size_t)row * 1024 + (cc >> 7) * 256 + 128 + (cc & 127)] = __float2half(v);
          }
        }
      }
    }
  }
}

// ============ split-bf16 MFMA GEMM, 64x128 tile, two A sources along K ============
__global__ __launch_bounds__(256, 2) void gemm64_kernel(
    const __hip_bfloat16* __restrict__ Ahi_, const __hip_bfloat16* __restrict__ Alo_, int ldA,
    int Ksplit,
    const __hip_bfloat16* __restrict__ A2hi_, const __hip_bfloat16* __restrict__ A2lo_, int ldA2,
    const __hip_bfloat16* __restrict__ Bhi_, const __hip_bfloat16* __restrict__ Blo_,
    const float* __restrict__ bias,
    float* __restrict__ Y, int ldY,
    __hip_bfloat16* __restrict__ Yhi, __hip_bfloat16* __restrict__ Ylo,
    int M, int K)
{
  __shared__ short Ah[64 * 64], Al[64 * 64], Bh[128 * 64], Bl[128 * 64];
  const short* Bhi = (const short*)Bhi_;
  const short* Blo = (const short*)Blo_;
  const int tid = threadIdx.x;
  const int w = tid >> 6, lane = tid & 63;
  const int rowBase = blockIdx.x * 64, colBase = blockIdx.y * 128;
  const int srow = lane >> 3;
  const int sw = ((lane & 7) ^ srow) << 3;
  const int lr = lane & 15, lg = lane >> 4;
  const int wr = w >> 1, wc = w & 1;

  f32x4v acc[2][4];
#pragma unroll
  for (int m = 0; m < 2; ++m)
#pragma unroll
    for (int n = 0; n < 4; ++n) acc[m][n] = (f32x4v){0.f, 0.f, 0.f, 0.f};

  for (int k0 = 0; k0 < K; k0 += 64) {
    if (k0) __syncthreads();
    const short* sAh;
    const short* sAl;
    int ldS, kloc;
    if (k0 < Ksplit) { sAh = (const short*)Ahi_;  sAl = (const short*)Alo_;  ldS = ldA;  kloc = k0; }
    else             { sAh = (const short*)A2hi_; sAl = (const short*)A2lo_; ldS = ldA2; kloc = k0 - Ksplit; }
#pragma unroll
    for (int t = 0; t < 2; ++t) {
      int r0 = w * 16 + t * 8;
      size_t arow = (size_t)(rowBase + r0 + srow) * ldS + kloc + sw;
      gload16(&Ah[r0 * 64], sAh + arow);
      gload16(&Al[r0 * 64], sAl + arow);
    }
#pragma unroll
    for (int t = 0; t < 4; ++t) {
      int r0 = w * 32 + t * 8;
      size_t brow = (size_t)(colBase + r0 + srow) * K + k0 + sw;
      gload16(&Bh[r0 * 64], Bhi + brow);
      gload16(&Bl[r0 * 64], Blo + brow);
    }
    __syncthreads();
#pragma unroll
    for (int kk = 0; kk < 2; ++kk) {
      bf16x8v ah[2], al[2], bh[4], bl[4];
      int cbase = ((kk * 4 + lg) ^ (lr & 7)) * 8;
#pragma unroll
      for (int m = 0; m < 2; ++m) {
        int idx = (wr * 32 + m * 16 + lr) * 64 + cbase;
        ah[m] = *(const bf16x8v*)&Ah[idx];
        al[m] = *(const bf16x8v*)&Al[idx];
      }
#pragma unroll
      for (int n = 0; n < 4; ++n) {
        int idx = (wc * 64 + n * 16 + lr) * 64 + cbase;
        bh[n] = *(const bf16x8v*)&Bh[idx];
        bl[n] = *(const bf16x8v*)&Bl[idx];
      }
#pragma unroll
      for (int m = 0; m < 2; ++m)
#pragma unroll
        for (int n = 0; n < 4; ++n) {
          acc[m][n] = __builtin_amdgcn_mfma_f32_16x16x32_bf16(ah[m], bh[n], acc[m][n], 0, 0, 0);
          acc[m][n] = __builtin_amdgcn_mfma_f32_16x16x32_bf16(ah[m], bl[n], acc[m][n], 0, 0, 0);
          acc[m][n] = __builtin_amdgcn_mfma_f32_16x16x32_bf16(al[m], bh[n], acc[m][n], 0, 0, 0);
        }
    }
  }
#pragma unroll
  for (int m = 0; m < 2; ++m) {
#pragma unroll
    for (int n = 0; n < 4; ++n) {
      int col = colBase + wc * 64 + n * 16 + lr;
      float bb = bias[col];
#pragma unroll
      for (int r = 0; r < 4; ++r) {
        int row = rowBase + wr * 32 + m * 16 + lg * 4 + r;
        if (row < M) {
          float v = fmaxf(acc[m][n][r] + bb, 0.f);
          if (Y) Y[(size_t)row * ldY + col] = v;
          __hip_bfloat16 hv = __float2bfloat16(v);
          Yhi[(size_t)row * ldY + col] = hv;
          Ylo[(size_t)row * ldY + col] = __float2bfloat16(v - __bfloat162float(hv));
        }
      }
    }
  }
}

// ============ Wsm = Ws@Wm fold (skip path into proj) ============
struct WsmArgs {
  const float* Ws[3];   // [din][512]
  const float* Wm[3];   // [512][128]
  const float* bs[3];   // [512]
  const float* bm[3];   // [128]
  __hip_bfloat16 *Wmx_hi[3], *Wmx_lo[3];  // [128][KP]  KP=576(l0)/640
  float* bm2;           // [3][128]
};

__global__ __launch_bounds__(256) void wsm_kernel(WsmArgs a)
{
  int idx = blockIdx.x * 256 + threadIdx.x;
  if (idx < 3 * 128 * 128) {
    int l = idx >> 14, r = idx & 16383;
    int n = r >> 7, d = r & 127;
    int K2pad = (l == 0) ? 64 : 128;
    if (d >= K2pad) return;
    int din = (l == 0) ? FIN : 128;
    float v = 0.f;
    if (d < din) {
      const float* ws = a.Ws[l] + (size_t)d * 512;
      const float* wm = a.Wm[l];
      for (int j = 0; j < 512; ++j) v += ws[j] * wm[(size_t)j * 128 + n];
    }
    int KP = 512 + K2pad;
    __hip_bfloat16 h = __float2bfloat16(v);
    a.Wmx_hi[l][(size_t)n * KP + 512 + d] = h;
    a.Wmx_lo[l][(size_t)n * KP + 512 + d] = __float2bfloat16(v - __bfloat162float(h));
  } else {
    int r = idx - 3 * 128 * 128;
    if (r >= 384) return;
    int l = r >> 7, n = r & 127;
    float v = a.bm[l][n];
    const float* bs = a.bs[l];
    const float* wm = a.Wm[l];
    for (int j = 0; j < 512; ++j) v += bs[j] * wm[(size_t)j * 128 + n];
    a.bm2[l * 128 + n] = v;
  }
}

// ============ pack everything in one launch ============
struct PackArgs {
  const float* W[9];      // [l*3 + {q,k,v}]  shape [K][512]
  const float* b[9];
  const float* Wm[3];     // [512][128]
  const float *Wg1, *Wg2, *Wf1;
  __hip_bfloat16 *Wp_hi[3], *Wp_lo[3];    // [1536][Kpad]
  __hip_bfloat16 *Wmx_hi[3], *Wmx_lo[3];  // [128][KP] (k<512 part)
  __hip_bfloat16 *Wg1_hi, *Wg1_lo;        // [1024][256]
  __hip_bfloat16 *Wg2_hi, *Wg2_lo;        // [512][1024]
  __hip_bfloat16 *Wf1_hi, *Wf1_lo;        // [256][512]
  float* bpack;                            // [3][1536]
};

__global__ __launch_bounds__(256) void pack_all_kernel(PackArgs a)
{
  int idx = blockIdx.x * 256 + threadIdx.x;
  if (idx < 98304) {
    int n = idx >> 6, k = idx & 63;
    int mat = n >> 9, nn = n & 511;
    float v = (k < FIN) ? a.W[mat][(size_t)k * 512 + nn] : 0.f;
    __hip_bfloat16 h = __float2bfloat16(v);
    a.Wp_hi[0][idx] = h;
    a.Wp_lo[0][idx] = __float2bfloat16(v - __bfloat162float(h));
  } else if (idx < 491520) {
    int rel = idx - 98304;
    int l = 1 + rel / 196608;
    int r2 = rel % 196608;
    int n = r2 >> 7, k = r2 & 127;
    int mat = n >> 9, nn = n & 511;
    float v = a.W[l * 3 + mat][(size_t)k * 512 + nn];
    __hip_bfloat16 h = __float2bfloat16(v);
    a.Wp_hi[l][r2] = h;
    a.Wp_lo[l][r2] = __float2bfloat16(v - __bfloat162float(h));
  } else if (idx < 688128) {
    int rel = idx - 491520;
    int l = rel >> 16;
    int r2 = rel & 65535;
    int n = r2 >> 9, k = r2 & 511;
    float v = a.Wm[l][(size_t)k * 128 + n];
    int KP = (l == 0) ? 576 : 640;
    __hip_bfloat16 h = __float2bfloat16(v);
    a.Wmx_hi[l][(size_t)n * KP + k] = h;
    a.Wmx_lo[l][(size_t)n * KP + k] = __float2bfloat16(v - __bfloat162float(h));
  } else if (idx < 692736) {
    int rel = idx - 688128;
    int l = rel / 1536, c = rel % 1536;
    a.bpack[rel] = a.b[l * 3 + (c >> 9)][c & 511];
  } else if (idx < 954880) {
    int rel = idx - 692736;
    int n = rel >> 8, k = rel & 255;
    float v = a.Wg1[(size_t)k * 1024 + n];
    __hip_bfloat16 h = __float2bfloat16(v);
    a.Wg1_hi[rel] = h;
    a.Wg1_lo[rel] = __float2bfloat16(v - __bfloat162float(h));
  } else if (idx < 1479168) {
    int rel = idx - 954880;
    int n = rel >> 10, k = rel & 1023;
    float v = a.Wg2[(size_t)k * 512 + n];
    __hip_bfloat16 h = __float2bfloat16(v);
    a.Wg2_hi[rel] = h;
    a.Wg2_lo[rel] = __float2bfloat16(v - __bfloat162float(h));
  } else if (idx < 1610240) {
    int rel = idx - 1479168;
    int n = rel >> 9, k = rel & 511;
    float v = a.Wf1[(size_t)k * 256 + n];
    __hip_bfloat16 h = __float2bfloat16(v);
    a.Wf1_hi[rel] = h;
    a.Wf1_lo[rel] = __float2bfloat16(v - __bfloat162float(h));
  }
}

__global__ __launch_bounds__(256) void split_x_kernel(
    const float* __restrict__ x, __hip_bfloat16* __restrict__ hi, __hip_bfloat16* __restrict__ lo)
{
  int idx = blockIdx.x * 256 + threadIdx.x;
  if (idx >= NN * 64) return;
  int r = idx >> 6, c = idx & 63;
  float v = (c < FIN) ? x[(size_t)r * FIN + c] : 0.f;
  __hip_bfloat16 h = __float2bfloat16(v);
  hi[idx] = h;
  lo[idx] = __float2bfloat16(v - __bfloat162float(h));
}

// ============ CSR build over dst ============
__global__ __launch_bounds__(256) void count_kernel(const int* __restrict__ dst, int* __restrict__ cnt)
{
  int e = blockIdx.x * 256 + threadIdx.x;
  if (e < NE) atomicAdd(&cnt[dst[e]], 1);
}

__global__ __launch_bounds__(1024) void scan_kernel(const int* __restrict__ cnt, int* __restrict__ row_start)
{
  __shared__ int sums[1024];
  int t = threadIdx.x;
  const int per = (NN + 1023) / 1024;
  int beg = t * per;
  int end = beg + per; if (end > NN) end = NN; if (beg > NN) beg = NN;
  int s = 0;
  for (int i = beg; i < end; ++i) s += cnt[i];
  sums[t] = s;
  __syncthreads();
  for (int off = 1; off < 1024; off <<= 1) {
    int v = (t >= off) ? sums[t - off] : 0;
    __syncthreads();
    sums[t] += v;
    __syncthreads();
  }
  int prefix = (t == 0) ? 0 : sums[t - 1];
  for (int i = beg; i < end; ++i) { row_start[i] = prefix; prefix += cnt[i]; }
  if (t == 1023) row_start[NN] = prefix;
}

__global__ __launch_bounds__(256) void scatter_kernel(
    const int* __restrict__ src, const int* __restrict__ dst,
    const int* __restrict__ row_start,
    int* __restrict__ cursor, int* __restrict__ edge_list)
{
  int e = blockIdx.x * 256 + threadIdx.x;
  if (e < NE) {
    int d = dst[e];
    int p = atomicAdd(&cursor[d], 1);
    edge_list[row_start[d] + p] = src[e];
  }
}

// ============ fused attention: single-pass, defer-max, barrier-free, HEAD-SPLIT ============
// grid (NN/4, 4): blockIdx.y = head (slow dispatch index -> per-phase KV working set 10 MB);
// wave w = node blockIdx.x*4+w. 16-lane subgroup keeps private (m,den,acc).
__global__ __launch_bounds__(256) void attn_kernel(
    const __half* __restrict__ qh16, const __half* __restrict__ kvh,
    const int* __restrict__ row_start, const int* __restrict__ edge_list,
    __hip_bfloat16* __restrict__ t0hi, __hip_bfloat16* __restrict__ t0lo)
{
  const int tid = threadIdx.x;
  const int w = tid >> 6, lane = tid & 63;
  const int node = blockIdx.x * 4 + w;
  const int hd = blockIdx.y;
  const int g4 = lane >> 4, sl = lane & 15;
  const int beg = row_start[node], cnt = row_start[node + 1] - beg;

  float4 qraw = *(const float4*)(qh16 + (size_t)node * 512 + hd * 128 + 8 * sl);
  const half2_t* qh = (const half2_t*)&qraw;

  float m = -INFINITY, den = 0.f;
  float a[8] = {0.f, 0.f, 0.f, 0.f, 0.f, 0.f, 0.f, 0.f};

  auto upd = [&](float p, const float4& vraw) {
    const __half2* vh = (const __half2*)&vraw;
    float2 f0 = __half22float2(vh[0]);
    float2 f1 = __half22float2(vh[1]);
    float2 f2 = __half22float2(vh[2]);
    float2 f3 = __half22float2(vh[3]);
    if (__builtin_expect(p > m + 8.f, 0)) {
      float c = __expf(m - p);   // m=-inf first time -> 0
      den = den * c + 1.f;
      a[0] = a[0] * c + f0.x; a[1] = a[1] * c + f0.y;
      a[2] = a[2] * c + f1.x; a[3] = a[3] * c + f1.y;
      a[4] = a[4] * c + f2.x; a[5] = a[5] * c + f2.y;
      a[6] = a[6] * c + f3.x; a[7] = a[7] * c + f3.y;
      m = p;
    } else {
      float e = __expf(p - m);
      den += e;
      a[0] += e * f0.x; a[1] += e * f0.y;
      a[2] += e * f1.x; a[3] += e * f1.y;
      a[4] += e * f2.x; a[5] += e * f2.y;
      a[6] += e * f3.x; a[7] += e * f3.y;
    }
  };

  const int* el = edge_list + beg;
  for (int j = 4 * g4; j < cnt; j += 16) {
    bool h1 = (j + 1 < cnt), h2 = (j + 2 < cnt), h3 = (j + 3 < cnt);
    int s0 = el[j];
    int s1 = h1 ? el[j + 1] : s0;
    int s2 = h2 ? el[j + 2] : s0;
    int s3 = h3 ? el[j + 3] : s0;
    const __half* b0 = kvh + (size_t)s0 * 1024 + hd * 256 + 8 * sl;
    const __half* b1 = kvh + (size_t)s1 * 1024 + hd * 256 + 8 * sl;
    const __half* b2 = kvh + (size_t)s2 * 1024 + hd * 256 + 8 * sl;
    const __half* b3 = kvh + (size_t)s3 * 1024 + hd * 256 + 8 * sl;
    float4 k0 = *(const float4*)b0;
    float4 k1 = *(const float4*)b1;
    float4 k2 = *(const float4*)b2;
    float4 k3 = *(const float4*)b3;
    float4 v0 = *(const float4*)(b0 + 128);
    float4 v1 = *(const float4*)(b1 + 128);
    float4 v2 = *(const float4*)(b2 + 128);
    float4 v3 = *(const float4*)(b3 + 128);

    const half2_t* kh0 = (const half2_t*)&k0;
    const half2_t* kh1 = (const half2_t*)&k1;
    const half2_t* kh2 = (const half2_t*)&k2;
    const half2_t* kh3 = (const half2_t*)&k3;
    float p0 = 0.f, p1 = 0.f, p2 = 0.f, p3 = 0.f;
#pragma unroll
    for (int i = 0; i < 4; ++i) {
      p0 = dot2acc(qh[i], kh0[i], p0);
      p1 = dot2acc(qh[i], kh1[i], p1);
      p2 = dot2acc(qh[i], kh2[i], p2);
      p3 = dot2acc(qh[i], kh3[i], p3);
    }
#pragma unroll
    for (int off = 8; off >= 1; off >>= 1) {
      p0 += __shfl_xor(p0, off);
      p1 += __shfl_xor(p1, off);
      p2 += __shfl_xor(p2, off);
      p3 += __shfl_xor(p3, off);
    }
    p0 *= ATT_SCALE; p1 *= ATT_SCALE; p2 *= ATT_SCALE; p3 *= ATT_SCALE;
    upd(p0, v0);
    if (h1) upd(p1, v1);
    if (h2) upd(p2, v2);
    if (h3) upd(p3, v3);
  }

  // combine the 4 subgroups (online-softmax merge; m's are deferred maxima)
  float m2 = fmaxf(m, __shfl_xor(m, 16));
  float mAll = fmaxf(m2, __shfl_xor(m2, 32));
  float scale = (m == -INFINITY) ? 0.f : __expf(m - mAll);
  den *= scale;
  den += __shfl_xor(den, 16);
  den += __shfl_xor(den, 32);
#pragma unroll
  for (int i = 0; i < 8; ++i) {
    a[i] *= scale;
    a[i] += __shfl_xor(a[i], 16);
    a[i] += __shfl_xor(a[i], 32);
  }

  if (g4 == 0) {
    float inv = 1.f / fmaxf(den, 1e-16f);
    short8v hi8, lo8;
#pragma unroll
    for (int i = 0; i < 8; ++i) {
      float v = a[i] * inv;
      __hip_bfloat16 hv = __float2bfloat16(v);
      __hip_bfloat16 lv = __float2bfloat16(v - __bfloat162float(hv));
      hi8[i] = *(short*)&hv;
      lo8[i] = *(short*)&lv;
    }
    size_t o = (size_t)node * HC + hd * 128 + 8 * sl;
    *(short8v*)(t0hi + o) = hi8;
    *(short8v*)(t0lo + o) = lo8;
  }
}

// ============ pooling (run-compressed: batch is sorted) ============
__global__ __launch_bounds__(256) void pool_init_kernel(float* __restrict__ gm, float* __restrict__ gsum, int* __restrict__ gcnt)
{
  int i = blockIdx.x * 256 + threadIdx.x;
  if (i < NB * HD) { ((int*)gm)[i] = 0xFF800000; gsum[i] = 0.f; }
  if (i < NB) gcnt[i] = 0;
}

#define PN 32  // nodes per block
__global__ __launch_bounds__(256) void pool_kernel(
    const float* __restrict__ h, const int* __restrict__ batch,
    float* __restrict__ gm, float* __restrict__ gsum, int* __restrict__ gcnt)
{
  __shared__ int sbatch[PN];
  const int base = blockIdx.x * PN;
  const int tid = threadIdx.x;
  if (tid < PN) {
    int n = base + tid;
    sbatch[tid] = (n < NN) ? batch[n] : -1;
  }
  __syncthreads();
  const int c = tid & 127;
  const int half = tid >> 7;
  const int i0 = half * (PN / 2), i1 = i0 + PN / 2;

  float sum = 0.f, mx = -INFINITY;
  int cur = sbatch[i0];
  bool any = false;
  for (int i = i0; i < i1; ++i) {
    int n = base + i;
    if (n >= NN) break;
    int b = sbatch[i];
    if (b != cur) {
      if (any) {
        atomicAdd(&gsum[(size_t)cur * HD + c], sum);
        atomicMax((int*)&gm[(size_t)cur * HD + c], __float_as_int(mx));
      }
      sum = 0.f; mx = -INFINITY; cur = b; any = false;
    }
    float val = h[(size_t)n * HD + c];
    sum += val; mx = fmaxf(mx, val);
    any = true;
  }
  if (any && cur >= 0) {
    atomicAdd(&gsum[(size_t)cur * HD + c], sum);
    atomicMax((int*)&gm[(size_t)cur * HD + c], __float_as_int(mx));
  }
  if (c == 0) {
    int cnt = 0; int cb = sbatch[i0];
    for (int i = i0; i < i1; ++i) {
      int n = base + i;
      if (n >= NN) break;
      if (sbatch[i] != cb) {
        if (cnt > 0 && cb >= 0) atomicAdd(&gcnt[cb], cnt);
        cnt = 0; cb = sbatch[i];
      }
      cnt++;
    }
    if (cnt > 0 && cb >= 0) atomicAdd(&gcnt[cb], cnt);
  }
}

__global__ __launch_bounds__(256) void pool_finalize_kernel(
    const float* __restrict__ gm, const float* __restrict__ gsum,
    const int* __restrict__ gcnt,
    __hip_bfloat16* __restrict__ ghi, __hip_bfloat16* __restrict__ glo)
{
  int idx = blockIdx.x * 256 + threadIdx.x;
  if (idx >= NB * HD) return;
  int b = idx >> 7, c = idx & 127;
  float mv = gm[idx];
  if (mv < -1e30f) mv = 0.f;
  float cf = (float)gcnt[b];
  float av = gsum[idx] / fmaxf(cf, 1.f);
  size_t o0 = (size_t)b * 256 + c;
  size_t o1 = o0 + 128;
  __hip_bfloat16 h0 = __float2bfloat16(mv);
  __hip_bfloat16 h1 = __float2bfloat16(av);
  ghi[o0] = h0; glo[o0] = __float2bfloat16(mv - __bfloat162float(h0));
  ghi[o1] = h1; glo[o1] = __float2bfloat16(av - __bfloat162float(h1));
}

// ============ final head layer: [512,256] @ [256,1] + b ============
__global__ __launch_bounds__(256) void head4_kernel(
    const float* __restrict__ g3, const float* __restrict__ Wf2,
    const float* __restrict__ bf2, float* __restrict__ out)
{
  int w = threadIdx.x >> 6, lane = threadIdx.x & 63;
  int row = blockIdx.x * 4 + w;
  const float* r = g3 + (size_t)row * 256;
  float p = r[lane] * Wf2[lane] + r[64 + lane] * Wf2[64 + lane]
          + r[128 + lane] * Wf2[128 + lane] + r[192 + lane] * Wf2[192 + lane];
#pragma unroll
  for (int off = 32; off >= 1; off >>= 1) p += __shfl_xor(p, off);
  if (lane == 0) out[row] = p + bf2[0];
}

extern "C" void kernel_launch(void* const* d_in, const int* in_sizes, int n_in,
                              void* d_out, int out_size, void* d_ws, size_t ws_size,
                              hipStream_t stream)
{
  const float* x = (const float*)d_in[0];
  const int* edge_index = (const int*)d_in[1];
  const int* batch = (const int*)d_in[2];
  const int* src = edge_index;
  const int* dstv = edge_index + NE;

  const float *Wq[3], *bq[3], *Wk[3], *bk[3], *Wv[3], *bv[3], *Wsk[3], *bsk[3], *Wm[3], *bm[3];
  int base = 3;
  for (int l = 0; l < 3; ++l) {
    Wq[l]  = (const float*)d_in[base + 0]; bq[l]  = (const float*)d_in[base + 1];
    Wk[l]  = (const float*)d_in[base + 2]; bk[l]  = (const float*)d_in[base + 3];
    Wv[l]  = (const float*)d_in[base + 4]; bv[l]  = (const float*)d_in[base + 5];
    Wsk[l] = (const float*)d_in[base + 6]; bsk[l] = (const float*)d_in[base + 7];
    Wm[l]  = (const float*)d_in[base + 8]; bm[l]  = (const float*)d_in[base + 9];
    base += 10;
  }
  const float* Wg1 = (const float*)d_in[33]; const float* bg1 = (const float*)d_in[34];
  const float* Wg2 = (const float*)d_in[35]; const float* bg2 = (const float*)d_in[36];
  const float* Wf1 = (const float*)d_in[37]; const float* bf1 = (const float*)d_in[38];
  const float* Wf2 = (const float*)d_in[39]; const float* bf2 = (const float*)d_in[40];

  // ---- workspace layout ----
  char* p = (char*)d_ws;
  auto alloc = [&](size_t bytes) { char* r = p; p += (bytes + 255) & ~(size_t)255; return r; };
  __half* qh16 = (__half*)alloc((size_t)MPAD * 512 * 2);   // Q fp16
  __half* kvh  = (__half*)alloc((size_t)MPAD * 1024 * 2);  // per head: K(128)|V(128) fp16
  float* h    = (float*)alloc((size_t)NN * HD * 4);        // last-layer h fp32 (pooling)
  __hip_bfloat16* t0hi = (__hip_bfloat16*)alloc((size_t)MPAD * HC * 2);
  __hip_bfloat16* t0lo = (__hip_bfloat16*)alloc((size_t)MPAD * HC * 2);
  __hip_bfloat16* hAhi = (__hip_bfloat16*)alloc((size_t)MPAD * HD * 2);
  __hip_bfloat16* hAlo = (__hip_bfloat16*)alloc((size_t)MPAD * HD * 2);
  __hip_bfloat16* hBhi = (__hip_bfloat16*)alloc((size_t)MPAD * HD * 2);
  __hip_bfloat16* hBlo = (__hip_bfloat16*)alloc((size_t)MPAD * HD * 2);
  __hip_bfloat16* xhi  = (__hip_bfloat16*)alloc((size_t)MPAD * 64 * 2);
  __hip_bfloat16* xlo  = (__hip_bfloat16*)alloc((size_t)MPAD * 64 * 2);
  __hip_bfloat16 *Wp_hi[3], *Wp_lo[3], *Wmx_hi[3], *Wmx_lo[3];
  Wp_hi[0] = (__hip_bfloat16*)alloc((size_t)1536 * 64 * 2);
  Wp_lo[0] = (__hip_bfloat16*)alloc((size_t)1536 * 64 * 2);
  for (int l = 1; l < 3; ++l) {
    Wp_hi[l] = (__hip_bfloat16*)alloc((size_t)1536 * 128 * 2);
    Wp_lo[l] = (__hip_bfloat16*)alloc((size_t)1536 * 128 * 2);
  }
  for (int l = 0; l < 3; ++l) {
    int KP = (l == 0) ? 576 : 640;
    Wmx_hi[l] = (__hip_bfloat16*)alloc((size_t)128 * KP * 2);
    Wmx_lo[l] = (__hip_bfloat16*)alloc((size_t)128 * KP * 2);
  }
  __hip_bfloat16* Wg1_hi = (__hip_bfloat16*)alloc((size_t)1024 * 256 * 2);
  __hip_bfloat16* Wg1_lo = (__hip_bfloat16*)alloc((size_t)1024 * 256 * 2);
  __hip_bfloat16* Wg2_hi = (__hip_bfloat16*)alloc((size_t)512 * 1024 * 2);
  __hip_bfloat16* Wg2_lo = (__hip_bfloat16*)alloc((size_t)512 * 1024 * 2);
  __hip_bfloat16* Wf1_hi = (__hip_bfloat16*)alloc((size_t)256 * 512 * 2);
  __hip_bfloat16* Wf1_lo = (__hip_bfloat16*)alloc((size_t)256 * 512 * 2);
  float* bpack = (float*)alloc(3 * 1536 * 4);
  float* bm2   = (float*)alloc(3 * 128 * 4);
  float* gm   = (float*)alloc((size_t)NB * HD * 4);
  float* gsum = (float*)alloc((size_t)NB * HD * 4);
  __hip_bfloat16* ghi = (__hip_bfloat16*)alloc((size_t)NB * 256 * 2);
  __hip_bfloat16* glo = (__hip_bfloat16*)alloc((size_t)NB * 256 * 2);
  __hip_bfloat16* g1hi = (__hip_bfloat16*)alloc((size_t)NB * 1024 * 2);
  __hip_bfloat16* g1lo = (__hip_bfloat16*)alloc((size_t)NB * 1024 * 2);
  __hip_bfloat16* g2hi = (__hip_bfloat16*)alloc((size_t)NB * 512 * 2);
  __hip_bfloat16* g2lo = (__hip_bfloat16*)alloc((size_t)NB * 512 * 2);
  float* g3 = (float*)alloc((size_t)NB * 256 * 4);
  __hip_bfloat16* g3hi = (__hip_bfloat16*)alloc((size_t)NB * 256 * 2);
  __hip_bfloat16* g3lo = (__hip_bfloat16*)alloc((size_t)NB * 256 * 2);
  int* icnt      = (int*)alloc(NN * 4);
  int* cursor    = (int*)alloc(NN * 4);
  int* row_start = (int*)alloc((NN + 1) * 4);
  int* edge_list = (int*)alloc((size_t)NE * 4);
  int* gcnt      = (int*)alloc(NB * 4);

  const int GR128 = (NN + 127) / 128;  // 157
  const int GR64  = (NN + 63) / 64;    // 313

  // ---- pack weights + compute Wsm fold ----
  PackArgs pa;
  for (int l = 0; l < 3; ++l) {
    pa.W[l * 3 + 0] = Wq[l];  pa.W[l * 3 + 1] = Wk[l];  pa.W[l * 3 + 2] = Wv[l];
    pa.b[l * 3 + 0] = bq[l];  pa.b[l * 3 + 1] = bk[l];  pa.b[l * 3 + 2] = bv[l];
    pa.Wm[l] = Wm[l];
    pa.Wp_hi[l] = Wp_hi[l]; pa.Wp_lo[l] = Wp_lo[l];
    pa.Wmx_hi[l] = Wmx_hi[l]; pa.Wmx_lo[l] = Wmx_lo[l];
  }
  pa.Wg1 = Wg1; pa.Wg2 = Wg2; pa.Wf1 = Wf1;
  pa.Wg1_hi = Wg1_hi; pa.Wg1_lo = Wg1_lo;
  pa.Wg2_hi = Wg2_hi; pa.Wg2_lo = Wg2_lo;
  pa.Wf1_hi = Wf1_hi; pa.Wf1_lo = Wf1_lo;
  pa.bpack = bpack;
  pack_all_kernel<<<(1610240 + 255) / 256, 256, 0, stream>>>(pa);

  WsmArgs wa;
  for (int l = 0; l < 3; ++l) {
    wa.Ws[l] = Wsk[l]; wa.Wm[l] = Wm[l]; wa.bs[l] = bsk[l]; wa.bm[l] = bm[l];
    wa.Wmx_hi[l] = Wmx_hi[l]; wa.Wmx_lo[l] = Wmx_lo[l];
  }
  wa.bm2 = bm2;
  wsm_kernel<<<(3 * 128 * 128 + 384 + 255) / 256, 256, 0, stream>>>(wa);

  // ---- CSR build ----
  hipMemsetAsync(icnt, 0, sizeof(int) * NN, stream);
  hipMemsetAsync(cursor, 0, sizeof(int) * NN, stream);
  count_kernel<<<(NE + 255) / 256, 256, 0, stream>>>(dstv, icnt);
  scan_kernel<<<1, 1024, 0, stream>>>(icnt, row_start);
  scatter_kernel<<<(NE + 255) / 256, 256, 0, stream>>>(src, dstv, row_start, cursor, edge_list);

  // ---- input split ----
  split_x_kernel<<<(NN * 64 + 255) / 256, 256, 0, stream>>>(x, xhi, xlo);

  // ---- 3 TransformerConv layers ----
  const __hip_bfloat16* Ain_hi = xhi;
  const __hip_bfloat16* Ain_lo = xlo;
  int KpadIn = 64;
  for (int l = 0; l < 3; ++l) {
    __hip_bfloat16* Hout_hi = (l & 1) ? hBhi : hAhi;
    __hip_bfloat16* Hout_lo = (l & 1) ? hBlo : hAlo;

    gemm_qkv_kernel<<<dim3(12, GR128), 256, 0, stream>>>(
        Ain_hi, Ain_lo, KpadIn, Wp_hi[l], Wp_lo[l], bpack + l * 1536,
        qh16, kvh, NN, KpadIn);

    attn_kernel<<<dim3(NN / 4, 4), 256, 0, stream>>>(
        qh16, kvh, row_start, edge_list, t0hi, t0lo);

    // proj: h = relu( t0@Wm + Ain@Wsm + bm2 ), A covers k<512 (t0), A2 = layer input
    gemm64_kernel<<<dim3(GR64, 1), 256, 0, stream>>>(
        t0hi, t0lo, HC, 512, Ain_hi, Ain_lo, KpadIn,
        Wmx_hi[l], Wmx_lo[l], bm2 + l * 128,
        (l == 2) ? h : nullptr, HD, Hout_hi, Hout_lo, NN, 512 + KpadIn);

    Ain_hi = Hout_hi; Ain_lo = Hout_lo; KpadIn = 128;
  }

  // ---- pooling ----
  pool_init_kernel<<<(NB * HD + 255) / 256, 256, 0, stream>>>(gm, gsum, gcnt);
  pool_kernel<<<(NN + PN - 1) / PN, 256, 0, stream>>>(h, batch, gm, gsum, gcnt);
  pool_finalize_kernel<<<(NB * HD + 255) / 256, 256, 0, stream>>>(gm, gsum, gcnt, ghi, glo);

  // ---- MLP head via MFMA (64-row tiles; single A source: Ksplit = K) ----
  gemm64_kernel<<<dim3(8, 8), 256, 0, stream>>>(
      ghi, glo, 256, 256, ghi, glo, 256,
      Wg1_hi, Wg1_lo, bg1, nullptr, 1024, g1hi, g1lo, NB, 256);
  gemm64_kernel<<<dim3(8, 4), 256, 0, stream>>>(
      g1hi, g1lo, 1024, 1024, g1hi, g1lo, 1024,
      Wg2_hi, Wg2_lo, bg2, nullptr, 512, g2hi, g2lo, NB, 1024);
  gemm64_kernel<<<dim3(8, 2), 256, 0, stream>>>(
      g2hi, g2lo, 512, 512, g2hi, g2lo, 512,
      Wf1_hi, Wf1_lo, bf1, g3, 256, g3hi, g3lo, NB, 512);
  head4_kernel<<<NB / 4, 256, 0, stream>>>(g3, Wf2, bf2, (float*)d_out);
}

// Round 11
// 510.858 us; speedup vs baseline: 4.1177x; 1.2030x over previous
//
#include <hip/hip_runtime.h>
#include <hip/hip_bf16.h>
#include <hip/hip_fp16.h>
#include <math.h>

#define NN 20000
#define MPAD 20096          // row padding for MFMA staging (mult of 128)
#define NE 320000
#define NB 512
#define FIN 43
#define HD 128
#define HC 512
#define ATT_SCALE 0.08838834764831843f

typedef __attribute__((ext_vector_type(8))) _Float16 f16x8v;
typedef __attribute__((ext_vector_type(8))) short short8v;
typedef __attribute__((ext_vector_type(4))) float f32x4v;
typedef _Float16 half2_t __attribute__((ext_vector_type(2)));

__device__ __forceinline__ void gload16(void* lds, const void* g) {
  __builtin_amdgcn_global_load_lds(
      (const __attribute__((address_space(1))) void*)g,
      (__attribute__((address_space(3))) void*)lds, 16, 0, 0);
}

__device__ __forceinline__ float dot2acc(half2_t a, half2_t b, float c) {
#if __has_builtin(__builtin_amdgcn_fdot2)
  return __builtin_amdgcn_fdot2(a, b, c, false);
#else
  return c + (float)a[0] * (float)b[0] + (float)a[1] * (float)b[1];
#endif
}

// ============ fp16 MFMA qkv GEMM, 128x128 tile (grid COL-FASTEST) ============
// cols [0,512):    fp16 Q -> qh16[row*512+col]
// cols [512,1024): K head h -> kvh[row*1024 + h*256 + c]
// cols [1024,1536):V head h -> kvh[row*1024 + h*256 + 128 + c]
__global__ __launch_bounds__(256, 2) void gemm_qkv_kernel(
    const __half* __restrict__ A_, int ldA,
    const __half* __restrict__ B_,
    const float* __restrict__ bias,
    __half* __restrict__ qh16, __half* __restrict__ kvh,
    int M, int K)
{
  __shared__ _Float16 Ah[128 * 64], Bh[128 * 64];
  const _Float16* A = (const _Float16*)A_;
  const _Float16* B = (const _Float16*)B_;
  const int tid = threadIdx.x;
  const int w = tid >> 6, lane = tid & 63;
  const int rowBase = blockIdx.y * 128, colBase = blockIdx.x * 128;
  const int srow = lane >> 3;
  const int sw = ((lane & 7) ^ srow) << 3;
  const int lr = lane & 15, lg = lane >> 4;
  const int wr = w >> 1, wc = w & 1;

  f32x4v acc[4][4];
#pragma unroll
  for (int m = 0; m < 4; ++m)
#pragma unroll
    for (int n = 0; n < 4; ++n) acc[m][n] = (f32x4v){0.f, 0.f, 0.f, 0.f};

  for (int k0 = 0; k0 < K; k0 += 64) {
    if (k0) __syncthreads();
#pragma unroll
    for (int t = 0; t < 4; ++t) {
      int r0 = w * 32 + t * 8;
      size_t arow = (size_t)(rowBase + r0 + srow) * ldA + k0 + sw;
      size_t brow = (size_t)(colBase + r0 + srow) * K + k0 + sw;
      gload16(&Ah[r0 * 64], A + arow);
      gload16(&Bh[r0 * 64], B + brow);
    }
    __syncthreads();
#pragma unroll
    for (int kk = 0; kk < 2; ++kk) {
      f16x8v ah[4], bh[4];
      int cbase = ((kk * 4 + lg) ^ (lr & 7)) * 8;
#pragma unroll
      for (int m = 0; m < 4; ++m)
        ah[m] = *(const f16x8v*)&Ah[(wr * 64 + m * 16 + lr) * 64 + cbase];
#pragma unroll
      for (int n = 0; n < 4; ++n)
        bh[n] = *(const f16x8v*)&Bh[(wc * 64 + n * 16 + lr) * 64 + cbase];
#pragma unroll
      for (int m = 0; m < 4; ++m)
#pragma unroll
        for (int n = 0; n < 4; ++n)
          acc[m][n] = __builtin_amdgcn_mfma_f32_16x16x32_f16(ah[m], bh[n], acc[m][n], 0, 0, 0);
    }
  }
#pragma unroll
  for (int m = 0; m < 4; ++m) {
#pragma unroll
    for (int n = 0; n < 4; ++n) {
      int col = colBase + wc * 64 + n * 16 + lr;
      float bb = bias[col];
#pragma unroll
      for (int r = 0; r < 4; ++r) {
        int row = rowBase + wr * 64 + m * 16 + lg * 4 + r;
        if (row < M) {
          float v = acc[m][n][r] + bb;
          if (col < 512) {
            qh16[(size_t)row * 512 + col] = __float2half(v);
          } else if (col < 1024) {
            int cc = col - 512;
            kvh[(size_t)row * 1024 + (cc >> 7) * 256 + (cc & 127)] = __float2half(v);
          } else {
            int cc = col - 1024;
            kvh[(size_t)row * 1024 + (cc >> 7) * 256 + 128 + (cc & 127)] = __float2half(v);
          }
        }
      }
    }
  }
}

// ============ fp16 MFMA GEMM, 64x128 tile, two A sources along K ============
// A covers k in [0,Ksplit), A2 covers k in [Ksplit,K). relu; optional fp32 Y; fp16 Yh.
__global__ __launch_bounds__(256, 2) void gemm64_kernel(
    const __half* __restrict__ A_, int ldA, int Ksplit,
    const __half* __restrict__ A2_, int ldA2,
    const __half* __restrict__ B_,
    const float* __restrict__ bias,
    float* __restrict__ Y, int ldY,
    __half* __restrict__ Yh,
    int M, int K)
{
  __shared__ _Float16 Ah[64 * 64], Bh[128 * 64];
  const _Float16* B = (const _Float16*)B_;
  const int tid = threadIdx.x;
  const int w = tid >> 6, lane = tid & 63;
  const int rowBase = blockIdx.x * 64, colBase = blockIdx.y * 128;
  const int srow = lane >> 3;
  const int sw = ((lane & 7) ^ srow) << 3;
  const int lr = lane & 15, lg = lane >> 4;
  const int wr = w >> 1, wc = w & 1;

  f32x4v acc[2][4];
#pragma unroll
  for (int m = 0; m < 2; ++m)
#pragma unroll
    for (int n = 0; n < 4; ++n) acc[m][n] = (f32x4v){0.f, 0.f, 0.f, 0.f};

  for (int k0 = 0; k0 < K; k0 += 64) {
    if (k0) __syncthreads();
    const _Float16* sA;
    int ldS, kloc;
    if (k0 < Ksplit) { sA = (const _Float16*)A_;  ldS = ldA;  kloc = k0; }
    else             { sA = (const _Float16*)A2_; ldS = ldA2; kloc = k0 - Ksplit; }
#pragma unroll
    for (int t = 0; t < 2; ++t) {
      int r0 = w * 16 + t * 8;
      size_t arow = (size_t)(rowBase + r0 + srow) * ldS + kloc + sw;
      gload16(&Ah[r0 * 64], sA + arow);
    }
#pragma unroll
    for (int t = 0; t < 4; ++t) {
      int r0 = w * 32 + t * 8;
      size_t brow = (size_t)(colBase + r0 + srow) * K + k0 + sw;
      gload16(&Bh[r0 * 64], B + brow);
    }
    __syncthreads();
#pragma unroll
    for (int kk = 0; kk < 2; ++kk) {
      f16x8v ah[2], bh[4];
      int cbase = ((kk * 4 + lg) ^ (lr & 7)) * 8;
#pragma unroll
      for (int m = 0; m < 2; ++m)
        ah[m] = *(const f16x8v*)&Ah[(wr * 32 + m * 16 + lr) * 64 + cbase];
#pragma unroll
      for (int n = 0; n < 4; ++n)
        bh[n] = *(const f16x8v*)&Bh[(wc * 64 + n * 16 + lr) * 64 + cbase];
#pragma unroll
      for (int m = 0; m < 2; ++m)
#pragma unroll
        for (int n = 0; n < 4; ++n)
          acc[m][n] = __builtin_amdgcn_mfma_f32_16x16x32_f16(ah[m], bh[n], acc[m][n], 0, 0, 0);
    }
  }
#pragma unroll
  for (int m = 0; m < 2; ++m) {
#pragma unroll
    for (int n = 0; n < 4; ++n) {
      int col = colBase + wc * 64 + n * 16 + lr;
      float bb = bias[col];
#pragma unroll
      for (int r = 0; r < 4; ++r) {
        int row = rowBase + wr * 32 + m * 16 + lg * 4 + r;
        if (row < M) {
          float v = fmaxf(acc[m][n][r] + bb, 0.f);
          if (Y) Y[(size_t)row * ldY + col] = v;
          Yh[(size_t)row * ldY + col] = __float2half(v);
        }
      }
    }
  }
}

// ============ Wsm = Ws@Wm fold (skip path into proj) ============
struct WsmArgs {
  const float* Ws[3];   // [din][512]
  const float* Wm[3];   // [512][128]
  const float* bs[3];   // [512]
  const float* bm[3];   // [128]
  __half* Wmx[3];       // [128][KP]  KP=576(l0)/640
  float* bm2;           // [3][128]
};

__global__ __launch_bounds__(256) void wsm_kernel(WsmArgs a)
{
  int idx = blockIdx.x * 256 + threadIdx.x;
  if (idx < 3 * 128 * 128) {
    int l = idx >> 14, r = idx & 16383;
    int n = r >> 7, d = r & 127;
    int K2pad = (l == 0) ? 64 : 128;
    if (d >= K2pad) return;
    int din = (l == 0) ? FIN : 128;
    float v = 0.f;
    if (d < din) {
      const float* ws = a.Ws[l] + (size_t)d * 512;
      const float* wm = a.Wm[l];
      for (int j = 0; j < 512; ++j) v += ws[j] * wm[(size_t)j * 128 + n];
    }
    int KP = 512 + K2pad;
    a.Wmx[l][(size_t)n * KP + 512 + d] = __float2half(v);
  } else {
    int r = idx - 3 * 128 * 128;
    if (r >= 384) return;
    int l = r >> 7, n = r & 127;
    float v = a.bm[l][n];
    const float* bs = a.bs[l];
    const float* wm = a.Wm[l];
    for (int j = 0; j < 512; ++j) v += bs[j] * wm[(size_t)j * 128 + n];
    a.bm2[l * 128 + n] = v;
  }
}

// ============ pack everything in one launch (all weights -> fp16, transposed) ============
struct PackArgs {
  const float* W[9];      // [l*3 + {q,k,v}]  shape [K][512]
  const float* b[9];
  const float* Wm[3];     // [512][128]
  const float *Wg1, *Wg2, *Wf1;
  __half* Wp[3];          // [1536][Kpad]
  __half* Wmx[3];         // [128][KP] (k<512 part)
  __half *Wg1p, *Wg2p, *Wf1p;   // [1024][256], [512][1024], [256][512]
  float* bpack;           // [3][1536]
};

__global__ __launch_bounds__(256) void pack_all_kernel(PackArgs a)
{
  int idx = blockIdx.x * 256 + threadIdx.x;
  if (idx < 98304) {
    int n = idx >> 6, k = idx & 63;
    int mat = n >> 9, nn = n & 511;
    float v = (k < FIN) ? a.W[mat][(size_t)k * 512 + nn] : 0.f;
    a.Wp[0][idx] = __float2half(v);
  } else if (idx < 491520) {
    int rel = idx - 98304;
    int l = 1 + rel / 196608;
    int r2 = rel % 196608;
    int n = r2 >> 7, k = r2 & 127;
    int mat = n >> 9, nn = n & 511;
    a.Wp[l][r2] = __float2half(a.W[l * 3 + mat][(size_t)k * 512 + nn]);
  } else if (idx < 688128) {
    int rel = idx - 491520;
    int l = rel >> 16;
    int r2 = rel & 65535;
    int n = r2 >> 9, k = r2 & 511;
    int KP = (l == 0) ? 576 : 640;
    a.Wmx[l][(size_t)n * KP + k] = __float2half(a.Wm[l][(size_t)k * 128 + n]);
  } else if (idx < 692736) {
    int rel = idx - 688128;
    int l = rel / 1536, c = rel % 1536;
    a.bpack[rel] = a.b[l * 3 + (c >> 9)][c & 511];
  } else if (idx < 954880) {
    int rel = idx - 692736;
    int n = rel >> 8, k = rel & 255;
    a.Wg1p[rel] = __float2half(a.Wg1[(size_t)k * 1024 + n]);
  } else if (idx < 1479168) {
    int rel = idx - 954880;
    int n = rel >> 10, k = rel & 1023;
    a.Wg2p[rel] = __float2half(a.Wg2[(size_t)k * 512 + n]);
  } else if (idx < 1610240) {
    int rel = idx - 1479168;
    int n = rel >> 9, k = rel & 511;
    a.Wf1p[rel] = __float2half(a.Wf1[(size_t)k * 256 + n]);
  }
}

__global__ __launch_bounds__(256) void split_x_kernel(
    const float* __restrict__ x, __half* __restrict__ xh)
{
  int idx = blockIdx.x * 256 + threadIdx.x;
  if (idx >= NN * 64) return;
  int r = idx >> 6, c = idx & 63;
  float v = (c < FIN) ? x[(size_t)r * FIN + c] : 0.f;
  xh[idx] = __float2half(v);
}

// ============ CSR build over dst ============
__global__ __launch_bounds__(256) void count_kernel(const int* __restrict__ dst, int* __restrict__ cnt)
{
  int e = blockIdx.x * 256 + threadIdx.x;
  if (e < NE) atomicAdd(&cnt[dst[e]], 1);
}

__global__ __launch_bounds__(1024) void scan_kernel(const int* __restrict__ cnt, int* __restrict__ row_start)
{
  __shared__ int sums[1024];
  int t = threadIdx.x;
  const int per = (NN + 1023) / 1024;
  int beg = t * per;
  int end = beg + per; if (end > NN) end = NN; if (beg > NN) beg = NN;
  int s = 0;
  for (int i = beg; i < end; ++i) s += cnt[i];
  sums[t] = s;
  __syncthreads();
  for (int off = 1; off < 1024; off <<= 1) {
    int v = (t >= off) ? sums[t - off] : 0;
    __syncthreads();
    sums[t] += v;
    __syncthreads();
  }
  int prefix = (t == 0) ? 0 : sums[t - 1];
  for (int i = beg; i < end; ++i) { row_start[i] = prefix; prefix += cnt[i]; }
  if (t == 1023) row_start[NN] = prefix;
}

__global__ __launch_bounds__(256) void scatter_kernel(
    const int* __restrict__ src, const int* __restrict__ dst,
    const int* __restrict__ row_start,
    int* __restrict__ cursor, int* __restrict__ edge_list)
{
  int e = blockIdx.x * 256 + threadIdx.x;
  if (e < NE) {
    int d = dst[e];
    int p = atomicAdd(&cursor[d], 1);
    edge_list[row_start[d] + p] = src[e];
  }
}

// ============ fused attention: single-pass, defer-max, barrier-free, HEAD-SPLIT ============
__global__ __launch_bounds__(256) void attn_kernel(
    const __half* __restrict__ qh16, const __half* __restrict__ kvh,
    const int* __restrict__ row_start, const int* __restrict__ edge_list,
    __half* __restrict__ t0h)
{
  const int tid = threadIdx.x;
  const int w = tid >> 6, lane = tid & 63;
  const int node = blockIdx.x * 4 + w;
  const int hd = blockIdx.y;
  const int g4 = lane >> 4, sl = lane & 15;
  const int beg = row_start[node], cnt = row_start[node + 1] - beg;

  float4 qraw = *(const float4*)(qh16 + (size_t)node * 512 + hd * 128 + 8 * sl);
  const half2_t* qh = (const half2_t*)&qraw;

  float m = -INFINITY, den = 0.f;
  float a[8] = {0.f, 0.f, 0.f, 0.f, 0.f, 0.f, 0.f, 0.f};

  auto upd = [&](float p, const float4& vraw) {
    const __half2* vh = (const __half2*)&vraw;
    float2 f0 = __half22float2(vh[0]);
    float2 f1 = __half22float2(vh[1]);
    float2 f2 = __half22float2(vh[2]);
    float2 f3 = __half22float2(vh[3]);
    if (__builtin_expect(p > m + 8.f, 0)) {
      float c = __expf(m - p);   // m=-inf first time -> 0
      den = den * c + 1.f;
      a[0] = a[0] * c + f0.x; a[1] = a[1] * c + f0.y;
      a[2] = a[2] * c + f1.x; a[3] = a[3] * c + f1.y;
      a[4] = a[4] * c + f2.x; a[5] = a[5] * c + f2.y;
      a[6] = a[6] * c + f3.x; a[7] = a[7] * c + f3.y;
      m = p;
    } else {
      float e = __expf(p - m);
      den += e;
      a[0] += e * f0.x; a[1] += e * f0.y;
      a[2] += e * f1.x; a[3] += e * f1.y;
      a[4] += e * f2.x; a[5] += e * f2.y;
      a[6] += e * f3.x; a[7] += e * f3.y;
    }
  };

  const int* el = edge_list + beg;
  for (int j = 4 * g4; j < cnt; j += 16) {
    bool h1 = (j + 1 < cnt), h2 = (j + 2 < cnt), h3 = (j + 3 < cnt);
    int s0 = el[j];
    int s1 = h1 ? el[j + 1] : s0;
    int s2 = h2 ? el[j + 2] : s0;
    int s3 = h3 ? el[j + 3] : s0;
    const __half* b0 = kvh + (size_t)s0 * 1024 + hd * 256 + 8 * sl;
    const __half* b1 = kvh + (size_t)s1 * 1024 + hd * 256 + 8 * sl;
    const __half* b2 = kvh + (size_t)s2 * 1024 + hd * 256 + 8 * sl;
    const __half* b3 = kvh + (size_t)s3 * 1024 + hd * 256 + 8 * sl;
    float4 k0 = *(const float4*)b0;
    float4 k1 = *(const float4*)b1;
    float4 k2 = *(const float4*)b2;
    float4 k3 = *(const float4*)b3;
    float4 v0 = *(const float4*)(b0 + 128);
    float4 v1 = *(const float4*)(b1 + 128);
    float4 v2 = *(const float4*)(b2 + 128);
    float4 v3 = *(const float4*)(b3 + 128);

    const half2_t* kh0 = (const half2_t*)&k0;
    const half2_t* kh1 = (const half2_t*)&k1;
    const half2_t* kh2 = (const half2_t*)&k2;
    const half2_t* kh3 = (const half2_t*)&k3;
    float p0 = 0.f, p1 = 0.f, p2 = 0.f, p3 = 0.f;
#pragma unroll
    for (int i = 0; i < 4; ++i) {
      p0 = dot2acc(qh[i], kh0[i], p0);
      p1 = dot2acc(qh[i], kh1[i], p1);
      p2 = dot2acc(qh[i], kh2[i], p2);
      p3 = dot2acc(qh[i], kh3[i], p3);
    }
#pragma unroll
    for (int off = 8; off >= 1; off >>= 1) {
      p0 += __shfl_xor(p0, off);
      p1 += __shfl_xor(p1, off);
      p2 += __shfl_xor(p2, off);
      p3 += __shfl_xor(p3, off);
    }
    p0 *= ATT_SCALE; p1 *= ATT_SCALE; p2 *= ATT_SCALE; p3 *= ATT_SCALE;
    upd(p0, v0);
    if (h1) upd(p1, v1);
    if (h2) upd(p2, v2);
    if (h3) upd(p3, v3);
  }

  // combine the 4 subgroups (online-softmax merge; m's are deferred maxima)
  float m2 = fmaxf(m, __shfl_xor(m, 16));
  float mAll = fmaxf(m2, __shfl_xor(m2, 32));
  float scale = (m == -INFINITY) ? 0.f : __expf(m - mAll);
  den *= scale;
  den += __shfl_xor(den, 16);
  den += __shfl_xor(den, 32);
#pragma unroll
  for (int i = 0; i < 8; ++i) {
    a[i] *= scale;
    a[i] += __shfl_xor(a[i], 16);
    a[i] += __shfl_xor(a[i], 32);
  }

  if (g4 == 0) {
    float inv = 1.f / fmaxf(den, 1e-16f);
    short8v o8;
#pragma unroll
    for (int i = 0; i < 8; ++i) {
      __half hv = __float2half(a[i] * inv);
      o8[i] = *(short*)&hv;
    }
    size_t o = (size_t)node * HC + hd * 128 + 8 * sl;
    *(short8v*)(t0h + o) = o8;
  }
}

// ============ pooling (run-compressed: batch is sorted) ============
__global__ __launch_bounds__(256) void pool_init_kernel(float* __restrict__ gm, float* __restrict__ gsum, int* __restrict__ gcnt)
{
  int i = blockIdx.x * 256 + threadIdx.x;
  if (i < NB * HD) { ((int*)gm)[i] = 0xFF800000; gsum[i] = 0.f; }
  if (i < NB) gcnt[i] = 0;
}

#define PN 32  // nodes per block
__global__ __launch_bounds__(256) void pool_kernel(
    const float* __restrict__ h, const int* __restrict__ batch,
    float* __restrict__ gm, float* __restrict__ gsum, int* __restrict__ gcnt)
{
  __shared__ int sbatch[PN];
  const int base = blockIdx.x * PN;
  const int tid = threadIdx.x;
  if (tid < PN) {
    int n = base + tid;
    sbatch[tid] = (n < NN) ? batch[n] : -1;
  }
  __syncthreads();
  const int c = tid & 127;
  const int half = tid >> 7;
  const int i0 = half * (PN / 2), i1 = i0 + PN / 2;

  float sum = 0.f, mx = -INFINITY;
  int cur = sbatch[i0];
  bool any = false;
  for (int i = i0; i < i1; ++i) {
    int n = base + i;
    if (n >= NN) break;
    int b = sbatch[i];
    if (b != cur) {
      if (any) {
        atomicAdd(&gsum[(size_t)cur * HD + c], sum);
        atomicMax((int*)&gm[(size_t)cur * HD + c], __float_as_int(mx));
      }
      sum = 0.f; mx = -INFINITY; cur = b; any = false;
    }
    float val = h[(size_t)n * HD + c];
    sum += val; mx = fmaxf(mx, val);
    any = true;
  }
  if (any && cur >= 0) {
    atomicAdd(&gsum[(size_t)cur * HD + c], sum);
    atomicMax((int*)&gm[(size_t)cur * HD + c], __float_as_int(mx));
  }
  if (c == 0) {
    int cnt = 0; int cb = sbatch[i0];
    for (int i = i0; i < i1; ++i) {
      int n = base + i;
      if (n >= NN) break;
      if (sbatch[i] != cb) {
        if (cnt > 0 && cb >= 0) atomicAdd(&gcnt[cb], cnt);
        cnt = 0; cb = sbatch[i];
      }
      cnt++;
    }
    if (cnt > 0 && cb >= 0) atomicAdd(&gcnt[cb], cnt);
  }
}

__global__ __launch_bounds__(256) void pool_finalize_kernel(
    const float* __restrict__ gm, const float* __restrict__ gsum,
    const int* __restrict__ gcnt, __half* __restrict__ gh)
{
  int idx = blockIdx.x * 256 + threadIdx.x;
  if (idx >= NB * HD) return;
  int b = idx >> 7, c = idx & 127;
  float mv = gm[idx];
  if (mv < -1e30f) mv = 0.f;
  float cf = (float)gcnt[b];
  float av = gsum[idx] / fmaxf(cf, 1.f);
  size_t o0 = (size_t)b * 256 + c;
  gh[o0] = __float2half(mv);
  gh[o0 + 128] = __float2half(av);
}

// ============ final head layer: [512,256] @ [256,1] + b ============
__global__ __launch_bounds__(256) void head4_kernel(
    const float* __restrict__ g3, const float* __restrict__ Wf2,
    const float* __restrict__ bf2, float* __restrict__ out)
{
  int w = threadIdx.x >> 6, lane = threadIdx.x & 63;
  int row = blockIdx.x * 4 + w;
  const float* r = g3 + (size_t)row * 256;
  float p = r[lane] * Wf2[lane] + r[64 + lane] * Wf2[64 + lane]
          + r[128 + lane] * Wf2[128 + lane] + r[192 + lane] * Wf2[192 + lane];
#pragma unroll
  for (int off = 32; off >= 1; off >>= 1) p += __shfl_xor(p, off);
  if (lane == 0) out[row] = p + bf2[0];
}

extern "C" void kernel_launch(void* const* d_in, const int* in_sizes, int n_in,
                              void* d_out, int out_size, void* d_ws, size_t ws_size,
                              hipStream_t stream)
{
  const float* x = (const float*)d_in[0];
  const int* edge_index = (const int*)d_in[1];
  const int* batch = (const int*)d_in[2];
  const int* src = edge_index;
  const int* dstv = edge_index + NE;

  const float *Wq[3], *bq[3], *Wk[3], *bk[3], *Wv[3], *bv[3], *Wsk[3], *bsk[3], *Wm[3], *bm[3];
  int base = 3;
  for (int l = 0; l < 3; ++l) {
    Wq[l]  = (const float*)d_in[base + 0]; bq[l]  = (const float*)d_in[base + 1];
    Wk[l]  = (const float*)d_in[base + 2]; bk[l]  = (const float*)d_in[base + 3];
    Wv[l]  = (const float*)d_in[base + 4]; bv[l]  = (const float*)d_in[base + 5];
    Wsk[l] = (const float*)d_in[base + 6]; bsk[l] = (const float*)d_in[base + 7];
    Wm[l]  = (const float*)d_in[base + 8]; bm[l]  = (const float*)d_in[base + 9];
    base += 10;
  }
  const float* Wg1 = (const float*)d_in[33]; const float* bg1 = (const float*)d_in[34];
  const float* Wg2 = (const float*)d_in[35]; const float* bg2 = (const float*)d_in[36];
  const float* Wf1 = (const float*)d_in[37]; const float* bf1 = (const float*)d_in[38];
  const float* Wf2 = (const float*)d_in[39]; const float* bf2 = (const float*)d_in[40];

  // ---- workspace layout ----
  char* p = (char*)d_ws;
  auto alloc = [&](size_t bytes) { char* r = p; p += (bytes + 255) & ~(size_t)255; return r; };
  __half* qh16 = (__half*)alloc((size_t)MPAD * 512 * 2);   // Q fp16
  __half* kvh  = (__half*)alloc((size_t)MPAD * 1024 * 2);  // per head: K(128)|V(128) fp16
  float* h    = (float*)alloc((size_t)NN * HD * 4);        // last-layer h fp32 (pooling)
  __half* t0h = (__half*)alloc((size_t)MPAD * HC * 2);     // attn out fp16
  __half* hA  = (__half*)alloc((size_t)MPAD * HD * 2);
  __half* hB  = (__half*)alloc((size_t)MPAD * HD * 2);
  __half* xh  = (__half*)alloc((size_t)MPAD * 64 * 2);
  __half *Wp[3], *Wmx[3];
  Wp[0] = (__half*)alloc((size_t)1536 * 64 * 2);
  for (int l = 1; l < 3; ++l) Wp[l] = (__half*)alloc((size_t)1536 * 128 * 2);
  for (int l = 0; l < 3; ++l) {
    int KP = (l == 0) ? 576 : 640;
    Wmx[l] = (__half*)alloc((size_t)128 * KP * 2);
  }
  __half* Wg1p = (__half*)alloc((size_t)1024 * 256 * 2);
  __half* Wg2p = (__half*)alloc((size_t)512 * 1024 * 2);
  __half* Wf1p = (__half*)alloc((size_t)256 * 512 * 2);
  float* bpack = (float*)alloc(3 * 1536 * 4);
  float* bm2   = (float*)alloc(3 * 128 * 4);
  float* gm   = (float*)alloc((size_t)NB * HD * 4);
  float* gsum = (float*)alloc((size_t)NB * HD * 4);
  __half* gh  = (__half*)alloc((size_t)NB * 256 * 2);
  __half* g1h = (__half*)alloc((size_t)NB * 1024 * 2);
  __half* g2h = (__half*)alloc((size_t)NB * 512 * 2);
  float* g3   = (float*)alloc((size_t)NB * 256 * 4);
  __half* g3h = (__half*)alloc((size_t)NB * 256 * 2);
  int* icnt      = (int*)alloc(NN * 4);
  int* cursor    = (int*)alloc(NN * 4);
  int* row_start = (int*)alloc((NN + 1) * 4);
  int* edge_list = (int*)alloc((size_t)NE * 4);
  int* gcnt      = (int*)alloc(NB * 4);

  const int GR128 = (NN + 127) / 128;  // 157
  const int GR64  = (NN + 63) / 64;    // 313

  // ---- pack weights + compute Wsm fold ----
  PackArgs pa;
  for (int l = 0; l < 3; ++l) {
    pa.W[l * 3 + 0] = Wq[l];  pa.W[l * 3 + 1] = Wk[l];  pa.W[l * 3 + 2] = Wv[l];
    pa.b[l * 3 + 0] = bq[l];  pa.b[l * 3 + 1] = bk[l];  pa.b[l * 3 + 2] = bv[l];
    pa.Wm[l] = Wm[l];
    pa.Wp[l] = Wp[l];
    pa.Wmx[l] = Wmx[l];
  }
  pa.Wg1 = Wg1; pa.Wg2 = Wg2; pa.Wf1 = Wf1;
  pa.Wg1p = Wg1p; pa.Wg2p = Wg2p; pa.Wf1p = Wf1p;
  pa.bpack = bpack;
  pack_all_kernel<<<(1610240 + 255) / 256, 256, 0, stream>>>(pa);

  WsmArgs wa;
  for (int l = 0; l < 3; ++l) {
    wa.Ws[l] = Wsk[l]; wa.Wm[l] = Wm[l]; wa.bs[l] = bsk[l]; wa.bm[l] = bm[l];
    wa.Wmx[l] = Wmx[l];
  }
  wa.bm2 = bm2;
  wsm_kernel<<<(3 * 128 * 128 + 384 + 255) / 256, 256, 0, stream>>>(wa);

  // ---- CSR build ----
  hipMemsetAsync(icnt, 0, sizeof(int) * NN, stream);
  hipMemsetAsync(cursor, 0, sizeof(int) * NN, stream);
  count_kernel<<<(NE + 255) / 256, 256, 0, stream>>>(dstv, icnt);
  scan_kernel<<<1, 1024, 0, stream>>>(icnt, row_start);
  scatter_kernel<<<(NE + 255) / 256, 256, 0, stream>>>(src, dstv, row_start, cursor, edge_list);

  // ---- input convert ----
  split_x_kernel<<<(NN * 64 + 255) / 256, 256, 0, stream>>>(x, xh);

  // ---- 3 TransformerConv layers ----
  const __half* Ain = xh;
  int KpadIn = 64;
  for (int l = 0; l < 3; ++l) {
    __half* Hout = (l & 1) ? hB : hA;

    gemm_qkv_kernel<<<dim3(12, GR128), 256, 0, stream>>>(
        Ain, KpadIn, Wp[l], bpack + l * 1536, qh16, kvh, NN, KpadIn);

    attn_kernel<<<dim3(NN / 4, 4), 256, 0, stream>>>(
        qh16, kvh, row_start, edge_list, t0h);

    // proj: h = relu( t0@Wm + Ain@Wsm + bm2 )
    gemm64_kernel<<<dim3(GR64, 1), 256, 0, stream>>>(
        t0h, HC, 512, Ain, KpadIn,
        Wmx[l], bm2 + l * 128,
        (l == 2) ? h : nullptr, HD, Hout, NN, 512 + KpadIn);

    Ain = Hout; KpadIn = 128;
  }

  // ---- pooling ----
  pool_init_kernel<<<(NB * HD + 255) / 256, 256, 0, stream>>>(gm, gsum, gcnt);
  pool_kernel<<<(NN + PN - 1) / PN, 256, 0, stream>>>(h, batch, gm, gsum, gcnt);
  pool_finalize_kernel<<<(NB * HD + 255) / 256, 256, 0, stream>>>(gm, gsum, gcnt, gh);

  // ---- MLP head via MFMA (64-row tiles; single A source: Ksplit = K) ----
  gemm64_kernel<<<dim3(8, 8), 256, 0, stream>>>(
      gh, 256, 256, gh, 256, Wg1p, bg1, nullptr, 1024, g1h, NB, 256);
  gemm64_kernel<<<dim3(8, 4), 256, 0, stream>>>(
      g1h, 1024, 1024, g1h, 1024, Wg2p, bg2, nullptr, 512, g2h, NB, 1024);
  gemm64_kernel<<<dim3(8, 2), 256, 0, stream>>>(
      g2h, 512, 512, g2h, 512, Wf1p, bf1, g3, 256, g3h, NB, 512);
  head4_kernel<<<NB / 4, 256, 0, stream>>>(g3, Wf2, bf2, (float*)d_out);
}